// Round 7
// baseline (1254.466 us; speedup 1.0000x reference)
//
#include <hip/hip_runtime.h>
#include <hip/hip_fp16.h>
#include <math.h>

// Problem constants
constexpr int S_IN = 32, V_IN = 16, INVD = 16;
constexpr int S_MSG = S_IN + V_IN;           // 48
constexpr int V_MSG = S_IN + V_IN;           // 48
constexpr int NFAC  = S_MSG + V_MSG;         // 96
constexpr int S_OUT = 32, V_OUT = 16;
constexpr int OUT_PER_NODE = S_OUT + V_OUT * 3;  // 80
constexpr int GPITCH = 96;                       // fp16 elems per gbuf row (192B)
constexpr float ISQRT3 = 0.57735026918962576f;
constexpr float ISQ48  = 0.14433756729740643f;   // 1/sqrt(48)

__device__ __forceinline__ float silu_f(float x) {
    return x / (1.0f + __expf(-x));
}

// ---------------------------------------------------------------------------
// CSR construction
// ---------------------------------------------------------------------------
__global__ __launch_bounds__(256) void hist_kernel(
    const int* __restrict__ edst, int* __restrict__ deg, int E)
{
    int e = blockIdx.x * 256 + threadIdx.x;
    if (e < E) atomicAdd(&deg[edst[e]], 1);
}

__global__ __launch_bounds__(1024) void scan_kernel(
    const int* __restrict__ deg, int* __restrict__ offs,
    int* __restrict__ cursor, int Nn)
{
    const int T = 1024;
    int t = threadIdx.x;
    int chunk = (Nn + T - 1) / T;
    int lo = t * chunk;
    int hi = lo + chunk; if (hi > Nn) hi = Nn;
    int s = 0;
    for (int i = lo; i < hi; i++) s += deg[i];
    __shared__ int ps[T];
    ps[t] = s;
    __syncthreads();
    for (int off = 1; off < T; off <<= 1) {
        int v = (t >= off) ? ps[t - off] : 0;
        __syncthreads();
        ps[t] += v;
        __syncthreads();
    }
    int base = (t > 0) ? ps[t - 1] : 0;
    for (int i = lo; i < hi; i++) {
        offs[i] = base;
        cursor[i] = base;
        base += deg[i];
    }
    if (t == 0) offs[Nn] = ps[T - 1];
}

__global__ __launch_bounds__(256) void scatter_kernel(
    const int* __restrict__ edst, int* __restrict__ cursor,
    int* __restrict__ perm, int E)
{
    int e = blockIdx.x * 256 + threadIdx.x;
    if (e < E) {
        int pos = atomicAdd(&cursor[edst[e]], 1);
        perm[pos] = e;
    }
}

// ---------------------------------------------------------------------------
// K1: per-edge MLP -> 96 gates (scaled), fp16, permuted order, pitch 96.
// ALL register-array loops fully unrolled (compile-time indices only).
// ---------------------------------------------------------------------------
__global__ __launch_bounds__(256, 2) void mlp_kernel(
    const int*   __restrict__ perm,
    const float* __restrict__ ecut,
    const float* __restrict__ einv,
    const float* __restrict__ W0,
    const float* __restrict__ W1,
    const float* __restrict__ W2,
    __half* __restrict__ gbuf,
    int p0, int p1)
{
    int p = p0 + blockIdx.x * 256 + threadIdx.x;
    if (p >= p1) return;
    int e = perm[p];

    constexpr float inv_s0 = 0.25f;   // 1/sqrt(16)
    constexpr float inv_s1 = 0.125f;  // 1/sqrt(64)

    float x[INVD];
    const float4* xin = reinterpret_cast<const float4*>(einv + (size_t)e * INVD);
    #pragma unroll
    for (int i = 0; i < 4; i++) {
        float4 t = xin[i];
        x[4*i+0] = t.x; x[4*i+1] = t.y; x[4*i+2] = t.z; x[4*i+3] = t.w;
    }

    float h1[64];
    #pragma unroll
    for (int j = 0; j < 64; j++) h1[j] = 0.0f;
    #pragma unroll
    for (int i = 0; i < INVD; i++) {
        float xi = x[i];
        #pragma unroll
        for (int j = 0; j < 64; j++)
            h1[j] = fmaf(xi, W0[i*64 + j], h1[j]);
    }
    #pragma unroll
    for (int j = 0; j < 64; j++) h1[j] = silu_f(h1[j] * inv_s0);

    float h2[64];
    #pragma unroll
    for (int j = 0; j < 64; j++) h2[j] = 0.0f;
    #pragma unroll
    for (int k = 0; k < 64; k++) {
        float hk = h1[k];
        #pragma unroll
        for (int j = 0; j < 64; j++)
            h2[j] = fmaf(hk, W1[k*64 + j], h2[j]);
    }
    #pragma unroll
    for (int j = 0; j < 64; j++) h2[j] = silu_f(h2[j] * inv_s1);

    float K = ecut[e] * inv_s1 * ISQ48;   // fold 1/sqrt(64), 1/sqrt(48)
    __half* grow = gbuf + (size_t)(p - p0) * GPITCH;

    #pragma unroll
    for (int cc = 0; cc < NFAC; cc += 16) {
        float fac[16];
        #pragma unroll
        for (int j = 0; j < 16; j++) fac[j] = 0.0f;
        #pragma unroll
        for (int k = 0; k < 64; k++) {
            float hk = h2[k];
            #pragma unroll
            for (int j = 0; j < 16; j++)
                fac[j] = fmaf(hk, W2[k*NFAC + cc + j], fac[j]);
        }
        float scale = (cc == 0) ? (K * ISQRT3) : K;   // cols 0..15 gate tp_s
        unsigned int w[8];
        #pragma unroll
        for (int q = 0; q < 8; q++) {
            __half2 hh = __floats2half2_rn(fac[2*q] * scale, fac[2*q+1] * scale);
            w[q] = *reinterpret_cast<unsigned int*>(&hh);
        }
        uint4* dst = reinterpret_cast<uint4*>(grow + cc);
        dst[0] = make_uint4(w[0], w[1], w[2], w[3]);
        dst[1] = make_uint4(w[4], w[5], w[6], w[7]);
    }
}

// ---------------------------------------------------------------------------
// K2: read gates (96 fp16), gather node features, apply WL, overwrite row
// in place with the 80-fp16 per-edge output contribution.
// ---------------------------------------------------------------------------
__global__ __launch_bounds__(256, 4) void wl_kernel(
    const int*   __restrict__ perm,
    const int*   __restrict__ esrc,
    const float* __restrict__ ns,
    const float* __restrict__ nv,
    const float* __restrict__ esh,
    const float* __restrict__ WLs,
    const float* __restrict__ WLv,
    __half* __restrict__ gbuf,
    int p0, int p1)
{
    int p = p0 + blockIdx.x * 256 + threadIdx.x;
    if (p >= p1) return;
    int e = perm[p];
    int s = esrc[e];

    float ev0 = esh[(size_t)e*3 + 0];
    float ev1 = esh[(size_t)e*3 + 1];
    float ev2 = esh[(size_t)e*3 + 2];
    const float* nsrow = ns + (size_t)s * S_IN;
    const float* nvrow = nv + (size_t)s * (V_IN * 3);
    __half* row = gbuf + (size_t)(p - p0) * GPITCH;
    uint4* row4 = reinterpret_cast<uint4*>(row);

    // ---- Phase B: scalar outputs ys[32] from fac[0:48] ----
    {
        unsigned int pw[24];                         // fac[0:48] = 48 fp16 = 24 u32
        #pragma unroll
        for (int q = 0; q < 6; q++) {                // row4[0..5] = elems 0..47
            uint4 t = row4[q];
            pw[4*q+0] = t.x; pw[4*q+1] = t.y; pw[4*q+2] = t.z; pw[4*q+3] = t.w;
        }
        float ys[S_OUT];
        #pragma unroll
        for (int o = 0; o < S_OUT; o++) ys[o] = 0.0f;

        #pragma unroll
        for (int c = 0; c < S_MSG; c += 2) {
            __half2 hh = *reinterpret_cast<const __half2*>(&pw[c >> 1]);
            float2 f2 = __half22float2(hh);
            float g0 = f2.x, g1 = f2.y;
            float m0, m1;
            if (c < V_IN) {            // pair fully inside tp_s region (0..15)
                m0 = (nvrow[3*c+0]*ev0 + nvrow[3*c+1]*ev1 + nvrow[3*c+2]*ev2) * g0;
                m1 = (nvrow[3*c+3]*ev0 + nvrow[3*c+4]*ev1 + nvrow[3*c+5]*ev2) * g1;
            } else {                   // src_s region (16..47)
                m0 = nsrow[c - V_IN]     * g0;
                m1 = nsrow[c - V_IN + 1] * g1;
            }
            #pragma unroll
            for (int o = 0; o < S_OUT; o++)
                ys[o] = fmaf(m0, WLs[c*S_OUT + o], ys[o]);
            #pragma unroll
            for (int o = 0; o < S_OUT; o++)
                ys[o] = fmaf(m1, WLs[(c+1)*S_OUT + o], ys[o]);
        }

        unsigned int w[16];
        #pragma unroll
        for (int q = 0; q < 16; q++) {
            __half2 hh = __floats2half2_rn(ys[2*q], ys[2*q+1]);
            w[q] = *reinterpret_cast<unsigned int*>(&hh);
        }
        #pragma unroll
        for (int q = 0; q < 4; q++)                  // writes elems 0..31 only
            row4[q] = make_uint4(w[4*q+0], w[4*q+1], w[4*q+2], w[4*q+3]);
    }

    // ---- Phase C: vector outputs yv[48] from fac[48:96] ----
    {
        unsigned int pw[24];                         // fac[48:96] = 48 fp16 = 24 u32
        #pragma unroll
        for (int q = 0; q < 6; q++) {                // row4[6..11] = elems 48..95
            uint4 t = row4[6 + q];
            pw[4*q+0] = t.x; pw[4*q+1] = t.y; pw[4*q+2] = t.z; pw[4*q+3] = t.w;
        }
        float yv[V_OUT * 3];
        #pragma unroll
        for (int q = 0; q < V_OUT*3; q++) yv[q] = 0.0f;

        #pragma unroll
        for (int c = 0; c < V_MSG; c += 2) {
            __half2 hh = *reinterpret_cast<const __half2*>(&pw[c >> 1]);
            float2 f2 = __half22float2(hh);
            float g0 = f2.x, g1 = f2.y;
            if (c < S_IN) {            // tp_v rows: ns[c] * ev
                float ma = nsrow[c]   * g0;
                float mb = nsrow[c+1] * g1;
                float a0 = ma*ev0, a1 = ma*ev1, a2 = ma*ev2;
                float b0 = mb*ev0, b1 = mb*ev1, b2 = mb*ev2;
                #pragma unroll
                for (int o = 0; o < V_OUT; o++) {
                    float wa = WLv[c*V_OUT + o];
                    float wb = WLv[(c+1)*V_OUT + o];
                    yv[3*o+0] = fmaf(wa, a0, fmaf(wb, b0, yv[3*o+0]));
                    yv[3*o+1] = fmaf(wa, a1, fmaf(wb, b1, yv[3*o+1]));
                    yv[3*o+2] = fmaf(wa, a2, fmaf(wb, b2, yv[3*o+2]));
                }
            } else {                   // src_v rows: nv row (c-32)
                int r0 = c - S_IN;
                float a0 = nvrow[3*r0+0]*g0, a1 = nvrow[3*r0+1]*g0, a2 = nvrow[3*r0+2]*g0;
                float b0 = nvrow[3*r0+3]*g1, b1 = nvrow[3*r0+4]*g1, b2 = nvrow[3*r0+5]*g1;
                #pragma unroll
                for (int o = 0; o < V_OUT; o++) {
                    float wa = WLv[c*V_OUT + o];
                    float wb = WLv[(c+1)*V_OUT + o];
                    yv[3*o+0] = fmaf(wa, a0, fmaf(wb, b0, yv[3*o+0]));
                    yv[3*o+1] = fmaf(wa, a1, fmaf(wb, b1, yv[3*o+1]));
                    yv[3*o+2] = fmaf(wa, a2, fmaf(wb, b2, yv[3*o+2]));
                }
            }
        }

        unsigned int w[24];
        #pragma unroll
        for (int q = 0; q < 24; q++) {
            __half2 hh = __floats2half2_rn(yv[2*q], yv[2*q+1]);
            w[q] = *reinterpret_cast<unsigned int*>(&hh);
        }
        #pragma unroll
        for (int q = 0; q < 6; q++)                  // writes elems 32..79
            row4[4 + q] = make_uint4(w[4*q+0], w[4*q+1], w[4*q+2], w[4*q+3]);
    }
}

// ---------------------------------------------------------------------------
// Gather: one wave per node, sum 80-elem fp16 rows (pitch 96) over the
// node's permuted range. Addresses depend only on p -> no dependent loads.
// ---------------------------------------------------------------------------
__global__ __launch_bounds__(256) void gather_sum(
    const int*    __restrict__ offs,
    const __half* __restrict__ gbuf,
    float* __restrict__ out,
    int Nn, int p0, int p1)
{
    int wid = (blockIdx.x * 256 + threadIdx.x) >> 6;   // node = global wave id
    int l = threadIdx.x & 63;
    if (wid >= Nn) return;
    int beg = offs[wid], end = offs[wid + 1];
    int lo = beg > p0 ? beg : p0;
    int hi = end < p1 ? end : p1;
    if (lo >= hi) return;

    float a0 = 0.0f, a1 = 0.0f;
    const __half* row = gbuf + (size_t)(lo - p0) * GPITCH;
    for (int p = lo; p < hi; ++p, row += GPITCH) {
        a0 += __half2float(row[l]);
        if (l < 16) a1 += __half2float(row[64 + l]);
    }
    float* orow = out + (size_t)wid * OUT_PER_NODE;
    orow[l] += a0;
    if (l < 16) orow[64 + l] += a1;
}

// ---------------------------------------------------------------------------
extern "C" void kernel_launch(void* const* d_in, const int* in_sizes, int n_in,
                              void* d_out, int out_size, void* d_ws, size_t ws_size,
                              hipStream_t stream) {
    const int*   esrc = (const int*)  d_in[0];
    const int*   edst = (const int*)  d_in[1];
    const float* ecut = (const float*)d_in[2];
    const float* einv = (const float*)d_in[3];
    const float* ns   = (const float*)d_in[4];
    const float* nv   = (const float*)d_in[5];
    const float* esh  = (const float*)d_in[6];
    const float* W0   = (const float*)d_in[7];
    const float* W1   = (const float*)d_in[8];
    const float* W2   = (const float*)d_in[9];
    const float* WLs  = (const float*)d_in[10];
    const float* WLv  = (const float*)d_in[11];
    float* out = (float*)d_out;

    const int E  = in_sizes[0];
    const int Nn = in_sizes[4] / S_IN;

    size_t int_bytes = (((size_t)(3 * Nn + 1 + E)) * sizeof(int) + 255) & ~(size_t)255;

    int eblocks = (E + 255) / 256;

    hipMemsetAsync(out, 0, (size_t)Nn * OUT_PER_NODE * sizeof(float), stream);

    int*    deg    = (int*)d_ws;
    int*    offs   = deg + Nn;          // Nn+1
    int*    cursor = offs + Nn + 1;     // Nn
    int*    perm   = cursor + Nn;       // E
    __half* gbuf   = (__half*)((char*)d_ws + int_bytes);

    size_t gbuf_avail = (ws_size > int_bytes) ? (ws_size - int_bytes) : 0;
    int chunkE = (int)(gbuf_avail / ((size_t)GPITCH * sizeof(__half)));
    if (chunkE > E) chunkE = E;

    if (chunkE >= 4096) {
        hipMemsetAsync(deg, 0, (size_t)Nn * sizeof(int), stream);
        hist_kernel<<<eblocks, 256, 0, stream>>>(edst, deg, E);
        scan_kernel<<<1, 1024, 0, stream>>>(deg, offs, cursor, Nn);
        scatter_kernel<<<eblocks, 256, 0, stream>>>(edst, cursor, perm, E);

        int gblocks = (Nn + 3) / 4;   // 4 waves (nodes) per 256-thread block
        for (int p0 = 0; p0 < E; p0 += chunkE) {
            int p1 = p0 + chunkE; if (p1 > E) p1 = E;
            int cblocks = (p1 - p0 + 255) / 256;
            mlp_kernel<<<cblocks, 256, 0, stream>>>(perm, ecut, einv,
                                                    W0, W1, W2, gbuf, p0, p1);
            wl_kernel<<<cblocks, 256, 0, stream>>>(perm, esrc, ns, nv, esh,
                                                   WLs, WLv, gbuf, p0, p1);
            gather_sum<<<gblocks, 256, 0, stream>>>(offs, gbuf, out, Nn, p0, p1);
        }
    }
}

// Round 8
// 899.335 us; speedup vs baseline: 1.3949x; 1.3949x over previous
//
#include <hip/hip_runtime.h>
#include <hip/hip_fp16.h>
#include <math.h>

// Problem constants
constexpr int S_IN = 32, V_IN = 16, INVD = 16;
constexpr int S_MSG = S_IN + V_IN;           // 48
constexpr int V_MSG = S_IN + V_IN;           // 48
constexpr int NFAC  = S_MSG + V_MSG;         // 96
constexpr int S_OUT = 32, V_OUT = 16;
constexpr int OUT_PER_NODE = S_OUT + V_OUT * 3;  // 80
constexpr int GPITCH = 96;                       // fp16 elems per gbuf row (192B)
constexpr float ISQRT3 = 0.57735026918962576f;
constexpr float ISQ48  = 0.14433756729740643f;   // 1/sqrt(48)

typedef __attribute__((ext_vector_type(8))) short bf16x8;
typedef __attribute__((ext_vector_type(4))) float f32x4;

__device__ __forceinline__ float silu_f(float x) {
    return x / (1.0f + __expf(-x));
}
__device__ __forceinline__ unsigned short f2bf(float f) {
    unsigned int u = __float_as_uint(f);
    u += 0x7FFFu + ((u >> 16) & 1u);         // round-to-nearest-even
    return (unsigned short)(u >> 16);
}

// ---------------------------------------------------------------------------
// CSR construction
// ---------------------------------------------------------------------------
__global__ __launch_bounds__(256) void hist_kernel(
    const int* __restrict__ edst, int* __restrict__ deg, int E)
{
    int e = blockIdx.x * 256 + threadIdx.x;
    if (e < E) atomicAdd(&deg[edst[e]], 1);
}

__global__ __launch_bounds__(1024) void scan_kernel(
    const int* __restrict__ deg, int* __restrict__ offs,
    int* __restrict__ cursor, int Nn)
{
    const int T = 1024;
    int t = threadIdx.x;
    int chunk = (Nn + T - 1) / T;
    int lo = t * chunk;
    int hi = lo + chunk; if (hi > Nn) hi = Nn;
    int s = 0;
    for (int i = lo; i < hi; i++) s += deg[i];
    __shared__ int ps[T];
    ps[t] = s;
    __syncthreads();
    for (int off = 1; off < T; off <<= 1) {
        int v = (t >= off) ? ps[t - off] : 0;
        __syncthreads();
        ps[t] += v;
        __syncthreads();
    }
    int base = (t > 0) ? ps[t - 1] : 0;
    for (int i = lo; i < hi; i++) {
        offs[i] = base;
        cursor[i] = base;
        base += deg[i];
    }
    if (t == 0) offs[Nn] = ps[T - 1];
}

__global__ __launch_bounds__(256) void scatter_kernel(
    const int* __restrict__ edst, int* __restrict__ cursor,
    int* __restrict__ perm, int E)
{
    int e = blockIdx.x * 256 + threadIdx.x;
    if (e < E) {
        int pos = atomicAdd(&cursor[edst[e]], 1);
        perm[pos] = e;
    }
}

// ---------------------------------------------------------------------------
// K1 (MFMA): per-edge MLP -> 96 gates (scaled) fp16, permuted order.
// Block = 128 edges, 4 waves x 32 edges. All GEMMs via mfma_f32_16x16x32_bf16.
// A = W^T[j][k] (K-contiguous LDS, padded stride), B = act[edge][k]
// (K-contiguous LDS, stride 72 shorts = 144B). D[j][edge]: col=lane&15(edge),
// row=(lane>>4)*4+reg (j) -> epilogue writes 4 consecutive k of next act row.
// ---------------------------------------------------------------------------
__global__ __launch_bounds__(256) void mlp_mfma(
    const int*   __restrict__ perm,
    const float* __restrict__ ecut,
    const float* __restrict__ einv,
    const float* __restrict__ W0,
    const float* __restrict__ W1,
    const float* __restrict__ W2,
    __half* __restrict__ gbuf,
    int p0, int p1)
{
    __shared__ unsigned short sW0T[64 * 40];   // [j][k pad40], k<16 real
    __shared__ unsigned short sW1T[64 * 72];   // [j][k pad72], k<64 real
    __shared__ unsigned short act0[128 * 72];  // X (k<32: 16 real + zeros), later h2
    __shared__ unsigned short act1[128 * 72];  // h1; later W2T [96][72]
    __shared__ float scuts[128];

    const int tid = threadIdx.x;
    const int pbase = p0 + blockIdx.x * 128;

    // ---- stage W0T, W1T (transposed, bf16, zero-padded K) ----
    for (int i = tid; i < 64 * 40; i += 256) {
        int j = i / 40, k = i - 40 * j;
        sW0T[i] = (k < INVD) ? f2bf(W0[k * 64 + j]) : (unsigned short)0;
    }
    for (int i = tid; i < 64 * 72; i += 256) {
        int j = i / 72, k = i - 72 * j;
        sW1T[i] = (k < 64) ? f2bf(W1[k * 64 + j]) : (unsigned short)0;
    }

    // ---- stage X: 128 edges, 16 feats -> bf16, zeros k 16..31 ----
    if (tid < 128) {
        int p = pbase + tid;
        unsigned short* row = &act0[tid * 72];
        unsigned int pk[8];
        float cw = 0.0f;
        if (p < p1) {
            int e = perm[p];
            const float4* xin = reinterpret_cast<const float4*>(einv + (size_t)e * INVD);
            #pragma unroll
            for (int q = 0; q < 4; q++) {
                float4 v = xin[q];
                pk[2*q+0] = (unsigned int)f2bf(v.x) | ((unsigned int)f2bf(v.y) << 16);
                pk[2*q+1] = (unsigned int)f2bf(v.z) | ((unsigned int)f2bf(v.w) << 16);
            }
            cw = ecut[e];
        } else {
            #pragma unroll
            for (int q = 0; q < 8; q++) pk[q] = 0u;
        }
        uint4* r4 = reinterpret_cast<uint4*>(row);
        r4[0] = make_uint4(pk[0], pk[1], pk[2], pk[3]);
        r4[1] = make_uint4(pk[4], pk[5], pk[6], pk[7]);
        r4[2] = make_uint4(0u, 0u, 0u, 0u);        // k 16..23 zero
        r4[3] = make_uint4(0u, 0u, 0u, 0u);        // k 24..31 zero
        scuts[tid] = cw;
    }
    __syncthreads();

    const int lane = tid & 63;
    const int w    = tid >> 6;
    const int lr   = lane & 15;        // A: j-within-tile | B/D: edge-within-tile
    const int lg   = lane >> 4;        // k-slot group / D row group
    const int e0   = w * 32 + lr;      // et=0 edge row (block-local)
    const int e1   = w * 32 + 16 + lr; // et=1

    const f32x4 zero4 = {0.f, 0.f, 0.f, 0.f};

    // ---- Layer 1: h1 = silu((X @ W0) / 4), K=32 ----
    {
        bf16x8 b0 = *(const bf16x8*)&act0[e0 * 72 + lg * 8];
        bf16x8 b1 = *(const bf16x8*)&act0[e1 * 72 + lg * 8];
        #pragma unroll
        for (int jt = 0; jt < 4; jt++) {
            bf16x8 a = *(const bf16x8*)&sW0T[(jt * 16 + lr) * 40 + lg * 8];
            f32x4 d0 = __builtin_amdgcn_mfma_f32_16x16x32_bf16(a, b0, zero4, 0, 0, 0);
            f32x4 d1 = __builtin_amdgcn_mfma_f32_16x16x32_bf16(a, b1, zero4, 0, 0, 0);
            unsigned int u0, u1;
            u0 = (unsigned int)f2bf(silu_f(d0[0] * 0.25f)) | ((unsigned int)f2bf(silu_f(d0[1] * 0.25f)) << 16);
            u1 = (unsigned int)f2bf(silu_f(d0[2] * 0.25f)) | ((unsigned int)f2bf(silu_f(d0[3] * 0.25f)) << 16);
            *(uint2*)&act1[e0 * 72 + jt * 16 + lg * 4] = make_uint2(u0, u1);
            u0 = (unsigned int)f2bf(silu_f(d1[0] * 0.25f)) | ((unsigned int)f2bf(silu_f(d1[1] * 0.25f)) << 16);
            u1 = (unsigned int)f2bf(silu_f(d1[2] * 0.25f)) | ((unsigned int)f2bf(silu_f(d1[3] * 0.25f)) << 16);
            *(uint2*)&act1[e1 * 72 + jt * 16 + lg * 4] = make_uint2(u0, u1);
        }
    }

    // ---- Layer 2: h2 = silu((h1 @ W1) / 8), K=64 (wave-local, no barrier) ----
    {
        bf16x8 b00 = *(const bf16x8*)&act1[e0 * 72 +      lg * 8];
        bf16x8 b01 = *(const bf16x8*)&act1[e0 * 72 + 32 + lg * 8];
        bf16x8 b10 = *(const bf16x8*)&act1[e1 * 72 +      lg * 8];
        bf16x8 b11 = *(const bf16x8*)&act1[e1 * 72 + 32 + lg * 8];
        #pragma unroll
        for (int jt = 0; jt < 4; jt++) {
            bf16x8 a0 = *(const bf16x8*)&sW1T[(jt * 16 + lr) * 72 +      lg * 8];
            bf16x8 a1 = *(const bf16x8*)&sW1T[(jt * 16 + lr) * 72 + 32 + lg * 8];
            f32x4 d0 = __builtin_amdgcn_mfma_f32_16x16x32_bf16(a0, b00, zero4, 0, 0, 0);
            d0 = __builtin_amdgcn_mfma_f32_16x16x32_bf16(a1, b01, d0, 0, 0, 0);
            f32x4 d1 = __builtin_amdgcn_mfma_f32_16x16x32_bf16(a0, b10, zero4, 0, 0, 0);
            d1 = __builtin_amdgcn_mfma_f32_16x16x32_bf16(a1, b11, d1, 0, 0, 0);
            unsigned int u0, u1;
            u0 = (unsigned int)f2bf(silu_f(d0[0] * 0.125f)) | ((unsigned int)f2bf(silu_f(d0[1] * 0.125f)) << 16);
            u1 = (unsigned int)f2bf(silu_f(d0[2] * 0.125f)) | ((unsigned int)f2bf(silu_f(d0[3] * 0.125f)) << 16);
            *(uint2*)&act0[e0 * 72 + jt * 16 + lg * 4] = make_uint2(u0, u1);
            u0 = (unsigned int)f2bf(silu_f(d1[0] * 0.125f)) | ((unsigned int)f2bf(silu_f(d1[1] * 0.125f)) << 16);
            u1 = (unsigned int)f2bf(silu_f(d1[2] * 0.125f)) | ((unsigned int)f2bf(silu_f(d1[3] * 0.125f)) << 16);
            *(uint2*)&act0[e1 * 72 + jt * 16 + lg * 4] = make_uint2(u0, u1);
        }
    }

    // ---- stage W2T into act1 (h1 is dead); needs all waves done with act1 ----
    __syncthreads();
    for (int i = tid; i < 96 * 72; i += 256) {
        int j = i / 72, k = i - 72 * j;
        act1[i] = (k < 64) ? f2bf(W2[k * 96 + j]) : (unsigned short)0;
    }
    __syncthreads();

    // ---- Layer 3: fac = (h2 @ W2) / 8, scale by cw/sqrt48 (+1/sqrt3 for j<16),
    //      convert fp16, store to gbuf rows (pitch 96) ----
    {
        bf16x8 b00 = *(const bf16x8*)&act0[e0 * 72 +      lg * 8];
        bf16x8 b01 = *(const bf16x8*)&act0[e0 * 72 + 32 + lg * 8];
        bf16x8 b10 = *(const bf16x8*)&act0[e1 * 72 +      lg * 8];
        bf16x8 b11 = *(const bf16x8*)&act0[e1 * 72 + 32 + lg * 8];
        float K0 = scuts[w * 32 + lr]      * 0.125f * ISQ48;
        float K1 = scuts[w * 32 + 16 + lr] * 0.125f * ISQ48;
        int prow0 = pbase + w * 32 + lr;
        int prow1 = pbase + w * 32 + 16 + lr;
        #pragma unroll
        for (int jt = 0; jt < 6; jt++) {
            bf16x8 a0 = *(const bf16x8*)&act1[(jt * 16 + lr) * 72 +      lg * 8];
            bf16x8 a1 = *(const bf16x8*)&act1[(jt * 16 + lr) * 72 + 32 + lg * 8];
            f32x4 d0 = __builtin_amdgcn_mfma_f32_16x16x32_bf16(a0, b00, zero4, 0, 0, 0);
            d0 = __builtin_amdgcn_mfma_f32_16x16x32_bf16(a1, b01, d0, 0, 0, 0);
            f32x4 d1 = __builtin_amdgcn_mfma_f32_16x16x32_bf16(a0, b10, zero4, 0, 0, 0);
            d1 = __builtin_amdgcn_mfma_f32_16x16x32_bf16(a1, b11, d1, 0, 0, 0);
            float s0 = (jt == 0) ? K0 * ISQRT3 : K0;
            float s1 = (jt == 0) ? K1 * ISQRT3 : K1;
            if (prow0 < p1) {
                __half2 ha = __floats2half2_rn(d0[0] * s0, d0[1] * s0);
                __half2 hb = __floats2half2_rn(d0[2] * s0, d0[3] * s0);
                uint2 v = make_uint2(*(unsigned int*)&ha, *(unsigned int*)&hb);
                *(uint2*)(gbuf + (size_t)(prow0 - p0) * GPITCH + jt * 16 + lg * 4) = v;
            }
            if (prow1 < p1) {
                __half2 ha = __floats2half2_rn(d1[0] * s1, d1[1] * s1);
                __half2 hb = __floats2half2_rn(d1[2] * s1, d1[3] * s1);
                uint2 v = make_uint2(*(unsigned int*)&ha, *(unsigned int*)&hb);
                *(uint2*)(gbuf + (size_t)(prow1 - p0) * GPITCH + jt * 16 + lg * 4) = v;
            }
        }
    }
}

// ---------------------------------------------------------------------------
// K2: read gates (96 fp16), gather node features, apply WL, overwrite row
// in place with the 80-fp16 per-edge output contribution.
// ---------------------------------------------------------------------------
__global__ __launch_bounds__(256, 4) void wl_kernel(
    const int*   __restrict__ perm,
    const int*   __restrict__ esrc,
    const float* __restrict__ ns,
    const float* __restrict__ nv,
    const float* __restrict__ esh,
    const float* __restrict__ WLs,
    const float* __restrict__ WLv,
    __half* __restrict__ gbuf,
    int p0, int p1)
{
    int p = p0 + blockIdx.x * 256 + threadIdx.x;
    if (p >= p1) return;
    int e = perm[p];
    int s = esrc[e];

    float ev0 = esh[(size_t)e*3 + 0];
    float ev1 = esh[(size_t)e*3 + 1];
    float ev2 = esh[(size_t)e*3 + 2];
    const float* nsrow = ns + (size_t)s * S_IN;
    const float* nvrow = nv + (size_t)s * (V_IN * 3);
    __half* row = gbuf + (size_t)(p - p0) * GPITCH;
    uint4* row4 = reinterpret_cast<uint4*>(row);

    // ---- Phase B: scalar outputs ys[32] from fac[0:48] ----
    {
        unsigned int pw[24];
        #pragma unroll
        for (int q = 0; q < 6; q++) {
            uint4 t = row4[q];
            pw[4*q+0] = t.x; pw[4*q+1] = t.y; pw[4*q+2] = t.z; pw[4*q+3] = t.w;
        }
        float ys[S_OUT];
        #pragma unroll
        for (int o = 0; o < S_OUT; o++) ys[o] = 0.0f;

        #pragma unroll
        for (int c = 0; c < S_MSG; c += 2) {
            __half2 hh = *reinterpret_cast<const __half2*>(&pw[c >> 1]);
            float2 f2 = __half22float2(hh);
            float g0 = f2.x, g1 = f2.y;
            float m0, m1;
            if (c < V_IN) {
                m0 = (nvrow[3*c+0]*ev0 + nvrow[3*c+1]*ev1 + nvrow[3*c+2]*ev2) * g0;
                m1 = (nvrow[3*c+3]*ev0 + nvrow[3*c+4]*ev1 + nvrow[3*c+5]*ev2) * g1;
            } else {
                m0 = nsrow[c - V_IN]     * g0;
                m1 = nsrow[c - V_IN + 1] * g1;
            }
            #pragma unroll
            for (int o = 0; o < S_OUT; o++)
                ys[o] = fmaf(m0, WLs[c*S_OUT + o], ys[o]);
            #pragma unroll
            for (int o = 0; o < S_OUT; o++)
                ys[o] = fmaf(m1, WLs[(c+1)*S_OUT + o], ys[o]);
        }

        unsigned int w[16];
        #pragma unroll
        for (int q = 0; q < 16; q++) {
            __half2 hh = __floats2half2_rn(ys[2*q], ys[2*q+1]);
            w[q] = *reinterpret_cast<unsigned int*>(&hh);
        }
        #pragma unroll
        for (int q = 0; q < 4; q++)
            row4[q] = make_uint4(w[4*q+0], w[4*q+1], w[4*q+2], w[4*q+3]);
    }

    // ---- Phase C: vector outputs yv[48] from fac[48:96] ----
    {
        unsigned int pw[24];
        #pragma unroll
        for (int q = 0; q < 6; q++) {
            uint4 t = row4[6 + q];
            pw[4*q+0] = t.x; pw[4*q+1] = t.y; pw[4*q+2] = t.z; pw[4*q+3] = t.w;
        }
        float yv[V_OUT * 3];
        #pragma unroll
        for (int q = 0; q < V_OUT*3; q++) yv[q] = 0.0f;

        #pragma unroll
        for (int c = 0; c < V_MSG; c += 2) {
            __half2 hh = *reinterpret_cast<const __half2*>(&pw[c >> 1]);
            float2 f2 = __half22float2(hh);
            float g0 = f2.x, g1 = f2.y;
            if (c < S_IN) {
                float ma = nsrow[c]   * g0;
                float mb = nsrow[c+1] * g1;
                float a0 = ma*ev0, a1 = ma*ev1, a2 = ma*ev2;
                float b0 = mb*ev0, b1 = mb*ev1, b2 = mb*ev2;
                #pragma unroll
                for (int o = 0; o < V_OUT; o++) {
                    float wa = WLv[c*V_OUT + o];
                    float wb = WLv[(c+1)*V_OUT + o];
                    yv[3*o+0] = fmaf(wa, a0, fmaf(wb, b0, yv[3*o+0]));
                    yv[3*o+1] = fmaf(wa, a1, fmaf(wb, b1, yv[3*o+1]));
                    yv[3*o+2] = fmaf(wa, a2, fmaf(wb, b2, yv[3*o+2]));
                }
            } else {
                int r0 = c - S_IN;
                float a0 = nvrow[3*r0+0]*g0, a1 = nvrow[3*r0+1]*g0, a2 = nvrow[3*r0+2]*g0;
                float b0 = nvrow[3*r0+3]*g1, b1 = nvrow[3*r0+4]*g1, b2 = nvrow[3*r0+5]*g1;
                #pragma unroll
                for (int o = 0; o < V_OUT; o++) {
                    float wa = WLv[c*V_OUT + o];
                    float wb = WLv[(c+1)*V_OUT + o];
                    yv[3*o+0] = fmaf(wa, a0, fmaf(wb, b0, yv[3*o+0]));
                    yv[3*o+1] = fmaf(wa, a1, fmaf(wb, b1, yv[3*o+1]));
                    yv[3*o+2] = fmaf(wa, a2, fmaf(wb, b2, yv[3*o+2]));
                }
            }
        }

        unsigned int w[24];
        #pragma unroll
        for (int q = 0; q < 24; q++) {
            __half2 hh = __floats2half2_rn(yv[2*q], yv[2*q+1]);
            w[q] = *reinterpret_cast<unsigned int*>(&hh);
        }
        #pragma unroll
        for (int q = 0; q < 6; q++)
            row4[4 + q] = make_uint4(w[4*q+0], w[4*q+1], w[4*q+2], w[4*q+3]);
    }
}

// ---------------------------------------------------------------------------
// Gather: one wave per node, sum 80-elem fp16 rows (pitch 96).
// ---------------------------------------------------------------------------
__global__ __launch_bounds__(256) void gather_sum(
    const int*    __restrict__ offs,
    const __half* __restrict__ gbuf,
    float* __restrict__ out,
    int Nn, int p0, int p1)
{
    int wid = (blockIdx.x * 256 + threadIdx.x) >> 6;
    int l = threadIdx.x & 63;
    if (wid >= Nn) return;
    int beg = offs[wid], end = offs[wid + 1];
    int lo = beg > p0 ? beg : p0;
    int hi = end < p1 ? end : p1;
    if (lo >= hi) return;

    float a0 = 0.0f, a1 = 0.0f;
    const __half* row = gbuf + (size_t)(lo - p0) * GPITCH;
    for (int p = lo; p < hi; ++p, row += GPITCH) {
        a0 += __half2float(row[l]);
        if (l < 16) a1 += __half2float(row[64 + l]);
    }
    float* orow = out + (size_t)wid * OUT_PER_NODE;
    orow[l] += a0;
    if (l < 16) orow[64 + l] += a1;
}

// ---------------------------------------------------------------------------
extern "C" void kernel_launch(void* const* d_in, const int* in_sizes, int n_in,
                              void* d_out, int out_size, void* d_ws, size_t ws_size,
                              hipStream_t stream) {
    const int*   esrc = (const int*)  d_in[0];
    const int*   edst = (const int*)  d_in[1];
    const float* ecut = (const float*)d_in[2];
    const float* einv = (const float*)d_in[3];
    const float* ns   = (const float*)d_in[4];
    const float* nv   = (const float*)d_in[5];
    const float* esh  = (const float*)d_in[6];
    const float* W0   = (const float*)d_in[7];
    const float* W1   = (const float*)d_in[8];
    const float* W2   = (const float*)d_in[9];
    const float* WLs  = (const float*)d_in[10];
    const float* WLv  = (const float*)d_in[11];
    float* out = (float*)d_out;

    const int E  = in_sizes[0];
    const int Nn = in_sizes[4] / S_IN;

    size_t int_bytes = (((size_t)(3 * Nn + 1 + E)) * sizeof(int) + 255) & ~(size_t)255;

    int eblocks = (E + 255) / 256;

    hipMemsetAsync(out, 0, (size_t)Nn * OUT_PER_NODE * sizeof(float), stream);

    int*    deg    = (int*)d_ws;
    int*    offs   = deg + Nn;          // Nn+1
    int*    cursor = offs + Nn + 1;     // Nn
    int*    perm   = cursor + Nn;       // E
    __half* gbuf   = (__half*)((char*)d_ws + int_bytes);

    size_t gbuf_avail = (ws_size > int_bytes) ? (ws_size - int_bytes) : 0;
    int chunkE = (int)(gbuf_avail / ((size_t)GPITCH * sizeof(__half)));
    if (chunkE > E) chunkE = E;

    if (chunkE >= 4096) {
        hipMemsetAsync(deg, 0, (size_t)Nn * sizeof(int), stream);
        hist_kernel<<<eblocks, 256, 0, stream>>>(edst, deg, E);
        scan_kernel<<<1, 1024, 0, stream>>>(deg, offs, cursor, Nn);
        scatter_kernel<<<eblocks, 256, 0, stream>>>(edst, cursor, perm, E);

        int gblocks = (Nn + 3) / 4;
        for (int p0 = 0; p0 < E; p0 += chunkE) {
            int p1 = p0 + chunkE; if (p1 > E) p1 = E;
            int n = p1 - p0;
            int mblocks = (n + 127) / 128;
            int cblocks = (n + 255) / 256;
            mlp_mfma<<<mblocks, 256, 0, stream>>>(perm, ecut, einv,
                                                  W0, W1, W2, gbuf, p0, p1);
            wl_kernel<<<cblocks, 256, 0, stream>>>(perm, esrc, ns, nv, esh,
                                                   WLs, WLv, gbuf, p0, p1);
            gather_sum<<<gblocks, 256, 0, stream>>>(offs, gbuf, out, Nn, p0, p1);
        }
    }
}

// Round 9
// 631.557 us; speedup vs baseline: 1.9863x; 1.4240x over previous
//
#include <hip/hip_runtime.h>
#include <hip/hip_fp16.h>
#include <hip/hip_bf16.h>
#include <math.h>

// Problem constants
constexpr int S_IN = 32, V_IN = 16, INVD = 16;
constexpr int S_MSG = S_IN + V_IN;           // 48
constexpr int V_MSG = S_IN + V_IN;           // 48
constexpr int NFAC  = S_MSG + V_MSG;         // 96
constexpr int S_OUT = 32, V_OUT = 16;
constexpr int OUT_PER_NODE = S_OUT + V_OUT * 3;  // 80
constexpr int CPITCH = 80;                       // fp16 elems per contribution row (160B)
constexpr float ISQRT3 = 0.57735026918962576f;
constexpr float ISQ48  = 0.14433756729740643f;   // 1/sqrt(48)

typedef __attribute__((ext_vector_type(8))) short bf16x8;
typedef __attribute__((ext_vector_type(4))) float f32x4;

__device__ __forceinline__ float silu_f(float x) {
    return x / (1.0f + __expf(-x));
}
__device__ __forceinline__ unsigned short f2bf(float f) {
    unsigned int u = __float_as_uint(f);
    u += 0x7FFFu + ((u >> 16) & 1u);         // round-to-nearest-even
    return (unsigned short)(u >> 16);
}
__device__ __forceinline__ float bf2f(unsigned short h) {
    unsigned int u = ((unsigned int)h) << 16;
    return __uint_as_float(u);
}

// ---------------------------------------------------------------------------
// CSR construction
// ---------------------------------------------------------------------------
__global__ __launch_bounds__(256) void hist_kernel(
    const int* __restrict__ edst, int* __restrict__ deg, int E)
{
    int e = blockIdx.x * 256 + threadIdx.x;
    if (e < E) atomicAdd(&deg[edst[e]], 1);
}

__global__ __launch_bounds__(1024) void scan_kernel(
    const int* __restrict__ deg, int* __restrict__ offs,
    int* __restrict__ cursor, int Nn)
{
    const int T = 1024;
    int t = threadIdx.x;
    int chunk = (Nn + T - 1) / T;
    int lo = t * chunk;
    int hi = lo + chunk; if (hi > Nn) hi = Nn;
    int s = 0;
    for (int i = lo; i < hi; i++) s += deg[i];
    __shared__ int ps[T];
    ps[t] = s;
    __syncthreads();
    for (int off = 1; off < T; off <<= 1) {
        int v = (t >= off) ? ps[t - off] : 0;
        __syncthreads();
        ps[t] += v;
        __syncthreads();
    }
    int base = (t > 0) ? ps[t - 1] : 0;
    for (int i = lo; i < hi; i++) {
        offs[i] = base;
        cursor[i] = base;
        base += deg[i];
    }
    if (t == 0) offs[Nn] = ps[T - 1];
}

__global__ __launch_bounds__(256) void scatter_kernel(
    const int* __restrict__ edst, int* __restrict__ cursor,
    int* __restrict__ perm, int E)
{
    int e = blockIdx.x * 256 + threadIdx.x;
    if (e < E) {
        int pos = atomicAdd(&cursor[edst[e]], 1);
        perm[pos] = e;
    }
}

// ---------------------------------------------------------------------------
// MEGA kernel: MLP (3 MFMA GEMMs) -> gates in regs -> gated messages in LDS
// -> WL (4 MFMA GEMMs) -> 80-fp16 contribution rows, dst-permuted order.
// Block = 128 edges, 4 waves x 32 edges.
// ---------------------------------------------------------------------------
__global__ __launch_bounds__(256, 2) void edge_mega(
    const int*   __restrict__ perm,
    const int*   __restrict__ esrc,
    const float* __restrict__ ecut,
    const float* __restrict__ einv,
    const float* __restrict__ ns,
    const float* __restrict__ nv,
    const float* __restrict__ esh,
    const float* __restrict__ W0,
    const float* __restrict__ W1,
    const float* __restrict__ W2,
    const float* __restrict__ WLs,
    const float* __restrict__ WLv,
    __half* __restrict__ cont,
    int p0, int p1)
{
    __shared__ __align__(16) unsigned char smem[53760];
    __shared__ float sev[128 * 3];
    __shared__ float scuts[128];

    unsigned short* sW0T = (unsigned short*)(smem + 0);      // [64][40]
    unsigned short* sW1T = (unsigned short*)(smem + 5120);   // [64][72]
    unsigned short* act0 = (unsigned short*)(smem + 14336);  // [128][72]
    unsigned short* act1 = (unsigned short*)(smem + 32768);  // [128][72]
    unsigned short* sWLT = (unsigned short*)(smem + 5120);   // [48][72] (phase B)
    unsigned short* M    = (unsigned short*)(smem + 14336);  // [128][72] (phase B)
    unsigned short* Fns  = (unsigned short*)(smem + 32768);  // [128][33] (phase B)
    unsigned short* Fnv  = (unsigned short*)(smem + 41216);  // [128][49] (phase B)

    const int tid = threadIdx.x;
    const int pbase = p0 + blockIdx.x * 128;

    // ---- phase 1: stage W0T, W1T, X, cuts ----
    for (int i = tid; i < 64 * 40; i += 256) {
        int j = i / 40, k = i - 40 * j;
        sW0T[i] = (k < INVD) ? f2bf(W0[k * 64 + j]) : (unsigned short)0;
    }
    for (int i = tid; i < 64 * 72; i += 256) {
        int j = i / 72, k = i - 72 * j;
        sW1T[i] = (k < 64) ? f2bf(W1[k * 64 + j]) : (unsigned short)0;
    }
    if (tid < 128) {
        int p = pbase + tid;
        unsigned short* row = &act0[tid * 72];
        unsigned int pk[8];
        float cw = 0.0f;
        if (p < p1) {
            int e = perm[p];
            const float4* xin = reinterpret_cast<const float4*>(einv + (size_t)e * INVD);
            #pragma unroll
            for (int q = 0; q < 4; q++) {
                float4 v = xin[q];
                pk[2*q+0] = (unsigned int)f2bf(v.x) | ((unsigned int)f2bf(v.y) << 16);
                pk[2*q+1] = (unsigned int)f2bf(v.z) | ((unsigned int)f2bf(v.w) << 16);
            }
            cw = ecut[e];
        } else {
            #pragma unroll
            for (int q = 0; q < 8; q++) pk[q] = 0u;
        }
        uint4* r4 = reinterpret_cast<uint4*>(row);
        r4[0] = make_uint4(pk[0], pk[1], pk[2], pk[3]);
        r4[1] = make_uint4(pk[4], pk[5], pk[6], pk[7]);
        r4[2] = make_uint4(0u, 0u, 0u, 0u);
        r4[3] = make_uint4(0u, 0u, 0u, 0u);
        scuts[tid] = cw;
    }
    __syncthreads();

    const int lane = tid & 63;
    const int w    = tid >> 6;
    const int lr   = lane & 15;
    const int lg   = lane >> 4;
    const int eb0  = w * 32 + lr;
    const int eb1  = eb0 + 16;

    const f32x4 zero4 = {0.f, 0.f, 0.f, 0.f};

    // ---- Layer 1 ----
    {
        bf16x8 b0 = *(const bf16x8*)&act0[eb0 * 72 + lg * 8];
        bf16x8 b1 = *(const bf16x8*)&act0[eb1 * 72 + lg * 8];
        #pragma unroll
        for (int jt = 0; jt < 4; jt++) {
            bf16x8 a = *(const bf16x8*)&sW0T[(jt * 16 + lr) * 40 + lg * 8];
            f32x4 d0 = __builtin_amdgcn_mfma_f32_16x16x32_bf16(a, b0, zero4, 0, 0, 0);
            f32x4 d1 = __builtin_amdgcn_mfma_f32_16x16x32_bf16(a, b1, zero4, 0, 0, 0);
            unsigned int u0, u1;
            u0 = (unsigned int)f2bf(silu_f(d0[0] * 0.25f)) | ((unsigned int)f2bf(silu_f(d0[1] * 0.25f)) << 16);
            u1 = (unsigned int)f2bf(silu_f(d0[2] * 0.25f)) | ((unsigned int)f2bf(silu_f(d0[3] * 0.25f)) << 16);
            *(uint2*)&act1[eb0 * 72 + jt * 16 + lg * 4] = make_uint2(u0, u1);
            u0 = (unsigned int)f2bf(silu_f(d1[0] * 0.25f)) | ((unsigned int)f2bf(silu_f(d1[1] * 0.25f)) << 16);
            u1 = (unsigned int)f2bf(silu_f(d1[2] * 0.25f)) | ((unsigned int)f2bf(silu_f(d1[3] * 0.25f)) << 16);
            *(uint2*)&act1[eb1 * 72 + jt * 16 + lg * 4] = make_uint2(u0, u1);
        }
    }

    // ---- Layer 2 ----
    {
        bf16x8 b00 = *(const bf16x8*)&act1[eb0 * 72 +      lg * 8];
        bf16x8 b01 = *(const bf16x8*)&act1[eb0 * 72 + 32 + lg * 8];
        bf16x8 b10 = *(const bf16x8*)&act1[eb1 * 72 +      lg * 8];
        bf16x8 b11 = *(const bf16x8*)&act1[eb1 * 72 + 32 + lg * 8];
        #pragma unroll
        for (int jt = 0; jt < 4; jt++) {
            bf16x8 a0 = *(const bf16x8*)&sW1T[(jt * 16 + lr) * 72 +      lg * 8];
            bf16x8 a1 = *(const bf16x8*)&sW1T[(jt * 16 + lr) * 72 + 32 + lg * 8];
            f32x4 d0 = __builtin_amdgcn_mfma_f32_16x16x32_bf16(a0, b00, zero4, 0, 0, 0);
            d0 = __builtin_amdgcn_mfma_f32_16x16x32_bf16(a1, b01, d0, 0, 0, 0);
            f32x4 d1 = __builtin_amdgcn_mfma_f32_16x16x32_bf16(a0, b10, zero4, 0, 0, 0);
            d1 = __builtin_amdgcn_mfma_f32_16x16x32_bf16(a1, b11, d1, 0, 0, 0);
            unsigned int u0, u1;
            u0 = (unsigned int)f2bf(silu_f(d0[0] * 0.125f)) | ((unsigned int)f2bf(silu_f(d0[1] * 0.125f)) << 16);
            u1 = (unsigned int)f2bf(silu_f(d0[2] * 0.125f)) | ((unsigned int)f2bf(silu_f(d0[3] * 0.125f)) << 16);
            *(uint2*)&act0[eb0 * 72 + jt * 16 + lg * 4] = make_uint2(u0, u1);
            u0 = (unsigned int)f2bf(silu_f(d1[0] * 0.125f)) | ((unsigned int)f2bf(silu_f(d1[1] * 0.125f)) << 16);
            u1 = (unsigned int)f2bf(silu_f(d1[2] * 0.125f)) | ((unsigned int)f2bf(silu_f(d1[3] * 0.125f)) << 16);
            *(uint2*)&act0[eb1 * 72 + jt * 16 + lg * 4] = make_uint2(u0, u1);
        }
    }

    // ---- stage W2T into act1 ----
    __syncthreads();
    for (int i = tid; i < 96 * 72; i += 256) {
        int j = i / 72, k = i - 72 * j;
        act1[i] = (k < 64) ? f2bf(W2[k * 96 + j]) : (unsigned short)0;
    }
    __syncthreads();

    // ---- Layer 3: fac -> registers (all scales folded) ----
    float fac0[6][4], fac1[6][4];
    {
        bf16x8 b00 = *(const bf16x8*)&act0[eb0 * 72 +      lg * 8];
        bf16x8 b01 = *(const bf16x8*)&act0[eb0 * 72 + 32 + lg * 8];
        bf16x8 b10 = *(const bf16x8*)&act0[eb1 * 72 +      lg * 8];
        bf16x8 b11 = *(const bf16x8*)&act0[eb1 * 72 + 32 + lg * 8];
        float K0 = scuts[eb0] * 0.125f * ISQ48;
        float K1 = scuts[eb1] * 0.125f * ISQ48;
        #pragma unroll
        for (int jt = 0; jt < 6; jt++) {
            bf16x8 a0 = *(const bf16x8*)&act1[(jt * 16 + lr) * 72 +      lg * 8];
            bf16x8 a1 = *(const bf16x8*)&act1[(jt * 16 + lr) * 72 + 32 + lg * 8];
            f32x4 d0 = __builtin_amdgcn_mfma_f32_16x16x32_bf16(a0, b00, zero4, 0, 0, 0);
            d0 = __builtin_amdgcn_mfma_f32_16x16x32_bf16(a1, b01, d0, 0, 0, 0);
            f32x4 d1 = __builtin_amdgcn_mfma_f32_16x16x32_bf16(a0, b10, zero4, 0, 0, 0);
            d1 = __builtin_amdgcn_mfma_f32_16x16x32_bf16(a1, b11, d1, 0, 0, 0);
            float s0 = (jt == 0) ? K0 * ISQRT3 : K0;
            float s1 = (jt == 0) ? K1 * ISQRT3 : K1;
            #pragma unroll
            for (int q = 0; q < 4; q++) {
                fac0[jt][q] = d0[q] * s0;
                fac1[jt][q] = d1[q] * s1;
            }
        }
    }
    __syncthreads();

    // ---- phase 6: stage node features (wave-local rows) + WLT ----
    {
        int t2 = tid >> 1, half = tid & 1;
        int p = pbase + t2;
        int e = (p < p1) ? perm[p] : 0;
        int s = esrc[e];
        if (half == 0) {
            const float4* nr = reinterpret_cast<const float4*>(ns + (size_t)s * S_IN);
            #pragma unroll
            for (int q = 0; q < 8; q++) {
                float4 v = nr[q];
                Fns[t2 * 33 + 4*q + 0] = f2bf(v.x);
                Fns[t2 * 33 + 4*q + 1] = f2bf(v.y);
                Fns[t2 * 33 + 4*q + 2] = f2bf(v.z);
                Fns[t2 * 33 + 4*q + 3] = f2bf(v.w);
            }
            sev[t2 * 3 + 0] = esh[(size_t)e * 3 + 0];
            sev[t2 * 3 + 1] = esh[(size_t)e * 3 + 1];
            sev[t2 * 3 + 2] = esh[(size_t)e * 3 + 2];
        } else {
            const float4* vr = reinterpret_cast<const float4*>(nv + (size_t)s * (V_IN * 3));
            #pragma unroll
            for (int q = 0; q < 12; q++) {
                float4 v = vr[q];
                Fnv[t2 * 49 + 4*q + 0] = f2bf(v.x);
                Fnv[t2 * 49 + 4*q + 1] = f2bf(v.y);
                Fnv[t2 * 49 + 4*q + 2] = f2bf(v.z);
                Fnv[t2 * 49 + 4*q + 3] = f2bf(v.w);
            }
        }
        for (int i = tid; i < 48 * 72; i += 256) {
            int j = i / 72, k = i - 72 * j;
            unsigned short v = 0;
            if (k < 48) v = (j < 32) ? f2bf(WLs[k * S_OUT + j])
                                     : f2bf(WLv[k * V_OUT + (j - 32)]);
            sWLT[i] = v;
        }
    }
    __syncthreads();

    const float ev0a = sev[eb0 * 3 + 0], ev1a = sev[eb0 * 3 + 1], ev2a = sev[eb0 * 3 + 2];
    const float ev0b = sev[eb1 * 3 + 0], ev1b = sev[eb1 * 3 + 1], ev2b = sev[eb1 * 3 + 2];
    const int pA = pbase + eb0;
    const int pB = pbase + eb1;

    // ---- M_s fill (wave-local) ----
    #pragma unroll
    for (int jt = 0; jt < 3; jt++) {
        int c0 = jt * 16 + lg * 4;
        float vA[4], vB[4];
        #pragma unroll
        for (int q = 0; q < 4; q++) {
            int c = c0 + q;
            float fa, fb;
            if (jt == 0) {
                fa = bf2f(Fnv[eb0 * 49 + 3*c + 0]) * ev0a
                   + bf2f(Fnv[eb0 * 49 + 3*c + 1]) * ev1a
                   + bf2f(Fnv[eb0 * 49 + 3*c + 2]) * ev2a;
                fb = bf2f(Fnv[eb1 * 49 + 3*c + 0]) * ev0b
                   + bf2f(Fnv[eb1 * 49 + 3*c + 1]) * ev1b
                   + bf2f(Fnv[eb1 * 49 + 3*c + 2]) * ev2b;
            } else {
                fa = bf2f(Fns[eb0 * 33 + (c - 16)]);
                fb = bf2f(Fns[eb1 * 33 + (c - 16)]);
            }
            vA[q] = fa * fac0[jt][q];
            vB[q] = fb * fac1[jt][q];
        }
        unsigned int w0 = (unsigned int)f2bf(vA[0]) | ((unsigned int)f2bf(vA[1]) << 16);
        unsigned int w1 = (unsigned int)f2bf(vA[2]) | ((unsigned int)f2bf(vA[3]) << 16);
        *(uint2*)&M[eb0 * 72 + c0] = make_uint2(w0, w1);
        w0 = (unsigned int)f2bf(vB[0]) | ((unsigned int)f2bf(vB[1]) << 16);
        w1 = (unsigned int)f2bf(vB[2]) | ((unsigned int)f2bf(vB[3]) << 16);
        *(uint2*)&M[eb1 * 72 + c0] = make_uint2(w0, w1);
    }
    *(uint2*)&M[eb0 * 72 + 48 + lg * 4] = make_uint2(0u, 0u);
    *(uint2*)&M[eb1 * 72 + 48 + lg * 4] = make_uint2(0u, 0u);

    // ---- ys GEMM + store cols 0..31 ----
    {
        f32x4 acc[2][2] = {{zero4, zero4}, {zero4, zero4}};
        #pragma unroll
        for (int kt = 0; kt < 2; kt++) {
            bf16x8 b0 = *(const bf16x8*)&M[eb0 * 72 + kt * 32 + lg * 8];
            bf16x8 b1 = *(const bf16x8*)&M[eb1 * 72 + kt * 32 + lg * 8];
            #pragma unroll
            for (int ot = 0; ot < 2; ot++) {
                bf16x8 a = *(const bf16x8*)&sWLT[(ot * 16 + lr) * 72 + kt * 32 + lg * 8];
                acc[0][ot] = __builtin_amdgcn_mfma_f32_16x16x32_bf16(a, b0, acc[0][ot], 0, 0, 0);
                acc[1][ot] = __builtin_amdgcn_mfma_f32_16x16x32_bf16(a, b1, acc[1][ot], 0, 0, 0);
            }
        }
        #pragma unroll
        for (int ot = 0; ot < 2; ot++) {
            if (pA < p1) {
                __half2 ha = __floats2half2_rn(acc[0][ot][0], acc[0][ot][1]);
                __half2 hb = __floats2half2_rn(acc[0][ot][2], acc[0][ot][3]);
                *(uint2*)(cont + (size_t)(pA - p0) * CPITCH + ot * 16 + lg * 4) =
                    make_uint2(*(unsigned int*)&ha, *(unsigned int*)&hb);
            }
            if (pB < p1) {
                __half2 ha = __floats2half2_rn(acc[1][ot][0], acc[1][ot][1]);
                __half2 hb = __floats2half2_rn(acc[1][ot][2], acc[1][ot][3]);
                *(uint2*)(cont + (size_t)(pB - p0) * CPITCH + ot * 16 + lg * 4) =
                    make_uint2(*(unsigned int*)&ha, *(unsigned int*)&hb);
            }
        }
    }

    // ---- vector path: 3 components ----
    #pragma unroll 1
    for (int i = 0; i < 3; i++) {
        float evA = (i == 0) ? ev0a : ((i == 1) ? ev1a : ev2a);
        float evB = (i == 0) ? ev0b : ((i == 1) ? ev1b : ev2b);
        #pragma unroll
        for (int jt = 0; jt < 3; jt++) {
            int c0 = jt * 16 + lg * 4;
            float vA[4], vB[4];
            #pragma unroll
            for (int q = 0; q < 4; q++) {
                int r = c0 + q;
                float fa, fb;
                if (jt < 2) {
                    fa = bf2f(Fns[eb0 * 33 + r]) * evA;
                    fb = bf2f(Fns[eb1 * 33 + r]) * evB;
                } else {
                    fa = bf2f(Fnv[eb0 * 49 + 3 * (r - 32) + i]);
                    fb = bf2f(Fnv[eb1 * 49 + 3 * (r - 32) + i]);
                }
                vA[q] = fa * fac0[3 + jt][q];
                vB[q] = fb * fac1[3 + jt][q];
            }
            unsigned int w0 = (unsigned int)f2bf(vA[0]) | ((unsigned int)f2bf(vA[1]) << 16);
            unsigned int w1 = (unsigned int)f2bf(vA[2]) | ((unsigned int)f2bf(vA[3]) << 16);
            *(uint2*)&M[eb0 * 72 + c0] = make_uint2(w0, w1);
            w0 = (unsigned int)f2bf(vB[0]) | ((unsigned int)f2bf(vB[1]) << 16);
            w1 = (unsigned int)f2bf(vB[2]) | ((unsigned int)f2bf(vB[3]) << 16);
            *(uint2*)&M[eb1 * 72 + c0] = make_uint2(w0, w1);
        }
        f32x4 acc0 = zero4, acc1 = zero4;
        #pragma unroll
        for (int kt = 0; kt < 2; kt++) {
            bf16x8 b0 = *(const bf16x8*)&M[eb0 * 72 + kt * 32 + lg * 8];
            bf16x8 b1 = *(const bf16x8*)&M[eb1 * 72 + kt * 32 + lg * 8];
            bf16x8 a  = *(const bf16x8*)&sWLT[(32 + lr) * 72 + kt * 32 + lg * 8];
            acc0 = __builtin_amdgcn_mfma_f32_16x16x32_bf16(a, b0, acc0, 0, 0, 0);
            acc1 = __builtin_amdgcn_mfma_f32_16x16x32_bf16(a, b1, acc1, 0, 0, 0);
        }
        if (pA < p1) {
            __half* orow = cont + (size_t)(pA - p0) * CPITCH;
            #pragma unroll
            for (int q = 0; q < 4; q++)
                orow[32 + 3 * (lg * 4 + q) + i] = __float2half(acc0[q]);
        }
        if (pB < p1) {
            __half* orow = cont + (size_t)(pB - p0) * CPITCH;
            #pragma unroll
            for (int q = 0; q < 4; q++)
                orow[32 + 3 * (lg * 4 + q) + i] = __float2half(acc1[q]);
        }
    }
}

// ---------------------------------------------------------------------------
// Gather: one wave per node, sum 80-elem fp16 rows (pitch 80, packed).
// ---------------------------------------------------------------------------
__global__ __launch_bounds__(256) void gather_sum(
    const int*    __restrict__ offs,
    const __half* __restrict__ cont,
    float* __restrict__ out,
    int Nn, int p0, int p1)
{
    int wid = (blockIdx.x * 256 + threadIdx.x) >> 6;
    int l = threadIdx.x & 63;
    if (wid >= Nn) return;
    int beg = offs[wid], end = offs[wid + 1];
    int lo = beg > p0 ? beg : p0;
    int hi = end < p1 ? end : p1;
    if (lo >= hi) return;

    float a0 = 0.0f, a1 = 0.0f;
    const __half* row = cont + (size_t)(lo - p0) * CPITCH;
    for (int p = lo; p < hi; ++p, row += CPITCH) {
        a0 += __half2float(row[l]);
        if (l < 16) a1 += __half2float(row[64 + l]);
    }
    float* orow = out + (size_t)wid * OUT_PER_NODE;
    orow[l] += a0;
    if (l < 16) orow[64 + l] += a1;
}

// ---------------------------------------------------------------------------
extern "C" void kernel_launch(void* const* d_in, const int* in_sizes, int n_in,
                              void* d_out, int out_size, void* d_ws, size_t ws_size,
                              hipStream_t stream) {
    const int*   esrc = (const int*)  d_in[0];
    const int*   edst = (const int*)  d_in[1];
    const float* ecut = (const float*)d_in[2];
    const float* einv = (const float*)d_in[3];
    const float* ns   = (const float*)d_in[4];
    const float* nv   = (const float*)d_in[5];
    const float* esh  = (const float*)d_in[6];
    const float* W0   = (const float*)d_in[7];
    const float* W1   = (const float*)d_in[8];
    const float* W2   = (const float*)d_in[9];
    const float* WLs  = (const float*)d_in[10];
    const float* WLv  = (const float*)d_in[11];
    float* out = (float*)d_out;

    const int E  = in_sizes[0];
    const int Nn = in_sizes[4] / S_IN;

    size_t int_bytes = (((size_t)(3 * Nn + 1 + E)) * sizeof(int) + 255) & ~(size_t)255;

    int eblocks = (E + 255) / 256;

    hipMemsetAsync(out, 0, (size_t)Nn * OUT_PER_NODE * sizeof(float), stream);

    int*    deg    = (int*)d_ws;
    int*    offs   = deg + Nn;          // Nn+1
    int*    cursor = offs + Nn + 1;     // Nn
    int*    perm   = cursor + Nn;       // E
    __half* cont   = (__half*)((char*)d_ws + int_bytes);

    size_t avail = (ws_size > int_bytes) ? (ws_size - int_bytes) : 0;
    int chunkE = (int)(avail / ((size_t)CPITCH * sizeof(__half)));
    if (chunkE > E) chunkE = E;

    if (chunkE >= 4096) {
        hipMemsetAsync(deg, 0, (size_t)Nn * sizeof(int), stream);
        hist_kernel<<<eblocks, 256, 0, stream>>>(edst, deg, E);
        scan_kernel<<<1, 1024, 0, stream>>>(deg, offs, cursor, Nn);
        scatter_kernel<<<eblocks, 256, 0, stream>>>(edst, cursor, perm, E);

        int gblocks = (Nn + 3) / 4;
        for (int p0 = 0; p0 < E; p0 += chunkE) {
            int p1 = p0 + chunkE; if (p1 > E) p1 = E;
            int n = p1 - p0;
            int mblocks = (n + 127) / 128;
            edge_mega<<<mblocks, 256, 0, stream>>>(perm, esrc, ecut, einv, ns, nv, esh,
                                                   W0, W1, W2, WLs, WLv, cont, p0, p1);
            gather_sum<<<gblocks, 256, 0, stream>>>(offs, cont, out, Nn, p0, p1);
        }
    }
}

// Round 10
// 447.052 us; speedup vs baseline: 2.8061x; 1.4127x over previous
//
#include <hip/hip_runtime.h>
#include <hip/hip_fp16.h>
#include <math.h>

// Problem constants
constexpr int S_IN = 32, V_IN = 16, INVD = 16;
constexpr int S_MSG = S_IN + V_IN;           // 48
constexpr int V_MSG = S_IN + V_IN;           // 48
constexpr int NFAC  = S_MSG + V_MSG;         // 96
constexpr int S_OUT = 32, V_OUT = 16;
constexpr int OUT_PER_NODE = S_OUT + V_OUT * 3;  // 80
constexpr int CPITCH = 80;                       // fp16 elems per contribution row
constexpr float ISQRT3 = 0.57735026918962576f;
constexpr float ISQ48  = 0.14433756729740643f;

// prepped-weight layout (in shorts): W0T[64][40] | W1T[64][72] | W2T[96][72] | WLT[48][72]
constexpr int PW0 = 0, PW1 = 2560, PW2 = 7168, PWL = 14080, PWTOT = 17536;

typedef __attribute__((ext_vector_type(8))) short bf16x8;
typedef __attribute__((ext_vector_type(4))) float f32x4;

__device__ __forceinline__ float silu_f(float x) {
    return x / (1.0f + __expf(-x));
}
__device__ __forceinline__ unsigned short f2bf(float f) {
    unsigned int u = __float_as_uint(f);
    u += 0x7FFFu + ((u >> 16) & 1u);
    return (unsigned short)(u >> 16);
}
__device__ __forceinline__ float bf2f(unsigned short h) {
    return __uint_as_float(((unsigned int)h) << 16);
}

// ---------------------------------------------------------------------------
// CSR construction
// ---------------------------------------------------------------------------
__global__ __launch_bounds__(256) void hist_kernel(
    const int* __restrict__ edst, int* __restrict__ deg, int E)
{
    int e = blockIdx.x * 256 + threadIdx.x;
    if (e < E) atomicAdd(&deg[edst[e]], 1);
}

__global__ __launch_bounds__(1024) void scan_kernel(
    const int* __restrict__ deg, int* __restrict__ offs,
    int* __restrict__ cursor, int Nn)
{
    const int T = 1024;
    int t = threadIdx.x;
    int chunk = (Nn + T - 1) / T;
    int lo = t * chunk;
    int hi = lo + chunk; if (hi > Nn) hi = Nn;
    int s = 0;
    for (int i = lo; i < hi; i++) s += deg[i];
    __shared__ int ps[T];
    ps[t] = s;
    __syncthreads();
    for (int off = 1; off < T; off <<= 1) {
        int v = (t >= off) ? ps[t - off] : 0;
        __syncthreads();
        ps[t] += v;
        __syncthreads();
    }
    int base = (t > 0) ? ps[t - 1] : 0;
    for (int i = lo; i < hi; i++) {
        offs[i] = base;
        cursor[i] = base;
        base += deg[i];
    }
    if (t == 0) offs[Nn] = ps[T - 1];
}

__global__ __launch_bounds__(256) void scatter_kernel(
    const int* __restrict__ edst, int* __restrict__ cursor,
    int* __restrict__ perm, int E)
{
    int e = blockIdx.x * 256 + threadIdx.x;
    if (e < E) {
        int pos = atomicAdd(&cursor[edst[e]], 1);
        perm[pos] = e;
    }
}

// ---------------------------------------------------------------------------
// Pre-pass: weights -> transposed/padded bf16; tensors -> bf16
// ---------------------------------------------------------------------------
__global__ __launch_bounds__(256) void prep_weights(
    const float* __restrict__ W0, const float* __restrict__ W1,
    const float* __restrict__ W2, const float* __restrict__ WLs,
    const float* __restrict__ WLv, unsigned short* __restrict__ pW)
{
    int i = blockIdx.x * 256 + threadIdx.x;
    if (i >= PWTOT) return;
    float v = 0.0f;
    if (i < PW1) {
        int j = i / 40, k = i - 40 * j;
        if (k < INVD) v = W0[k * 64 + j];
    } else if (i < PW2) {
        int t = i - PW1; int j = t / 72, k = t - 72 * j;
        if (k < 64) v = W1[k * 64 + j];
    } else if (i < PWL) {
        int t = i - PW2; int j = t / 72, k = t - 72 * j;
        if (k < 64) v = W2[k * 96 + j];
    } else {
        int t = i - PWL; int j = t / 72, k = t - 72 * j;
        if (k < 48) v = (j < 32) ? WLs[k * S_OUT + j] : WLv[k * V_OUT + (j - 32)];
    }
    pW[i] = f2bf(v);
}

// cast n floats (n % 8 == 0) to bf16, vectorized
__global__ __launch_bounds__(256) void cast_bf16(
    const float* __restrict__ src, unsigned short* __restrict__ dst, int n8)
{
    int i = blockIdx.x * 256 + threadIdx.x;   // index of 8-group
    if (i >= n8) return;
    const float4* s4 = reinterpret_cast<const float4*>(src + (size_t)i * 8);
    float4 a = s4[0], b = s4[1];
    uint4 o;
    o.x = (unsigned int)f2bf(a.x) | ((unsigned int)f2bf(a.y) << 16);
    o.y = (unsigned int)f2bf(a.z) | ((unsigned int)f2bf(a.w) << 16);
    o.z = (unsigned int)f2bf(b.x) | ((unsigned int)f2bf(b.y) << 16);
    o.w = (unsigned int)f2bf(b.z) | ((unsigned int)f2bf(b.w) << 16);
    *reinterpret_cast<uint4*>(dst + (size_t)i * 8) = o;
}

// ---------------------------------------------------------------------------
// MEGA kernel v2: all-bf16 staging (pure copies), LDS = 53760 B -> 3 blocks/CU.
// Block = 128 edges, 4 waves x 32 edges.
// ---------------------------------------------------------------------------
__global__ __launch_bounds__(256, 3) void edge_mega(
    const int*   __restrict__ perm,
    const int*   __restrict__ esrc,
    const float* __restrict__ ecut,
    const float* __restrict__ esh,
    const unsigned short* __restrict__ pW,
    const unsigned short* __restrict__ pNS,
    const unsigned short* __restrict__ pNV,
    const unsigned short* __restrict__ pXE,
    __half* __restrict__ cont,
    int p0, int p1)
{
    __shared__ __align__(16) unsigned char smem[53760];

    unsigned short* act0 = (unsigned short*)(smem + 14336);  // [128][72]
    unsigned short* act1 = (unsigned short*)(smem + 32768);  // [128][72]
    unsigned short* sW0T = (unsigned short*)(smem + 0);      // [64][40]
    unsigned short* sW1T = (unsigned short*)(smem + 5120);   // [64][72]
    unsigned short* sWLT = (unsigned short*)(smem + 5120);   // [48][72] (phase B)
    unsigned short* M    = (unsigned short*)(smem + 14336);  // [128][72] (phase B)
    unsigned short* Fns  = (unsigned short*)(smem + 32768);  // [128][33] (phase B)
    unsigned short* Fnv  = (unsigned short*)(smem + 41216);  // [128][49] (phase B)

    const int tid = threadIdx.x;
    const int pbase = p0 + blockIdx.x * 128;

    const uint4* wsrc = reinterpret_cast<const uint4*>(pW);

    // ---- phase 1: copy W0T+W1T (896 uint4), stage X from pXE ----
    {
        uint4* s4 = reinterpret_cast<uint4*>(smem);
        #pragma unroll 2
        for (int i = tid; i < 896; i += 256) s4[i] = wsrc[i];
    }
    if (tid < 128) {
        int p = pbase + tid;
        int e = perm[p < p1 ? p : p0];
        const uint4* xr = reinterpret_cast<const uint4*>(pXE + (size_t)e * 16);
        uint4* r4 = reinterpret_cast<uint4*>(&act0[tid * 72]);
        r4[0] = xr[0];
        r4[1] = xr[1];
        r4[2] = make_uint4(0u, 0u, 0u, 0u);
        r4[3] = make_uint4(0u, 0u, 0u, 0u);
    }
    __syncthreads();

    const int lane = tid & 63;
    const int w    = tid >> 6;
    const int lr   = lane & 15;
    const int lg   = lane >> 4;
    const int eb0  = w * 32 + lr;
    const int eb1  = eb0 + 16;
    const int pA   = pbase + eb0;
    const int pB   = pbase + eb1;
    const int eA   = perm[pA < p1 ? pA : p0];
    const int eB   = perm[pB < p1 ? pB : p0];

    const f32x4 zero4 = {0.f, 0.f, 0.f, 0.f};

    // ---- Layer 1: h1 = silu((X@W0)/4) ----
    {
        bf16x8 b0 = *(const bf16x8*)&act0[eb0 * 72 + lg * 8];
        bf16x8 b1 = *(const bf16x8*)&act0[eb1 * 72 + lg * 8];
        #pragma unroll
        for (int jt = 0; jt < 4; jt++) {
            bf16x8 a = *(const bf16x8*)&sW0T[(jt * 16 + lr) * 40 + lg * 8];
            f32x4 d0 = __builtin_amdgcn_mfma_f32_16x16x32_bf16(a, b0, zero4, 0, 0, 0);
            f32x4 d1 = __builtin_amdgcn_mfma_f32_16x16x32_bf16(a, b1, zero4, 0, 0, 0);
            unsigned int u0, u1;
            u0 = (unsigned int)f2bf(silu_f(d0[0] * 0.25f)) | ((unsigned int)f2bf(silu_f(d0[1] * 0.25f)) << 16);
            u1 = (unsigned int)f2bf(silu_f(d0[2] * 0.25f)) | ((unsigned int)f2bf(silu_f(d0[3] * 0.25f)) << 16);
            *(uint2*)&act1[eb0 * 72 + jt * 16 + lg * 4] = make_uint2(u0, u1);
            u0 = (unsigned int)f2bf(silu_f(d1[0] * 0.25f)) | ((unsigned int)f2bf(silu_f(d1[1] * 0.25f)) << 16);
            u1 = (unsigned int)f2bf(silu_f(d1[2] * 0.25f)) | ((unsigned int)f2bf(silu_f(d1[3] * 0.25f)) << 16);
            *(uint2*)&act1[eb1 * 72 + jt * 16 + lg * 4] = make_uint2(u0, u1);
        }
    }

    // ---- Layer 2: h2 = silu((h1@W1)/8) ----
    {
        bf16x8 b00 = *(const bf16x8*)&act1[eb0 * 72 +      lg * 8];
        bf16x8 b01 = *(const bf16x8*)&act1[eb0 * 72 + 32 + lg * 8];
        bf16x8 b10 = *(const bf16x8*)&act1[eb1 * 72 +      lg * 8];
        bf16x8 b11 = *(const bf16x8*)&act1[eb1 * 72 + 32 + lg * 8];
        #pragma unroll
        for (int jt = 0; jt < 4; jt++) {
            bf16x8 a0 = *(const bf16x8*)&sW1T[(jt * 16 + lr) * 72 +      lg * 8];
            bf16x8 a1 = *(const bf16x8*)&sW1T[(jt * 16 + lr) * 72 + 32 + lg * 8];
            f32x4 d0 = __builtin_amdgcn_mfma_f32_16x16x32_bf16(a0, b00, zero4, 0, 0, 0);
            d0 = __builtin_amdgcn_mfma_f32_16x16x32_bf16(a1, b01, d0, 0, 0, 0);
            f32x4 d1 = __builtin_amdgcn_mfma_f32_16x16x32_bf16(a0, b10, zero4, 0, 0, 0);
            d1 = __builtin_amdgcn_mfma_f32_16x16x32_bf16(a1, b11, d1, 0, 0, 0);
            unsigned int u0, u1;
            u0 = (unsigned int)f2bf(silu_f(d0[0] * 0.125f)) | ((unsigned int)f2bf(silu_f(d0[1] * 0.125f)) << 16);
            u1 = (unsigned int)f2bf(silu_f(d0[2] * 0.125f)) | ((unsigned int)f2bf(silu_f(d0[3] * 0.125f)) << 16);
            *(uint2*)&act0[eb0 * 72 + jt * 16 + lg * 4] = make_uint2(u0, u1);
            u0 = (unsigned int)f2bf(silu_f(d1[0] * 0.125f)) | ((unsigned int)f2bf(silu_f(d1[1] * 0.125f)) << 16);
            u1 = (unsigned int)f2bf(silu_f(d1[2] * 0.125f)) | ((unsigned int)f2bf(silu_f(d1[3] * 0.125f)) << 16);
            *(uint2*)&act0[eb1 * 72 + jt * 16 + lg * 4] = make_uint2(u0, u1);
        }
    }

    // ---- stage W2T into act1 (864 uint4) ----
    __syncthreads();
    {
        uint4* a14 = reinterpret_cast<uint4*>(act1);
        const uint4* w2s = wsrc + 896;
        #pragma unroll 2
        for (int i = tid; i < 864; i += 256) a14[i] = w2s[i];
    }
    __syncthreads();

    // ---- Layer 3: fac -> registers (scales folded) ----
    float fac0[6][4], fac1[6][4];
    {
        bf16x8 b00 = *(const bf16x8*)&act0[eb0 * 72 +      lg * 8];
        bf16x8 b01 = *(const bf16x8*)&act0[eb0 * 72 + 32 + lg * 8];
        bf16x8 b10 = *(const bf16x8*)&act0[eb1 * 72 +      lg * 8];
        bf16x8 b11 = *(const bf16x8*)&act0[eb1 * 72 + 32 + lg * 8];
        float K0 = ecut[eA] * 0.125f * ISQ48;
        float K1 = ecut[eB] * 0.125f * ISQ48;
        #pragma unroll
        for (int jt = 0; jt < 6; jt++) {
            bf16x8 a0 = *(const bf16x8*)&act1[(jt * 16 + lr) * 72 +      lg * 8];
            bf16x8 a1 = *(const bf16x8*)&act1[(jt * 16 + lr) * 72 + 32 + lg * 8];
            f32x4 d0 = __builtin_amdgcn_mfma_f32_16x16x32_bf16(a0, b00, zero4, 0, 0, 0);
            d0 = __builtin_amdgcn_mfma_f32_16x16x32_bf16(a1, b01, d0, 0, 0, 0);
            f32x4 d1 = __builtin_amdgcn_mfma_f32_16x16x32_bf16(a0, b10, zero4, 0, 0, 0);
            d1 = __builtin_amdgcn_mfma_f32_16x16x32_bf16(a1, b11, d1, 0, 0, 0);
            float s0 = (jt == 0) ? K0 * ISQRT3 : K0;
            float s1 = (jt == 0) ? K1 * ISQRT3 : K1;
            #pragma unroll
            for (int q = 0; q < 4; q++) {
                fac0[jt][q] = d0[q] * s0;
                fac1[jt][q] = d1[q] * s1;
            }
        }
    }
    __syncthreads();

    // ---- phase 6: stage features (bf16 copies) + WLT (432 uint4) ----
    {
        int t2 = tid >> 1, half = tid & 1;
        int p = pbase + t2;
        int e = perm[p < p1 ? p : p0];
        int s = esrc[e];
        if (half == 0) {
            const uint4* nr = reinterpret_cast<const uint4*>(pNS + (size_t)s * 32);
            #pragma unroll
            for (int q = 0; q < 4; q++) {
                uint4 v = nr[q];
                unsigned short* d = &Fns[t2 * 33 + 8 * q];
                d[0] = (unsigned short)v.x; d[1] = (unsigned short)(v.x >> 16);
                d[2] = (unsigned short)v.y; d[3] = (unsigned short)(v.y >> 16);
                d[4] = (unsigned short)v.z; d[5] = (unsigned short)(v.z >> 16);
                d[6] = (unsigned short)v.w; d[7] = (unsigned short)(v.w >> 16);
            }
        } else {
            const uint4* vr = reinterpret_cast<const uint4*>(pNV + (size_t)s * 48);
            #pragma unroll
            for (int q = 0; q < 6; q++) {
                uint4 v = vr[q];
                unsigned short* d = &Fnv[t2 * 49 + 8 * q];
                d[0] = (unsigned short)v.x; d[1] = (unsigned short)(v.x >> 16);
                d[2] = (unsigned short)v.y; d[3] = (unsigned short)(v.y >> 16);
                d[4] = (unsigned short)v.z; d[5] = (unsigned short)(v.z >> 16);
                d[6] = (unsigned short)v.w; d[7] = (unsigned short)(v.w >> 16);
            }
        }
        uint4* wl4 = reinterpret_cast<uint4*>(sWLT);
        const uint4* wls = wsrc + 896 + 864;
        #pragma unroll 2
        for (int i = tid; i < 432; i += 256) wl4[i] = wls[i];
    }
    __syncthreads();

    const float ev0a = esh[(size_t)eA * 3 + 0], ev1a = esh[(size_t)eA * 3 + 1], ev2a = esh[(size_t)eA * 3 + 2];
    const float ev0b = esh[(size_t)eB * 3 + 0], ev1b = esh[(size_t)eB * 3 + 1], ev2b = esh[(size_t)eB * 3 + 2];

    // ---- M_s fill ----
    #pragma unroll
    for (int jt = 0; jt < 3; jt++) {
        int c0 = jt * 16 + lg * 4;
        float vA[4], vB[4];
        #pragma unroll
        for (int q = 0; q < 4; q++) {
            int c = c0 + q;
            float fa, fb;
            if (jt == 0) {
                fa = bf2f(Fnv[eb0 * 49 + 3*c + 0]) * ev0a
                   + bf2f(Fnv[eb0 * 49 + 3*c + 1]) * ev1a
                   + bf2f(Fnv[eb0 * 49 + 3*c + 2]) * ev2a;
                fb = bf2f(Fnv[eb1 * 49 + 3*c + 0]) * ev0b
                   + bf2f(Fnv[eb1 * 49 + 3*c + 1]) * ev1b
                   + bf2f(Fnv[eb1 * 49 + 3*c + 2]) * ev2b;
            } else {
                fa = bf2f(Fns[eb0 * 33 + (c - 16)]);
                fb = bf2f(Fns[eb1 * 33 + (c - 16)]);
            }
            vA[q] = fa * fac0[jt][q];
            vB[q] = fb * fac1[jt][q];
        }
        unsigned int w0 = (unsigned int)f2bf(vA[0]) | ((unsigned int)f2bf(vA[1]) << 16);
        unsigned int w1 = (unsigned int)f2bf(vA[2]) | ((unsigned int)f2bf(vA[3]) << 16);
        *(uint2*)&M[eb0 * 72 + c0] = make_uint2(w0, w1);
        w0 = (unsigned int)f2bf(vB[0]) | ((unsigned int)f2bf(vB[1]) << 16);
        w1 = (unsigned int)f2bf(vB[2]) | ((unsigned int)f2bf(vB[3]) << 16);
        *(uint2*)&M[eb1 * 72 + c0] = make_uint2(w0, w1);
    }
    *(uint2*)&M[eb0 * 72 + 48 + lg * 4] = make_uint2(0u, 0u);
    *(uint2*)&M[eb1 * 72 + 48 + lg * 4] = make_uint2(0u, 0u);

    // ---- ys GEMM + store cols 0..31 ----
    {
        f32x4 acc[2][2] = {{zero4, zero4}, {zero4, zero4}};
        #pragma unroll
        for (int kt = 0; kt < 2; kt++) {
            bf16x8 b0 = *(const bf16x8*)&M[eb0 * 72 + kt * 32 + lg * 8];
            bf16x8 b1 = *(const bf16x8*)&M[eb1 * 72 + kt * 32 + lg * 8];
            #pragma unroll
            for (int ot = 0; ot < 2; ot++) {
                bf16x8 a = *(const bf16x8*)&sWLT[(ot * 16 + lr) * 72 + kt * 32 + lg * 8];
                acc[0][ot] = __builtin_amdgcn_mfma_f32_16x16x32_bf16(a, b0, acc[0][ot], 0, 0, 0);
                acc[1][ot] = __builtin_amdgcn_mfma_f32_16x16x32_bf16(a, b1, acc[1][ot], 0, 0, 0);
            }
        }
        #pragma unroll
        for (int ot = 0; ot < 2; ot++) {
            if (pA < p1) {
                __half2 ha = __floats2half2_rn(acc[0][ot][0], acc[0][ot][1]);
                __half2 hb = __floats2half2_rn(acc[0][ot][2], acc[0][ot][3]);
                *(uint2*)(cont + (size_t)(pA - p0) * CPITCH + ot * 16 + lg * 4) =
                    make_uint2(*(unsigned int*)&ha, *(unsigned int*)&hb);
            }
            if (pB < p1) {
                __half2 ha = __floats2half2_rn(acc[1][ot][0], acc[1][ot][1]);
                __half2 hb = __floats2half2_rn(acc[1][ot][2], acc[1][ot][3]);
                *(uint2*)(cont + (size_t)(pB - p0) * CPITCH + ot * 16 + lg * 4) =
                    make_uint2(*(unsigned int*)&ha, *(unsigned int*)&hb);
            }
        }
    }

    // ---- vector path: 3 components ----
    #pragma unroll 1
    for (int i = 0; i < 3; i++) {
        float evA = (i == 0) ? ev0a : ((i == 1) ? ev1a : ev2a);
        float evB = (i == 0) ? ev0b : ((i == 1) ? ev1b : ev2b);
        #pragma unroll
        for (int jt = 0; jt < 3; jt++) {
            int c0 = jt * 16 + lg * 4;
            float vA[4], vB[4];
            #pragma unroll
            for (int q = 0; q < 4; q++) {
                int r = c0 + q;
                float fa, fb;
                if (jt < 2) {
                    fa = bf2f(Fns[eb0 * 33 + r]) * evA;
                    fb = bf2f(Fns[eb1 * 33 + r]) * evB;
                } else {
                    fa = bf2f(Fnv[eb0 * 49 + 3 * (r - 32) + i]);
                    fb = bf2f(Fnv[eb1 * 49 + 3 * (r - 32) + i]);
                }
                vA[q] = fa * fac0[3 + jt][q];
                vB[q] = fb * fac1[3 + jt][q];
            }
            unsigned int w0 = (unsigned int)f2bf(vA[0]) | ((unsigned int)f2bf(vA[1]) << 16);
            unsigned int w1 = (unsigned int)f2bf(vA[2]) | ((unsigned int)f2bf(vA[3]) << 16);
            *(uint2*)&M[eb0 * 72 + c0] = make_uint2(w0, w1);
            w0 = (unsigned int)f2bf(vB[0]) | ((unsigned int)f2bf(vB[1]) << 16);
            w1 = (unsigned int)f2bf(vB[2]) | ((unsigned int)f2bf(vB[3]) << 16);
            *(uint2*)&M[eb1 * 72 + c0] = make_uint2(w0, w1);
        }
        f32x4 acc0 = zero4, acc1 = zero4;
        #pragma unroll
        for (int kt = 0; kt < 2; kt++) {
            bf16x8 b0 = *(const bf16x8*)&M[eb0 * 72 + kt * 32 + lg * 8];
            bf16x8 b1 = *(const bf16x8*)&M[eb1 * 72 + kt * 32 + lg * 8];
            bf16x8 a  = *(const bf16x8*)&sWLT[(32 + lr) * 72 + kt * 32 + lg * 8];
            acc0 = __builtin_amdgcn_mfma_f32_16x16x32_bf16(a, b0, acc0, 0, 0, 0);
            acc1 = __builtin_amdgcn_mfma_f32_16x16x32_bf16(a, b1, acc1, 0, 0, 0);
        }
        if (pA < p1) {
            __half* orow = cont + (size_t)(pA - p0) * CPITCH;
            #pragma unroll
            for (int q = 0; q < 4; q++)
                orow[32 + 3 * (lg * 4 + q) + i] = __float2half(acc0[q]);
        }
        if (pB < p1) {
            __half* orow = cont + (size_t)(pB - p0) * CPITCH;
            #pragma unroll
            for (int q = 0; q < 4; q++)
                orow[32 + 3 * (lg * 4 + q) + i] = __float2half(acc1[q]);
        }
    }
}

// ---------------------------------------------------------------------------
// Gather: one wave per node; lane l<40 reads uint (2 fp16) per row, float2 out.
// ---------------------------------------------------------------------------
__global__ __launch_bounds__(256) void gather_sum(
    const int*    __restrict__ offs,
    const __half* __restrict__ cont,
    float* __restrict__ out,
    int Nn, int p0, int p1)
{
    int wid = (blockIdx.x * 256 + threadIdx.x) >> 6;
    int l = threadIdx.x & 63;
    if (wid >= Nn || l >= 40) return;
    int beg = offs[wid], end = offs[wid + 1];
    int lo = beg > p0 ? beg : p0;
    int hi = end < p1 ? end : p1;
    if (lo >= hi) return;

    float a0 = 0.0f, a1 = 0.0f;
    const unsigned int* row = reinterpret_cast<const unsigned int*>(
        cont + (size_t)(lo - p0) * CPITCH) + l;
    for (int p = lo; p < hi; ++p, row += CPITCH / 2) {
        unsigned int v = *row;
        __half2 h2 = *reinterpret_cast<const __half2*>(&v);
        float2 f2 = __half22float2(h2);
        a0 += f2.x;
        a1 += f2.y;
    }
    float2* o2 = reinterpret_cast<float2*>(out + (size_t)wid * OUT_PER_NODE + 2 * l);
    float2 cur = *o2;
    cur.x += a0; cur.y += a1;
    *o2 = cur;
}

// ---------------------------------------------------------------------------
extern "C" void kernel_launch(void* const* d_in, const int* in_sizes, int n_in,
                              void* d_out, int out_size, void* d_ws, size_t ws_size,
                              hipStream_t stream) {
    const int*   esrc = (const int*)  d_in[0];
    const int*   edst = (const int*)  d_in[1];
    const float* ecut = (const float*)d_in[2];
    const float* einv = (const float*)d_in[3];
    const float* ns   = (const float*)d_in[4];
    const float* nv   = (const float*)d_in[5];
    const float* esh  = (const float*)d_in[6];
    const float* W0   = (const float*)d_in[7];
    const float* W1   = (const float*)d_in[8];
    const float* W2   = (const float*)d_in[9];
    const float* WLs  = (const float*)d_in[10];
    const float* WLv  = (const float*)d_in[11];
    float* out = (float*)d_out;

    const int E  = in_sizes[0];
    const int Nn = in_sizes[4] / S_IN;

    size_t int_bytes = (((size_t)(3 * Nn + 1 + E)) * sizeof(int) + 255) & ~(size_t)255;
    size_t pw_bytes  = ((size_t)PWTOT * 2 + 255) & ~(size_t)255;
    size_t ns_bytes  = ((size_t)Nn * 32 * 2 + 255) & ~(size_t)255;
    size_t nv_bytes  = ((size_t)Nn * 48 * 2 + 255) & ~(size_t)255;
    size_t xe_bytes  = ((size_t)E * 16 * 2 + 255) & ~(size_t)255;
    size_t fixed = int_bytes + pw_bytes + ns_bytes + nv_bytes + xe_bytes;

    int eblocks = (E + 255) / 256;

    hipMemsetAsync(out, 0, (size_t)Nn * OUT_PER_NODE * sizeof(float), stream);

    int*            deg    = (int*)d_ws;
    int*            offs   = deg + Nn;
    int*            cursor = offs + Nn + 1;
    int*            perm   = cursor + Nn;
    unsigned short* pW     = (unsigned short*)((char*)d_ws + int_bytes);
    unsigned short* pNS    = (unsigned short*)((char*)d_ws + int_bytes + pw_bytes);
    unsigned short* pNV    = (unsigned short*)((char*)d_ws + int_bytes + pw_bytes + ns_bytes);
    unsigned short* pXE    = (unsigned short*)((char*)d_ws + int_bytes + pw_bytes + ns_bytes + nv_bytes);
    __half*         cont   = (__half*)((char*)d_ws + fixed);

    size_t avail = (ws_size > fixed) ? (ws_size - fixed) : 0;
    int chunkE = (int)(avail / ((size_t)CPITCH * sizeof(__half)));
    if (chunkE > E) chunkE = E;

    if (chunkE >= 4096) {
        hipMemsetAsync(deg, 0, (size_t)Nn * sizeof(int), stream);
        hist_kernel<<<eblocks, 256, 0, stream>>>(edst, deg, E);
        scan_kernel<<<1, 1024, 0, stream>>>(deg, offs, cursor, Nn);
        scatter_kernel<<<eblocks, 256, 0, stream>>>(edst, cursor, perm, E);

        prep_weights<<<(PWTOT + 255) / 256, 256, 0, stream>>>(W0, W1, W2, WLs, WLv, pW);
        cast_bf16<<<((Nn * 32 / 8) + 255) / 256, 256, 0, stream>>>(ns, pNS, Nn * 32 / 8);
        cast_bf16<<<((Nn * 48 / 8) + 255) / 256, 256, 0, stream>>>(nv, pNV, Nn * 48 / 8);
        cast_bf16<<<((E * 16 / 8) + 255) / 256, 256, 0, stream>>>(einv, pXE, E * 16 / 8);

        int gblocks = (Nn + 3) / 4;
        for (int p0 = 0; p0 < E; p0 += chunkE) {
            int p1 = p0 + chunkE; if (p1 > E) p1 = E;
            int n = p1 - p0;
            int mblocks = (n + 127) / 128;
            edge_mega<<<mblocks, 256, 0, stream>>>(perm, esrc, ecut, esh,
                                                   pW, pNS, pNV, pXE, cont, p0, p1);
            gather_sum<<<gblocks, 256, 0, stream>>>(offs, cont, out, Nn, p0, p1);
        }
    }
}

// Round 11
// 422.001 us; speedup vs baseline: 2.9727x; 1.0594x over previous
//
#include <hip/hip_runtime.h>
#include <hip/hip_fp16.h>
#include <math.h>

// Problem constants
constexpr int S_IN = 32, V_IN = 16, INVD = 16;
constexpr int S_MSG = S_IN + V_IN;           // 48
constexpr int V_MSG = S_IN + V_IN;           // 48
constexpr int NFAC  = S_MSG + V_MSG;         // 96
constexpr int S_OUT = 32, V_OUT = 16;
constexpr int OUT_PER_NODE = S_OUT + V_OUT * 3;  // 80
constexpr int CPITCH = 80;                       // fp16 elems per contribution row
constexpr float ISQRT3 = 0.57735026918962576f;
constexpr float ISQ48  = 0.14433756729740643f;

// prepped-weight layout (in shorts): W0T[64][40] | W1T[64][72] | W2T[96][72] | WLT[48][72]
constexpr int PW0 = 0, PW1 = 2560, PW2 = 7168, PWL = 14080, PWTOT = 17536;

typedef __attribute__((ext_vector_type(8))) short bf16x8;
typedef __attribute__((ext_vector_type(4))) float f32x4;

__device__ __forceinline__ float silu_f(float x) {
    return x / (1.0f + __expf(-x));
}
__device__ __forceinline__ unsigned short f2bf(float f) {
    unsigned int u = __float_as_uint(f);
    u += 0x7FFFu + ((u >> 16) & 1u);
    return (unsigned short)(u >> 16);
}
__device__ __forceinline__ float bf2f(unsigned short h) {
    return __uint_as_float(((unsigned int)h) << 16);
}

// ---------------------------------------------------------------------------
// CSR construction
// ---------------------------------------------------------------------------
__global__ __launch_bounds__(256) void hist_kernel(
    const int* __restrict__ edst, int* __restrict__ deg, int E)
{
    int e = blockIdx.x * 256 + threadIdx.x;
    if (e < E) atomicAdd(&deg[edst[e]], 1);
}

__global__ __launch_bounds__(1024) void scan_kernel(
    const int* __restrict__ deg, int* __restrict__ offs,
    int* __restrict__ cursor, int Nn)
{
    const int T = 1024;
    int t = threadIdx.x;
    int chunk = (Nn + T - 1) / T;
    int lo = t * chunk;
    int hi = lo + chunk; if (hi > Nn) hi = Nn;
    int s = 0;
    for (int i = lo; i < hi; i++) s += deg[i];
    __shared__ int ps[T];
    ps[t] = s;
    __syncthreads();
    for (int off = 1; off < T; off <<= 1) {
        int v = (t >= off) ? ps[t - off] : 0;
        __syncthreads();
        ps[t] += v;
        __syncthreads();
    }
    int base = (t > 0) ? ps[t - 1] : 0;
    for (int i = lo; i < hi; i++) {
        offs[i] = base;
        cursor[i] = base;
        base += deg[i];
    }
    if (t == 0) offs[Nn] = ps[T - 1];
}

__global__ __launch_bounds__(256) void scatter_kernel(
    const int* __restrict__ edst, int* __restrict__ cursor,
    int* __restrict__ perm, int E)
{
    int e = blockIdx.x * 256 + threadIdx.x;
    if (e < E) {
        int pos = atomicAdd(&cursor[edst[e]], 1);
        perm[pos] = e;
    }
}

// ---------------------------------------------------------------------------
// Pre-pass: weights -> transposed/padded bf16; node features -> bf16
// ---------------------------------------------------------------------------
__global__ __launch_bounds__(256) void prep_weights(
    const float* __restrict__ W0, const float* __restrict__ W1,
    const float* __restrict__ W2, const float* __restrict__ WLs,
    const float* __restrict__ WLv, unsigned short* __restrict__ pW)
{
    int i = blockIdx.x * 256 + threadIdx.x;
    if (i >= PWTOT) return;
    float v = 0.0f;
    if (i < PW1) {
        int j = i / 40, k = i - 40 * j;
        if (k < INVD) v = W0[k * 64 + j];
    } else if (i < PW2) {
        int t = i - PW1; int j = t / 72, k = t - 72 * j;
        if (k < 64) v = W1[k * 64 + j];
    } else if (i < PWL) {
        int t = i - PW2; int j = t / 72, k = t - 72 * j;
        if (k < 64) v = W2[k * 96 + j];
    } else {
        int t = i - PWL; int j = t / 72, k = t - 72 * j;
        if (k < 48) v = (j < 32) ? WLs[k * S_OUT + j] : WLv[k * V_OUT + (j - 32)];
    }
    pW[i] = f2bf(v);
}

__global__ __launch_bounds__(256) void cast_bf16(
    const float* __restrict__ src, unsigned short* __restrict__ dst, int n8)
{
    int i = blockIdx.x * 256 + threadIdx.x;
    if (i >= n8) return;
    const float4* s4 = reinterpret_cast<const float4*>(src + (size_t)i * 8);
    float4 a = s4[0], b = s4[1];
    uint4 o;
    o.x = (unsigned int)f2bf(a.x) | ((unsigned int)f2bf(a.y) << 16);
    o.y = (unsigned int)f2bf(a.z) | ((unsigned int)f2bf(a.w) << 16);
    o.z = (unsigned int)f2bf(b.x) | ((unsigned int)f2bf(b.y) << 16);
    o.w = (unsigned int)f2bf(b.z) | ((unsigned int)f2bf(b.w) << 16);
    *reinterpret_cast<uint4*>(dst + (size_t)i * 8) = o;
}

// ---------------------------------------------------------------------------
// MEGA kernel v3: prefetched gathers (T14 async-split), packed stores.
// Block = 128 edges, 4 waves x 32 edges. LDS 53760 B -> 3 blocks/CU.
// ---------------------------------------------------------------------------
__global__ __launch_bounds__(256, 3) void edge_mega(
    const int*   __restrict__ perm,
    const int*   __restrict__ esrc,
    const float* __restrict__ ecut,
    const float* __restrict__ esh,
    const float* __restrict__ einv,
    const unsigned short* __restrict__ pW,
    const unsigned short* __restrict__ pNS,
    const unsigned short* __restrict__ pNV,
    __half* __restrict__ cont,
    int p0, int p1)
{
    __shared__ __align__(16) unsigned char smem[53760];

    unsigned short* sW0T = (unsigned short*)(smem + 0);      // [64][40]
    unsigned short* sW1T = (unsigned short*)(smem + 5120);   // [64][72]
    unsigned short* act0 = (unsigned short*)(smem + 14336);  // [128][72]
    unsigned short* act1 = (unsigned short*)(smem + 32768);  // [128][72]
    unsigned short* sWLT = (unsigned short*)(smem + 5120);   // [48][72] (phase B)
    unsigned short* M    = (unsigned short*)(smem + 14336);  // [128][72] (phase B)
    unsigned short* Fns  = (unsigned short*)(smem + 32768);  // [128][33] (phase B)
    unsigned short* Fnv  = (unsigned short*)(smem + 41216);  // [128][49] (phase B)

    const int tid = threadIdx.x;
    const int pbase = p0 + blockIdx.x * 128;

    const int lane = tid & 63;
    const int w    = tid >> 6;
    const int lr   = lane & 15;
    const int lg   = lane >> 4;
    const int eb0  = w * 32 + lr;
    const int eb1  = eb0 + 16;
    const int pA   = pbase + eb0;
    const int pB   = pbase + eb1;

    // ================= PREFETCH (issue all random gathers up front) =========
    const int eA = perm[pA < p1 ? pA : p0];
    const int eB = perm[pB < p1 ? pB : p0];
    const float ev0a = esh[(size_t)eA * 3 + 0];
    const float ev1a = esh[(size_t)eA * 3 + 1];
    const float ev2a = esh[(size_t)eA * 3 + 2];
    const float ev0b = esh[(size_t)eB * 3 + 0];
    const float ev1b = esh[(size_t)eB * 3 + 1];
    const float ev2b = esh[(size_t)eB * 3 + 2];
    const float cutA = ecut[eA];
    const float cutB = ecut[eB];

    // feature prefetch for staging role (t2 = edge slot, half = which tensor)
    const int t2 = tid >> 1, half = tid & 1;
    uint4 pf0, pf1, pf2, pf3, pf4, pf5;
    {
        int pS = pbase + t2;
        int eS = perm[pS < p1 ? pS : p0];
        int sS = esrc[eS];
        if (half == 0) {
            const uint4* nr = reinterpret_cast<const uint4*>(pNS + (size_t)sS * 32);
            pf0 = nr[0]; pf1 = nr[1]; pf2 = nr[2]; pf3 = nr[3];
        } else {
            const uint4* vr = reinterpret_cast<const uint4*>(pNV + (size_t)sS * 48);
            pf0 = vr[0]; pf1 = vr[1]; pf2 = vr[2]; pf3 = vr[3]; pf4 = vr[4]; pf5 = vr[5];
        }
    }

    const uint4* wsrc = reinterpret_cast<const uint4*>(pW);

    // ---- phase 1: copy W0T+W1T (896 uint4), stage X from einv (f32) ----
    {
        uint4* s4 = reinterpret_cast<uint4*>(smem);
        #pragma unroll 2
        for (int i = tid; i < 896; i += 256) s4[i] = wsrc[i];
    }
    if (tid < 128) {
        int p = pbase + tid;
        int e = perm[p < p1 ? p : p0];
        const float4* xr = reinterpret_cast<const float4*>(einv + (size_t)e * INVD);
        unsigned int pk[8];
        #pragma unroll
        for (int q = 0; q < 4; q++) {
            float4 v = xr[q];
            pk[2*q+0] = (unsigned int)f2bf(v.x) | ((unsigned int)f2bf(v.y) << 16);
            pk[2*q+1] = (unsigned int)f2bf(v.z) | ((unsigned int)f2bf(v.w) << 16);
        }
        uint4* r4 = reinterpret_cast<uint4*>(&act0[tid * 72]);
        r4[0] = make_uint4(pk[0], pk[1], pk[2], pk[3]);
        r4[1] = make_uint4(pk[4], pk[5], pk[6], pk[7]);
        r4[2] = make_uint4(0u, 0u, 0u, 0u);
        r4[3] = make_uint4(0u, 0u, 0u, 0u);
    }
    __syncthreads();

    const f32x4 zero4 = {0.f, 0.f, 0.f, 0.f};

    // ---- Layer 1: h1 = silu((X@W0)/4) ----
    {
        bf16x8 b0 = *(const bf16x8*)&act0[eb0 * 72 + lg * 8];
        bf16x8 b1 = *(const bf16x8*)&act0[eb1 * 72 + lg * 8];
        #pragma unroll
        for (int jt = 0; jt < 4; jt++) {
            bf16x8 a = *(const bf16x8*)&sW0T[(jt * 16 + lr) * 40 + lg * 8];
            f32x4 d0 = __builtin_amdgcn_mfma_f32_16x16x32_bf16(a, b0, zero4, 0, 0, 0);
            f32x4 d1 = __builtin_amdgcn_mfma_f32_16x16x32_bf16(a, b1, zero4, 0, 0, 0);
            unsigned int u0, u1;
            u0 = (unsigned int)f2bf(silu_f(d0[0] * 0.25f)) | ((unsigned int)f2bf(silu_f(d0[1] * 0.25f)) << 16);
            u1 = (unsigned int)f2bf(silu_f(d0[2] * 0.25f)) | ((unsigned int)f2bf(silu_f(d0[3] * 0.25f)) << 16);
            *(uint2*)&act1[eb0 * 72 + jt * 16 + lg * 4] = make_uint2(u0, u1);
            u0 = (unsigned int)f2bf(silu_f(d1[0] * 0.25f)) | ((unsigned int)f2bf(silu_f(d1[1] * 0.25f)) << 16);
            u1 = (unsigned int)f2bf(silu_f(d1[2] * 0.25f)) | ((unsigned int)f2bf(silu_f(d1[3] * 0.25f)) << 16);
            *(uint2*)&act1[eb1 * 72 + jt * 16 + lg * 4] = make_uint2(u0, u1);
        }
    }

    // ---- Layer 2: h2 = silu((h1@W1)/8) ----
    {
        bf16x8 b00 = *(const bf16x8*)&act1[eb0 * 72 +      lg * 8];
        bf16x8 b01 = *(const bf16x8*)&act1[eb0 * 72 + 32 + lg * 8];
        bf16x8 b10 = *(const bf16x8*)&act1[eb1 * 72 +      lg * 8];
        bf16x8 b11 = *(const bf16x8*)&act1[eb1 * 72 + 32 + lg * 8];
        #pragma unroll
        for (int jt = 0; jt < 4; jt++) {
            bf16x8 a0 = *(const bf16x8*)&sW1T[(jt * 16 + lr) * 72 +      lg * 8];
            bf16x8 a1 = *(const bf16x8*)&sW1T[(jt * 16 + lr) * 72 + 32 + lg * 8];
            f32x4 d0 = __builtin_amdgcn_mfma_f32_16x16x32_bf16(a0, b00, zero4, 0, 0, 0);
            d0 = __builtin_amdgcn_mfma_f32_16x16x32_bf16(a1, b01, d0, 0, 0, 0);
            f32x4 d1 = __builtin_amdgcn_mfma_f32_16x16x32_bf16(a0, b10, zero4, 0, 0, 0);
            d1 = __builtin_amdgcn_mfma_f32_16x16x32_bf16(a1, b11, d1, 0, 0, 0);
            unsigned int u0, u1;
            u0 = (unsigned int)f2bf(silu_f(d0[0] * 0.125f)) | ((unsigned int)f2bf(silu_f(d0[1] * 0.125f)) << 16);
            u1 = (unsigned int)f2bf(silu_f(d0[2] * 0.125f)) | ((unsigned int)f2bf(silu_f(d0[3] * 0.125f)) << 16);
            *(uint2*)&act0[eb0 * 72 + jt * 16 + lg * 4] = make_uint2(u0, u1);
            u0 = (unsigned int)f2bf(silu_f(d1[0] * 0.125f)) | ((unsigned int)f2bf(silu_f(d1[1] * 0.125f)) << 16);
            u1 = (unsigned int)f2bf(silu_f(d1[2] * 0.125f)) | ((unsigned int)f2bf(silu_f(d1[3] * 0.125f)) << 16);
            *(uint2*)&act0[eb1 * 72 + jt * 16 + lg * 4] = make_uint2(u0, u1);
        }
    }

    // ---- stage W2T into act1 ----
    __syncthreads();
    {
        uint4* a14 = reinterpret_cast<uint4*>(act1);
        const uint4* w2s = wsrc + 896;
        #pragma unroll 2
        for (int i = tid; i < 864; i += 256) a14[i] = w2s[i];
    }
    __syncthreads();

    // ---- Layer 3: fac -> registers (scales folded) ----
    float fac0[6][4], fac1[6][4];
    {
        bf16x8 b00 = *(const bf16x8*)&act0[eb0 * 72 +      lg * 8];
        bf16x8 b01 = *(const bf16x8*)&act0[eb0 * 72 + 32 + lg * 8];
        bf16x8 b10 = *(const bf16x8*)&act0[eb1 * 72 +      lg * 8];
        bf16x8 b11 = *(const bf16x8*)&act0[eb1 * 72 + 32 + lg * 8];
        float K0 = cutA * 0.125f * ISQ48;
        float K1 = cutB * 0.125f * ISQ48;
        #pragma unroll
        for (int jt = 0; jt < 6; jt++) {
            bf16x8 a0 = *(const bf16x8*)&act1[(jt * 16 + lr) * 72 +      lg * 8];
            bf16x8 a1 = *(const bf16x8*)&act1[(jt * 16 + lr) * 72 + 32 + lg * 8];
            f32x4 d0 = __builtin_amdgcn_mfma_f32_16x16x32_bf16(a0, b00, zero4, 0, 0, 0);
            d0 = __builtin_amdgcn_mfma_f32_16x16x32_bf16(a1, b01, d0, 0, 0, 0);
            f32x4 d1 = __builtin_amdgcn_mfma_f32_16x16x32_bf16(a0, b10, zero4, 0, 0, 0);
            d1 = __builtin_amdgcn_mfma_f32_16x16x32_bf16(a1, b11, d1, 0, 0, 0);
            float s0 = (jt == 0) ? K0 * ISQRT3 : K0;
            float s1 = (jt == 0) ? K1 * ISQRT3 : K1;
            #pragma unroll
            for (int q = 0; q < 4; q++) {
                fac0[jt][q] = d0[q] * s0;
                fac1[jt][q] = d1[q] * s1;
            }
        }
    }
    __syncthreads();

    // ---- phase 6: write PREFETCHED features to LDS + copy WLT ----
    {
        if (half == 0) {
            uint4 vv[4] = {pf0, pf1, pf2, pf3};
            #pragma unroll
            for (int q = 0; q < 4; q++) {
                uint4 v = vv[q];
                unsigned short* d = &Fns[t2 * 33 + 8 * q];
                d[0] = (unsigned short)v.x; d[1] = (unsigned short)(v.x >> 16);
                d[2] = (unsigned short)v.y; d[3] = (unsigned short)(v.y >> 16);
                d[4] = (unsigned short)v.z; d[5] = (unsigned short)(v.z >> 16);
                d[6] = (unsigned short)v.w; d[7] = (unsigned short)(v.w >> 16);
            }
        } else {
            uint4 vv[6] = {pf0, pf1, pf2, pf3, pf4, pf5};
            #pragma unroll
            for (int q = 0; q < 6; q++) {
                uint4 v = vv[q];
                unsigned short* d = &Fnv[t2 * 49 + 8 * q];
                d[0] = (unsigned short)v.x; d[1] = (unsigned short)(v.x >> 16);
                d[2] = (unsigned short)v.y; d[3] = (unsigned short)(v.y >> 16);
                d[4] = (unsigned short)v.z; d[5] = (unsigned short)(v.z >> 16);
                d[6] = (unsigned short)v.w; d[7] = (unsigned short)(v.w >> 16);
            }
        }
        uint4* wl4 = reinterpret_cast<uint4*>(sWLT);
        const uint4* wls = wsrc + 896 + 864;
        #pragma unroll 2
        for (int i = tid; i < 432; i += 256) wl4[i] = wls[i];
    }
    __syncthreads();

    // ---- M_s fill ----
    #pragma unroll
    for (int jt = 0; jt < 3; jt++) {
        int c0 = jt * 16 + lg * 4;
        float vA[4], vB[4];
        #pragma unroll
        for (int q = 0; q < 4; q++) {
            int c = c0 + q;
            float fa, fb;
            if (jt == 0) {
                fa = bf2f(Fnv[eb0 * 49 + 3*c + 0]) * ev0a
                   + bf2f(Fnv[eb0 * 49 + 3*c + 1]) * ev1a
                   + bf2f(Fnv[eb0 * 49 + 3*c + 2]) * ev2a;
                fb = bf2f(Fnv[eb1 * 49 + 3*c + 0]) * ev0b
                   + bf2f(Fnv[eb1 * 49 + 3*c + 1]) * ev1b
                   + bf2f(Fnv[eb1 * 49 + 3*c + 2]) * ev2b;
            } else {
                fa = bf2f(Fns[eb0 * 33 + (c - 16)]);
                fb = bf2f(Fns[eb1 * 33 + (c - 16)]);
            }
            vA[q] = fa * fac0[jt][q];
            vB[q] = fb * fac1[jt][q];
        }
        unsigned int w0 = (unsigned int)f2bf(vA[0]) | ((unsigned int)f2bf(vA[1]) << 16);
        unsigned int w1 = (unsigned int)f2bf(vA[2]) | ((unsigned int)f2bf(vA[3]) << 16);
        *(uint2*)&M[eb0 * 72 + c0] = make_uint2(w0, w1);
        w0 = (unsigned int)f2bf(vB[0]) | ((unsigned int)f2bf(vB[1]) << 16);
        w1 = (unsigned int)f2bf(vB[2]) | ((unsigned int)f2bf(vB[3]) << 16);
        *(uint2*)&M[eb1 * 72 + c0] = make_uint2(w0, w1);
    }
    *(uint2*)&M[eb0 * 72 + 48 + lg * 4] = make_uint2(0u, 0u);
    *(uint2*)&M[eb1 * 72 + 48 + lg * 4] = make_uint2(0u, 0u);

    // ---- ys GEMM + store cols 0..31 (uint2 x2 per edge) ----
    {
        f32x4 acc[2][2] = {{zero4, zero4}, {zero4, zero4}};
        #pragma unroll
        for (int kt = 0; kt < 2; kt++) {
            bf16x8 b0 = *(const bf16x8*)&M[eb0 * 72 + kt * 32 + lg * 8];
            bf16x8 b1 = *(const bf16x8*)&M[eb1 * 72 + kt * 32 + lg * 8];
            #pragma unroll
            for (int ot = 0; ot < 2; ot++) {
                bf16x8 a = *(const bf16x8*)&sWLT[(ot * 16 + lr) * 72 + kt * 32 + lg * 8];
                acc[0][ot] = __builtin_amdgcn_mfma_f32_16x16x32_bf16(a, b0, acc[0][ot], 0, 0, 0);
                acc[1][ot] = __builtin_amdgcn_mfma_f32_16x16x32_bf16(a, b1, acc[1][ot], 0, 0, 0);
            }
        }
        #pragma unroll
        for (int ot = 0; ot < 2; ot++) {
            if (pA < p1) {
                __half2 ha = __floats2half2_rn(acc[0][ot][0], acc[0][ot][1]);
                __half2 hb = __floats2half2_rn(acc[0][ot][2], acc[0][ot][3]);
                *(uint2*)(cont + (size_t)(pA - p0) * CPITCH + ot * 16 + lg * 4) =
                    make_uint2(*(unsigned int*)&ha, *(unsigned int*)&hb);
            }
            if (pB < p1) {
                __half2 ha = __floats2half2_rn(acc[1][ot][0], acc[1][ot][1]);
                __half2 hb = __floats2half2_rn(acc[1][ot][2], acc[1][ot][3]);
                *(uint2*)(cont + (size_t)(pB - p0) * CPITCH + ot * 16 + lg * 4) =
                    make_uint2(*(unsigned int*)&ha, *(unsigned int*)&hb);
            }
        }
    }

    // ---- vector path: 3 components, fully unrolled; collect 12 halves/edge
    //      in registers, write as 3 x uint2 (24B contiguous per edge) ----
    unsigned short hA[12], hB[12];
    #pragma unroll
    for (int i = 0; i < 3; i++) {
        float evA = (i == 0) ? ev0a : ((i == 1) ? ev1a : ev2a);
        float evB = (i == 0) ? ev0b : ((i == 1) ? ev1b : ev2b);
        #pragma unroll
        for (int jt = 0; jt < 3; jt++) {
            int c0 = jt * 16 + lg * 4;
            float vA[4], vB[4];
            #pragma unroll
            for (int q = 0; q < 4; q++) {
                int r = c0 + q;
                float fa, fb;
                if (jt < 2) {
                    fa = bf2f(Fns[eb0 * 33 + r]) * evA;
                    fb = bf2f(Fns[eb1 * 33 + r]) * evB;
                } else {
                    fa = bf2f(Fnv[eb0 * 49 + 3 * (r - 32) + i]);
                    fb = bf2f(Fnv[eb1 * 49 + 3 * (r - 32) + i]);
                }
                vA[q] = fa * fac0[3 + jt][q];
                vB[q] = fb * fac1[3 + jt][q];
            }
            unsigned int w0 = (unsigned int)f2bf(vA[0]) | ((unsigned int)f2bf(vA[1]) << 16);
            unsigned int w1 = (unsigned int)f2bf(vA[2]) | ((unsigned int)f2bf(vA[3]) << 16);
            *(uint2*)&M[eb0 * 72 + c0] = make_uint2(w0, w1);
            w0 = (unsigned int)f2bf(vB[0]) | ((unsigned int)f2bf(vB[1]) << 16);
            w1 = (unsigned int)f2bf(vB[2]) | ((unsigned int)f2bf(vB[3]) << 16);
            *(uint2*)&M[eb1 * 72 + c0] = make_uint2(w0, w1);
        }
        f32x4 acc0 = zero4, acc1 = zero4;
        #pragma unroll
        for (int kt = 0; kt < 2; kt++) {
            bf16x8 b0 = *(const bf16x8*)&M[eb0 * 72 + kt * 32 + lg * 8];
            bf16x8 b1 = *(const bf16x8*)&M[eb1 * 72 + kt * 32 + lg * 8];
            bf16x8 a  = *(const bf16x8*)&sWLT[(32 + lr) * 72 + kt * 32 + lg * 8];
            acc0 = __builtin_amdgcn_mfma_f32_16x16x32_bf16(a, b0, acc0, 0, 0, 0);
            acc1 = __builtin_amdgcn_mfma_f32_16x16x32_bf16(a, b1, acc1, 0, 0, 0);
        }
        #pragma unroll
        for (int q = 0; q < 4; q++) {
            hA[3 * q + i] = __half_as_ushort(__float2half(acc0[q]));
            hB[3 * q + i] = __half_as_ushort(__float2half(acc1[q]));
        }
    }
    if (pA < p1) {
        unsigned int u0 = (unsigned int)hA[0] | ((unsigned int)hA[1]  << 16);
        unsigned int u1 = (unsigned int)hA[2] | ((unsigned int)hA[3]  << 16);
        unsigned int u2 = (unsigned int)hA[4] | ((unsigned int)hA[5]  << 16);
        unsigned int u3 = (unsigned int)hA[6] | ((unsigned int)hA[7]  << 16);
        unsigned int u4 = (unsigned int)hA[8] | ((unsigned int)hA[9]  << 16);
        unsigned int u5 = (unsigned int)hA[10]| ((unsigned int)hA[11] << 16);
        uint2* d = (uint2*)(cont + (size_t)(pA - p0) * CPITCH + 32 + 12 * lg);
        d[0] = make_uint2(u0, u1); d[1] = make_uint2(u2, u3); d[2] = make_uint2(u4, u5);
    }
    if (pB < p1) {
        unsigned int u0 = (unsigned int)hB[0] | ((unsigned int)hB[1]  << 16);
        unsigned int u1 = (unsigned int)hB[2] | ((unsigned int)hB[3]  << 16);
        unsigned int u2 = (unsigned int)hB[4] | ((unsigned int)hB[5]  << 16);
        unsigned int u3 = (unsigned int)hB[6] | ((unsigned int)hB[7]  << 16);
        unsigned int u4 = (unsigned int)hB[8] | ((unsigned int)hB[9]  << 16);
        unsigned int u5 = (unsigned int)hB[10]| ((unsigned int)hB[11] << 16);
        uint2* d = (uint2*)(cont + (size_t)(pB - p0) * CPITCH + 32 + 12 * lg);
        d[0] = make_uint2(u0, u1); d[1] = make_uint2(u2, u3); d[2] = make_uint2(u4, u5);
    }
}

// ---------------------------------------------------------------------------
// Gather: one wave per node; lane l<40 reads uint (2 fp16) per row, float2 out.
// ---------------------------------------------------------------------------
__global__ __launch_bounds__(256) void gather_sum(
    const int*    __restrict__ offs,
    const __half* __restrict__ cont,
    float* __restrict__ out,
    int Nn, int p0, int p1)
{
    int wid = (blockIdx.x * 256 + threadIdx.x) >> 6;
    int l = threadIdx.x & 63;
    if (wid >= Nn || l >= 40) return;
    int beg = offs[wid], end = offs[wid + 1];
    int lo = beg > p0 ? beg : p0;
    int hi = end < p1 ? end : p1;
    if (lo >= hi) return;

    float a0 = 0.0f, a1 = 0.0f;
    const unsigned int* row = reinterpret_cast<const unsigned int*>(
        cont + (size_t)(lo - p0) * CPITCH) + l;
    for (int p = lo; p < hi; ++p, row += CPITCH / 2) {
        unsigned int v = *row;
        __half2 h2 = *reinterpret_cast<const __half2*>(&v);
        float2 f2 = __half22float2(h2);
        a0 += f2.x;
        a1 += f2.y;
    }
    float2* o2 = reinterpret_cast<float2*>(out + (size_t)wid * OUT_PER_NODE + 2 * l);
    float2 cur = *o2;
    cur.x += a0; cur.y += a1;
    *o2 = cur;
}

// ---------------------------------------------------------------------------
extern "C" void kernel_launch(void* const* d_in, const int* in_sizes, int n_in,
                              void* d_out, int out_size, void* d_ws, size_t ws_size,
                              hipStream_t stream) {
    const int*   esrc = (const int*)  d_in[0];
    const int*   edst = (const int*)  d_in[1];
    const float* ecut = (const float*)d_in[2];
    const float* einv = (const float*)d_in[3];
    const float* ns   = (const float*)d_in[4];
    const float* nv   = (const float*)d_in[5];
    const float* esh  = (const float*)d_in[6];
    const float* W0   = (const float*)d_in[7];
    const float* W1   = (const float*)d_in[8];
    const float* W2   = (const float*)d_in[9];
    const float* WLs  = (const float*)d_in[10];
    const float* WLv  = (const float*)d_in[11];
    float* out = (float*)d_out;

    const int E  = in_sizes[0];
    const int Nn = in_sizes[4] / S_IN;

    size_t int_bytes = (((size_t)(3 * Nn + 1 + E)) * sizeof(int) + 255) & ~(size_t)255;
    size_t pw_bytes  = ((size_t)PWTOT * 2 + 255) & ~(size_t)255;
    size_t ns_bytes  = ((size_t)Nn * 32 * 2 + 255) & ~(size_t)255;
    size_t nv_bytes  = ((size_t)Nn * 48 * 2 + 255) & ~(size_t)255;
    size_t fixed = int_bytes + pw_bytes + ns_bytes + nv_bytes;

    int eblocks = (E + 255) / 256;

    hipMemsetAsync(out, 0, (size_t)Nn * OUT_PER_NODE * sizeof(float), stream);

    int*            deg    = (int*)d_ws;
    int*            offs   = deg + Nn;
    int*            cursor = offs + Nn + 1;
    int*            perm   = cursor + Nn;
    unsigned short* pW     = (unsigned short*)((char*)d_ws + int_bytes);
    unsigned short* pNS    = (unsigned short*)((char*)d_ws + int_bytes + pw_bytes);
    unsigned short* pNV    = (unsigned short*)((char*)d_ws + int_bytes + pw_bytes + ns_bytes);
    __half*         cont   = (__half*)((char*)d_ws + fixed);

    size_t avail = (ws_size > fixed) ? (ws_size - fixed) : 0;
    int chunkE = (int)(avail / ((size_t)CPITCH * sizeof(__half)));
    if (chunkE > E) chunkE = E;
    chunkE &= ~127;   // keep chunks a multiple of the 128-edge block

    if (chunkE >= 4096) {
        hipMemsetAsync(deg, 0, (size_t)Nn * sizeof(int), stream);
        hist_kernel<<<eblocks, 256, 0, stream>>>(edst, deg, E);
        scan_kernel<<<1, 1024, 0, stream>>>(deg, offs, cursor, Nn);
        scatter_kernel<<<eblocks, 256, 0, stream>>>(edst, cursor, perm, E);

        prep_weights<<<(PWTOT + 255) / 256, 256, 0, stream>>>(W0, W1, W2, WLs, WLv, pW);
        cast_bf16<<<((Nn * 32 / 8) + 255) / 256, 256, 0, stream>>>(ns, pNS, Nn * 32 / 8);
        cast_bf16<<<((Nn * 48 / 8) + 255) / 256, 256, 0, stream>>>(nv, pNV, Nn * 48 / 8);

        int gblocks = (Nn + 3) / 4;
        for (int p0 = 0; p0 < E; p0 += chunkE) {
            int p1 = p0 + chunkE; if (p1 > E) p1 = E;
            int n = p1 - p0;
            int mblocks = (n + 127) / 128;
            edge_mega<<<mblocks, 256, 0, stream>>>(perm, esrc, ecut, esh, einv,
                                                   pW, pNS, pNV, cont, p0, p1);
            gather_sum<<<gblocks, 256, 0, stream>>>(offs, cont, out, Nn, p0, p1);
        }
    }
}

// Round 12
// 393.853 us; speedup vs baseline: 3.1851x; 1.0715x over previous
//
#include <hip/hip_runtime.h>
#include <hip/hip_fp16.h>
#include <math.h>

// Problem constants
constexpr int S_IN = 32, V_IN = 16, INVD = 16;
constexpr int S_MSG = S_IN + V_IN;           // 48
constexpr int V_MSG = S_IN + V_IN;           // 48
constexpr int NFAC  = S_MSG + V_MSG;         // 96
constexpr int S_OUT = 32, V_OUT = 16;
constexpr int OUT_PER_NODE = S_OUT + V_OUT * 3;  // 80
constexpr float ISQRT3 = 0.57735026918962576f;
constexpr float ISQ48  = 0.14433756729740643f;

// prepped-weight layout (in shorts): W0T[64][40] | W1T[64][72] | W2T[96][72] | WLT[48][72]
constexpr int PW0 = 0, PW1 = 2560, PW2 = 7168, PWL = 14080, PWTOT = 17536;

typedef __attribute__((ext_vector_type(8))) short bf16x8;
typedef __attribute__((ext_vector_type(4))) float f32x4;

__device__ __forceinline__ float silu_f(float x) {
    return x / (1.0f + __expf(-x));
}
__device__ __forceinline__ unsigned short f2bf(float f) {
    unsigned int u = __float_as_uint(f);
    u += 0x7FFFu + ((u >> 16) & 1u);
    return (unsigned short)(u >> 16);
}
__device__ __forceinline__ float bf2f(unsigned short h) {
    return __uint_as_float(((unsigned int)h) << 16);
}

// ---------------------------------------------------------------------------
// CSR construction
// ---------------------------------------------------------------------------
__global__ __launch_bounds__(256) void hist_kernel(
    const int* __restrict__ edst, int* __restrict__ deg, int E)
{
    int e = blockIdx.x * 256 + threadIdx.x;
    if (e < E) atomicAdd(&deg[edst[e]], 1);
}

__global__ __launch_bounds__(1024) void scan_kernel(
    const int* __restrict__ deg, int* __restrict__ offs,
    int* __restrict__ cursor, int Nn)
{
    const int T = 1024;
    int t = threadIdx.x;
    int chunk = (Nn + T - 1) / T;
    int lo = t * chunk;
    int hi = lo + chunk; if (hi > Nn) hi = Nn;
    int s = 0;
    for (int i = lo; i < hi; i++) s += deg[i];
    __shared__ int ps[T];
    ps[t] = s;
    __syncthreads();
    for (int off = 1; off < T; off <<= 1) {
        int v = (t >= off) ? ps[t - off] : 0;
        __syncthreads();
        ps[t] += v;
        __syncthreads();
    }
    int base = (t > 0) ? ps[t - 1] : 0;
    for (int i = lo; i < hi; i++) {
        offs[i] = base;
        cursor[i] = base;
        base += deg[i];
    }
    if (t == 0) offs[Nn] = ps[T - 1];
}

__global__ __launch_bounds__(256) void scatter_kernel(
    const int* __restrict__ edst, int* __restrict__ cursor,
    int* __restrict__ perm, int* __restrict__ pdst, int E)
{
    int e = blockIdx.x * 256 + threadIdx.x;
    if (e < E) {
        int d = edst[e];
        int pos = atomicAdd(&cursor[d], 1);
        perm[pos] = e;
        pdst[pos] = d;
    }
}

// ---------------------------------------------------------------------------
// Pre-pass: weights -> transposed/padded bf16; node features -> bf16
// ---------------------------------------------------------------------------
__global__ __launch_bounds__(256) void prep_weights(
    const float* __restrict__ W0, const float* __restrict__ W1,
    const float* __restrict__ W2, const float* __restrict__ WLs,
    const float* __restrict__ WLv, unsigned short* __restrict__ pW)
{
    int i = blockIdx.x * 256 + threadIdx.x;
    if (i >= PWTOT) return;
    float v = 0.0f;
    if (i < PW1) {
        int j = i / 40, k = i - 40 * j;
        if (k < INVD) v = W0[k * 64 + j];
    } else if (i < PW2) {
        int t = i - PW1; int j = t / 72, k = t - 72 * j;
        if (k < 64) v = W1[k * 64 + j];
    } else if (i < PWL) {
        int t = i - PW2; int j = t / 72, k = t - 72 * j;
        if (k < 64) v = W2[k * 96 + j];
    } else {
        int t = i - PWL; int j = t / 72, k = t - 72 * j;
        if (k < 48) v = (j < 32) ? WLs[k * S_OUT + j] : WLv[k * V_OUT + (j - 32)];
    }
    pW[i] = f2bf(v);
}

__global__ __launch_bounds__(256) void cast_bf16(
    const float* __restrict__ src, unsigned short* __restrict__ dst, int n8)
{
    int i = blockIdx.x * 256 + threadIdx.x;
    if (i >= n8) return;
    const float4* s4 = reinterpret_cast<const float4*>(src + (size_t)i * 8);
    float4 a = s4[0], b = s4[1];
    uint4 o;
    o.x = (unsigned int)f2bf(a.x) | ((unsigned int)f2bf(a.y) << 16);
    o.y = (unsigned int)f2bf(a.z) | ((unsigned int)f2bf(a.w) << 16);
    o.z = (unsigned int)f2bf(b.x) | ((unsigned int)f2bf(b.y) << 16);
    o.w = (unsigned int)f2bf(b.z) | ((unsigned int)f2bf(b.w) << 16);
    *reinterpret_cast<uint4*>(dst + (size_t)i * 8) = o;
}

// ---------------------------------------------------------------------------
// MEGA kernel v4: fused MLP + WL + in-block segmented reduction -> atomicAdd
// into out. Block = 128 edges (sorted by dst), 4 waves x 32 edges.
// ---------------------------------------------------------------------------
__global__ __launch_bounds__(256, 3) void edge_mega(
    const int*   __restrict__ perm,
    const int*   __restrict__ pdst,
    const int*   __restrict__ esrc,
    const float* __restrict__ ecut,
    const float* __restrict__ esh,
    const float* __restrict__ einv,
    const unsigned short* __restrict__ pW,
    const unsigned short* __restrict__ pNS,
    const unsigned short* __restrict__ pNV,
    float* __restrict__ out,
    int E)
{
    __shared__ __align__(16) unsigned char smem[53760];

    unsigned short* sW0T = (unsigned short*)(smem + 0);      // [64][40]  (phase A)
    unsigned short* sW1T = (unsigned short*)(smem + 5120);   // [64][72]  (phase A)
    unsigned short* act0 = (unsigned short*)(smem + 14336);  // [128][72] (phase A)
    unsigned short* act1 = (unsigned short*)(smem + 32768);  // [128][72] (phase A)
    unsigned short* sWLT = (unsigned short*)(smem + 5120);   // [48][72]  (phase B)
    unsigned short* M    = (unsigned short*)(smem + 14336);  // [128][72] (phase B)
    unsigned short* Fns  = (unsigned short*)(smem + 32768);  // [128][33] (phase B)
    unsigned short* Fnv  = (unsigned short*)(smem + 41216);  // [128][49] (phase B)
    float*          redf = (float*)smem;                     // [128][80] (phase C)
    int*            sdst = (int*)(smem + 49152);             // [128]     (phase C)

    const int tid = threadIdx.x;
    const int pbase = blockIdx.x * 128;
    const int p1 = E;

    const int lane = tid & 63;
    const int w    = tid >> 6;
    const int lr   = lane & 15;
    const int lg   = lane >> 4;
    const int eb0  = w * 32 + lr;
    const int eb1  = eb0 + 16;
    const int pA   = pbase + eb0;
    const int pB   = pbase + eb1;

    // ================= PREFETCH (issue all random gathers up front) =========
    const int eA = perm[pA < p1 ? pA : p1 - 1];
    const int eB = perm[pB < p1 ? pB : p1 - 1];
    const float ev0a = esh[(size_t)eA * 3 + 0];
    const float ev1a = esh[(size_t)eA * 3 + 1];
    const float ev2a = esh[(size_t)eA * 3 + 2];
    const float ev0b = esh[(size_t)eB * 3 + 0];
    const float ev1b = esh[(size_t)eB * 3 + 1];
    const float ev2b = esh[(size_t)eB * 3 + 2];
    const float cutA = ecut[eA];
    const float cutB = ecut[eB];

    int dstS = 0;
    if (tid < 128) {
        int p = pbase + tid; if (p >= p1) p = p1 - 1;
        dstS = pdst[p];
    }

    // feature prefetch for staging role (t2 = edge slot, half = which tensor)
    const int t2 = tid >> 1, half = tid & 1;
    uint4 pf0, pf1, pf2, pf3, pf4, pf5;
    {
        int pS = pbase + t2; if (pS >= p1) pS = p1 - 1;
        int eS = perm[pS];
        int sS = esrc[eS];
        if (half == 0) {
            const uint4* nr = reinterpret_cast<const uint4*>(pNS + (size_t)sS * 32);
            pf0 = nr[0]; pf1 = nr[1]; pf2 = nr[2]; pf3 = nr[3];
        } else {
            const uint4* vr = reinterpret_cast<const uint4*>(pNV + (size_t)sS * 48);
            pf0 = vr[0]; pf1 = vr[1]; pf2 = vr[2]; pf3 = vr[3]; pf4 = vr[4]; pf5 = vr[5];
        }
    }

    const uint4* wsrc = reinterpret_cast<const uint4*>(pW);

    // ---- phase 1: copy W0T+W1T (896 uint4), stage X from einv (f32) ----
    {
        uint4* s4 = reinterpret_cast<uint4*>(smem);
        #pragma unroll 2
        for (int i = tid; i < 896; i += 256) s4[i] = wsrc[i];
    }
    if (tid < 128) {
        int p = pbase + tid;
        int e = perm[p < p1 ? p : p1 - 1];
        const float4* xr = reinterpret_cast<const float4*>(einv + (size_t)e * INVD);
        unsigned int pk[8];
        #pragma unroll
        for (int q = 0; q < 4; q++) {
            float4 v = xr[q];
            pk[2*q+0] = (unsigned int)f2bf(v.x) | ((unsigned int)f2bf(v.y) << 16);
            pk[2*q+1] = (unsigned int)f2bf(v.z) | ((unsigned int)f2bf(v.w) << 16);
        }
        uint4* r4 = reinterpret_cast<uint4*>(&act0[tid * 72]);
        r4[0] = make_uint4(pk[0], pk[1], pk[2], pk[3]);
        r4[1] = make_uint4(pk[4], pk[5], pk[6], pk[7]);
        r4[2] = make_uint4(0u, 0u, 0u, 0u);
        r4[3] = make_uint4(0u, 0u, 0u, 0u);
    }
    __syncthreads();

    const f32x4 zero4 = {0.f, 0.f, 0.f, 0.f};

    // ---- Layer 1: h1 = silu((X@W0)/4) ----
    {
        bf16x8 b0 = *(const bf16x8*)&act0[eb0 * 72 + lg * 8];
        bf16x8 b1 = *(const bf16x8*)&act0[eb1 * 72 + lg * 8];
        #pragma unroll
        for (int jt = 0; jt < 4; jt++) {
            bf16x8 a = *(const bf16x8*)&sW0T[(jt * 16 + lr) * 40 + lg * 8];
            f32x4 d0 = __builtin_amdgcn_mfma_f32_16x16x32_bf16(a, b0, zero4, 0, 0, 0);
            f32x4 d1 = __builtin_amdgcn_mfma_f32_16x16x32_bf16(a, b1, zero4, 0, 0, 0);
            unsigned int u0, u1;
            u0 = (unsigned int)f2bf(silu_f(d0[0] * 0.25f)) | ((unsigned int)f2bf(silu_f(d0[1] * 0.25f)) << 16);
            u1 = (unsigned int)f2bf(silu_f(d0[2] * 0.25f)) | ((unsigned int)f2bf(silu_f(d0[3] * 0.25f)) << 16);
            *(uint2*)&act1[eb0 * 72 + jt * 16 + lg * 4] = make_uint2(u0, u1);
            u0 = (unsigned int)f2bf(silu_f(d1[0] * 0.25f)) | ((unsigned int)f2bf(silu_f(d1[1] * 0.25f)) << 16);
            u1 = (unsigned int)f2bf(silu_f(d1[2] * 0.25f)) | ((unsigned int)f2bf(silu_f(d1[3] * 0.25f)) << 16);
            *(uint2*)&act1[eb1 * 72 + jt * 16 + lg * 4] = make_uint2(u0, u1);
        }
    }

    // ---- Layer 2: h2 = silu((h1@W1)/8) ----
    {
        bf16x8 b00 = *(const bf16x8*)&act1[eb0 * 72 +      lg * 8];
        bf16x8 b01 = *(const bf16x8*)&act1[eb0 * 72 + 32 + lg * 8];
        bf16x8 b10 = *(const bf16x8*)&act1[eb1 * 72 +      lg * 8];
        bf16x8 b11 = *(const bf16x8*)&act1[eb1 * 72 + 32 + lg * 8];
        #pragma unroll
        for (int jt = 0; jt < 4; jt++) {
            bf16x8 a0 = *(const bf16x8*)&sW1T[(jt * 16 + lr) * 72 +      lg * 8];
            bf16x8 a1 = *(const bf16x8*)&sW1T[(jt * 16 + lr) * 72 + 32 + lg * 8];
            f32x4 d0 = __builtin_amdgcn_mfma_f32_16x16x32_bf16(a0, b00, zero4, 0, 0, 0);
            d0 = __builtin_amdgcn_mfma_f32_16x16x32_bf16(a1, b01, d0, 0, 0, 0);
            f32x4 d1 = __builtin_amdgcn_mfma_f32_16x16x32_bf16(a0, b10, zero4, 0, 0, 0);
            d1 = __builtin_amdgcn_mfma_f32_16x16x32_bf16(a1, b11, d1, 0, 0, 0);
            unsigned int u0, u1;
            u0 = (unsigned int)f2bf(silu_f(d0[0] * 0.125f)) | ((unsigned int)f2bf(silu_f(d0[1] * 0.125f)) << 16);
            u1 = (unsigned int)f2bf(silu_f(d0[2] * 0.125f)) | ((unsigned int)f2bf(silu_f(d0[3] * 0.125f)) << 16);
            *(uint2*)&act0[eb0 * 72 + jt * 16 + lg * 4] = make_uint2(u0, u1);
            u0 = (unsigned int)f2bf(silu_f(d1[0] * 0.125f)) | ((unsigned int)f2bf(silu_f(d1[1] * 0.125f)) << 16);
            u1 = (unsigned int)f2bf(silu_f(d1[2] * 0.125f)) | ((unsigned int)f2bf(silu_f(d1[3] * 0.125f)) << 16);
            *(uint2*)&act0[eb1 * 72 + jt * 16 + lg * 4] = make_uint2(u0, u1);
        }
    }

    // ---- stage W2T into act1 ----
    __syncthreads();
    {
        uint4* a14 = reinterpret_cast<uint4*>(act1);
        const uint4* w2s = wsrc + 896;
        #pragma unroll 2
        for (int i = tid; i < 864; i += 256) a14[i] = w2s[i];
    }
    __syncthreads();

    // ---- Layer 3: fac -> registers (scales folded) ----
    float fac0[6][4], fac1[6][4];
    {
        bf16x8 b00 = *(const bf16x8*)&act0[eb0 * 72 +      lg * 8];
        bf16x8 b01 = *(const bf16x8*)&act0[eb0 * 72 + 32 + lg * 8];
        bf16x8 b10 = *(const bf16x8*)&act0[eb1 * 72 +      lg * 8];
        bf16x8 b11 = *(const bf16x8*)&act0[eb1 * 72 + 32 + lg * 8];
        float K0 = cutA * 0.125f * ISQ48;
        float K1 = cutB * 0.125f * ISQ48;
        #pragma unroll
        for (int jt = 0; jt < 6; jt++) {
            bf16x8 a0 = *(const bf16x8*)&act1[(jt * 16 + lr) * 72 +      lg * 8];
            bf16x8 a1 = *(const bf16x8*)&act1[(jt * 16 + lr) * 72 + 32 + lg * 8];
            f32x4 d0 = __builtin_amdgcn_mfma_f32_16x16x32_bf16(a0, b00, zero4, 0, 0, 0);
            d0 = __builtin_amdgcn_mfma_f32_16x16x32_bf16(a1, b01, d0, 0, 0, 0);
            f32x4 d1 = __builtin_amdgcn_mfma_f32_16x16x32_bf16(a0, b10, zero4, 0, 0, 0);
            d1 = __builtin_amdgcn_mfma_f32_16x16x32_bf16(a1, b11, d1, 0, 0, 0);
            float s0 = (jt == 0) ? K0 * ISQRT3 : K0;
            float s1 = (jt == 0) ? K1 * ISQRT3 : K1;
            #pragma unroll
            for (int q = 0; q < 4; q++) {
                fac0[jt][q] = d0[q] * s0;
                fac1[jt][q] = d1[q] * s1;
            }
        }
    }
    __syncthreads();

    // ---- phase 6: write PREFETCHED features to LDS + copy WLT ----
    {
        if (half == 0) {
            uint4 vv[4] = {pf0, pf1, pf2, pf3};
            #pragma unroll
            for (int q = 0; q < 4; q++) {
                uint4 v = vv[q];
                unsigned short* d = &Fns[t2 * 33 + 8 * q];
                d[0] = (unsigned short)v.x; d[1] = (unsigned short)(v.x >> 16);
                d[2] = (unsigned short)v.y; d[3] = (unsigned short)(v.y >> 16);
                d[4] = (unsigned short)v.z; d[5] = (unsigned short)(v.z >> 16);
                d[6] = (unsigned short)v.w; d[7] = (unsigned short)(v.w >> 16);
            }
        } else {
            uint4 vv[6] = {pf0, pf1, pf2, pf3, pf4, pf5};
            #pragma unroll
            for (int q = 0; q < 6; q++) {
                uint4 v = vv[q];
                unsigned short* d = &Fnv[t2 * 49 + 8 * q];
                d[0] = (unsigned short)v.x; d[1] = (unsigned short)(v.x >> 16);
                d[2] = (unsigned short)v.y; d[3] = (unsigned short)(v.y >> 16);
                d[4] = (unsigned short)v.z; d[5] = (unsigned short)(v.z >> 16);
                d[6] = (unsigned short)v.w; d[7] = (unsigned short)(v.w >> 16);
            }
        }
        uint4* wl4 = reinterpret_cast<uint4*>(sWLT);
        const uint4* wls = wsrc + 896 + 864;
        #pragma unroll 2
        for (int i = tid; i < 432; i += 256) wl4[i] = wls[i];
    }
    __syncthreads();

    // ---- M_s fill (48 gated scalar-message cols; 48..63 zero) ----
    #pragma unroll
    for (int jt = 0; jt < 3; jt++) {
        int c0 = jt * 16 + lg * 4;
        float vA[4], vB[4];
        #pragma unroll
        for (int q = 0; q < 4; q++) {
            int c = c0 + q;
            float fa, fb;
            if (jt == 0) {
                fa = bf2f(Fnv[eb0 * 49 + 3*c + 0]) * ev0a
                   + bf2f(Fnv[eb0 * 49 + 3*c + 1]) * ev1a
                   + bf2f(Fnv[eb0 * 49 + 3*c + 2]) * ev2a;
                fb = bf2f(Fnv[eb1 * 49 + 3*c + 0]) * ev0b
                   + bf2f(Fnv[eb1 * 49 + 3*c + 1]) * ev1b
                   + bf2f(Fnv[eb1 * 49 + 3*c + 2]) * ev2b;
            } else {
                fa = bf2f(Fns[eb0 * 33 + (c - 16)]);
                fb = bf2f(Fns[eb1 * 33 + (c - 16)]);
            }
            vA[q] = fa * fac0[jt][q];
            vB[q] = fb * fac1[jt][q];
        }
        unsigned int w0 = (unsigned int)f2bf(vA[0]) | ((unsigned int)f2bf(vA[1]) << 16);
        unsigned int w1 = (unsigned int)f2bf(vA[2]) | ((unsigned int)f2bf(vA[3]) << 16);
        *(uint2*)&M[eb0 * 72 + c0] = make_uint2(w0, w1);
        w0 = (unsigned int)f2bf(vB[0]) | ((unsigned int)f2bf(vB[1]) << 16);
        w1 = (unsigned int)f2bf(vB[2]) | ((unsigned int)f2bf(vB[3]) << 16);
        *(uint2*)&M[eb1 * 72 + c0] = make_uint2(w0, w1);
    }
    *(uint2*)&M[eb0 * 72 + 48 + lg * 4] = make_uint2(0u, 0u);
    *(uint2*)&M[eb1 * 72 + 48 + lg * 4] = make_uint2(0u, 0u);

    // ---- ys GEMM (keep in regs) ----
    f32x4 accS[2][2] = {{zero4, zero4}, {zero4, zero4}};
    #pragma unroll
    for (int kt = 0; kt < 2; kt++) {
        bf16x8 b0 = *(const bf16x8*)&M[eb0 * 72 + kt * 32 + lg * 8];
        bf16x8 b1 = *(const bf16x8*)&M[eb1 * 72 + kt * 32 + lg * 8];
        #pragma unroll
        for (int ot = 0; ot < 2; ot++) {
            bf16x8 a = *(const bf16x8*)&sWLT[(ot * 16 + lr) * 72 + kt * 32 + lg * 8];
            accS[0][ot] = __builtin_amdgcn_mfma_f32_16x16x32_bf16(a, b0, accS[0][ot], 0, 0, 0);
            accS[1][ot] = __builtin_amdgcn_mfma_f32_16x16x32_bf16(a, b1, accS[1][ot], 0, 0, 0);
        }
    }

    // ---- T1: (ns .* g2[0:32]) @ WLv[0:32], K=32, i-independent ----
    #pragma unroll
    for (int jt = 0; jt < 2; jt++) {
        int c0 = jt * 16 + lg * 4;
        float vA[4], vB[4];
        #pragma unroll
        for (int q = 0; q < 4; q++) {
            int c = c0 + q;
            vA[q] = bf2f(Fns[eb0 * 33 + c]) * fac0[3 + jt][q];
            vB[q] = bf2f(Fns[eb1 * 33 + c]) * fac1[3 + jt][q];
        }
        unsigned int w0 = (unsigned int)f2bf(vA[0]) | ((unsigned int)f2bf(vA[1]) << 16);
        unsigned int w1 = (unsigned int)f2bf(vA[2]) | ((unsigned int)f2bf(vA[3]) << 16);
        *(uint2*)&M[eb0 * 72 + c0] = make_uint2(w0, w1);
        w0 = (unsigned int)f2bf(vB[0]) | ((unsigned int)f2bf(vB[1]) << 16);
        w1 = (unsigned int)f2bf(vB[2]) | ((unsigned int)f2bf(vB[3]) << 16);
        *(uint2*)&M[eb1 * 72 + c0] = make_uint2(w0, w1);
    }
    f32x4 t1A = zero4, t1B = zero4;
    {
        bf16x8 b0 = *(const bf16x8*)&M[eb0 * 72 + lg * 8];
        bf16x8 b1 = *(const bf16x8*)&M[eb1 * 72 + lg * 8];
        bf16x8 a  = *(const bf16x8*)&sWLT[(32 + lr) * 72 + lg * 8];
        t1A = __builtin_amdgcn_mfma_f32_16x16x32_bf16(a, b0, t1A, 0, 0, 0);
        t1B = __builtin_amdgcn_mfma_f32_16x16x32_bf16(a, b1, t1B, 0, 0, 0);
    }

    // ---- T2_i: (nv_i .* g2[32:48]) @ WLv[32:48], K=16 (padded); combine ----
    float yvA[4][3], yvB[4][3];
    // zero pad cols 16..31 once (stays zero across i)
    *(uint2*)&M[eb0 * 72 + 16 + lg * 4] = make_uint2(0u, 0u);
    *(uint2*)&M[eb1 * 72 + 16 + lg * 4] = make_uint2(0u, 0u);
    #pragma unroll
    for (int i = 0; i < 3; i++) {
        int k0 = lg * 4;
        float vA[4], vB[4];
        #pragma unroll
        for (int q = 0; q < 4; q++) {
            int r = k0 + q;
            vA[q] = bf2f(Fnv[eb0 * 49 + 3 * r + i]) * fac0[5][q];
            vB[q] = bf2f(Fnv[eb1 * 49 + 3 * r + i]) * fac1[5][q];
        }
        unsigned int w0 = (unsigned int)f2bf(vA[0]) | ((unsigned int)f2bf(vA[1]) << 16);
        unsigned int w1 = (unsigned int)f2bf(vA[2]) | ((unsigned int)f2bf(vA[3]) << 16);
        *(uint2*)&M[eb0 * 72 + k0] = make_uint2(w0, w1);
        w0 = (unsigned int)f2bf(vB[0]) | ((unsigned int)f2bf(vB[1]) << 16);
        w1 = (unsigned int)f2bf(vB[2]) | ((unsigned int)f2bf(vB[3]) << 16);
        *(uint2*)&M[eb1 * 72 + k0] = make_uint2(w0, w1);

        f32x4 t2A = zero4, t2B = zero4;
        bf16x8 b0 = *(const bf16x8*)&M[eb0 * 72 + lg * 8];
        bf16x8 b1 = *(const bf16x8*)&M[eb1 * 72 + lg * 8];
        bf16x8 a  = *(const bf16x8*)&sWLT[(32 + lr) * 72 + 32 + lg * 8];
        t2A = __builtin_amdgcn_mfma_f32_16x16x32_bf16(a, b0, t2A, 0, 0, 0);
        t2B = __builtin_amdgcn_mfma_f32_16x16x32_bf16(a, b1, t2B, 0, 0, 0);

        float evA = (i == 0) ? ev0a : ((i == 1) ? ev1a : ev2a);
        float evB = (i == 0) ? ev0b : ((i == 1) ? ev1b : ev2b);
        #pragma unroll
        for (int q = 0; q < 4; q++) {
            yvA[q][i] = fmaf(evA, t1A[q], t2A[q]);
            yvB[q][i] = fmaf(evB, t1B[q], t2B[q]);
        }
    }

    // ================= phase C: in-block segmented reduction ================
    __syncthreads();   // all waves done reading Fns/Fnv/M/sWLT

    if (tid < 128) sdst[tid] = dstS;

    // write red[128][80] f32
    {
        bool okA = (pA < p1), okB = (pB < p1);
        #pragma unroll
        for (int ot = 0; ot < 2; ot++) {
            *(f32x4*)&redf[eb0 * 80 + ot * 16 + lg * 4] = okA ? accS[0][ot] : zero4;
            *(f32x4*)&redf[eb1 * 80 + ot * 16 + lg * 4] = okB ? accS[1][ot] : zero4;
        }
        #pragma unroll
        for (int q = 0; q < 4; q++) {
            int m = lg * 4 + q;
            #pragma unroll
            for (int i = 0; i < 3; i++) {
                redf[eb0 * 80 + 32 + 3 * m + i] = okA ? yvA[q][i] : 0.0f;
                redf[eb1 * 80 + 32 + 3 * m + i] = okB ? yvB[q][i] : 0.0f;
            }
        }
    }
    __syncthreads();

    // wave w reduces rows [w*32, w*32+32) segment-by-dst; lane l owns col l
    // (and col 64+l for l<16). dst change is row-uniform -> no divergence.
    {
        int base = w * 32;
        int cur = sdst[base];
        float s0 = 0.0f, s1 = 0.0f;
        for (int r = 0; r < 32; r++) {
            int d = sdst[base + r];
            if (d != cur) {
                atomicAdd(&out[(size_t)cur * OUT_PER_NODE + lane], s0);
                if (lane < 16) atomicAdd(&out[(size_t)cur * OUT_PER_NODE + 64 + lane], s1);
                s0 = 0.0f; s1 = 0.0f; cur = d;
            }
            s0 += redf[(base + r) * 80 + lane];
            if (lane < 16) s1 += redf[(base + r) * 80 + 64 + lane];
        }
        atomicAdd(&out[(size_t)cur * OUT_PER_NODE + lane], s0);
        if (lane < 16) atomicAdd(&out[(size_t)cur * OUT_PER_NODE + 64 + lane], s1);
    }
}

// ---------------------------------------------------------------------------
extern "C" void kernel_launch(void* const* d_in, const int* in_sizes, int n_in,
                              void* d_out, int out_size, void* d_ws, size_t ws_size,
                              hipStream_t stream) {
    const int*   esrc = (const int*)  d_in[0];
    const int*   edst = (const int*)  d_in[1];
    const float* ecut = (const float*)d_in[2];
    const float* einv = (const float*)d_in[3];
    const float* ns   = (const float*)d_in[4];
    const float* nv   = (const float*)d_in[5];
    const float* esh  = (const float*)d_in[6];
    const float* W0   = (const float*)d_in[7];
    const float* W1   = (const float*)d_in[8];
    const float* W2   = (const float*)d_in[9];
    const float* WLs  = (const float*)d_in[10];
    const float* WLv  = (const float*)d_in[11];
    float* out = (float*)d_out;

    const int E  = in_sizes[0];
    const int Nn = in_sizes[4] / S_IN;

    size_t int_bytes = (((size_t)(3 * Nn + 1 + 2 * E)) * sizeof(int) + 255) & ~(size_t)255;
    size_t pw_bytes  = ((size_t)PWTOT * 2 + 255) & ~(size_t)255;
    size_t ns_bytes  = ((size_t)Nn * 32 * 2 + 255) & ~(size_t)255;
    size_t nv_bytes  = ((size_t)Nn * 48 * 2 + 255) & ~(size_t)255;
    size_t fixed = int_bytes + pw_bytes + ns_bytes + nv_bytes;

    int eblocks = (E + 255) / 256;

    hipMemsetAsync(out, 0, (size_t)Nn * OUT_PER_NODE * sizeof(float), stream);

    if (ws_size < fixed) return;   // (ws is known ample from prior rounds)

    int*            deg    = (int*)d_ws;
    int*            offs   = deg + Nn;
    int*            cursor = offs + Nn + 1;
    int*            perm   = cursor + Nn;
    int*            pdst   = perm + E;
    unsigned short* pW     = (unsigned short*)((char*)d_ws + int_bytes);
    unsigned short* pNS    = (unsigned short*)((char*)d_ws + int_bytes + pw_bytes);
    unsigned short* pNV    = (unsigned short*)((char*)d_ws + int_bytes + pw_bytes + ns_bytes);

    hipMemsetAsync(deg, 0, (size_t)Nn * sizeof(int), stream);
    hist_kernel<<<eblocks, 256, 0, stream>>>(edst, deg, E);
    scan_kernel<<<1, 1024, 0, stream>>>(deg, offs, cursor, Nn);
    scatter_kernel<<<eblocks, 256, 0, stream>>>(edst, cursor, perm, pdst, E);

    prep_weights<<<(PWTOT + 255) / 256, 256, 0, stream>>>(W0, W1, W2, WLs, WLv, pW);
    cast_bf16<<<((Nn * 32 / 8) + 255) / 256, 256, 0, stream>>>(ns, pNS, Nn * 32 / 8);
    cast_bf16<<<((Nn * 48 / 8) + 255) / 256, 256, 0, stream>>>(nv, pNV, Nn * 48 / 8);

    int mblocks = (E + 127) / 128;
    edge_mega<<<mblocks, 256, 0, stream>>>(perm, pdst, esrc, ecut, esh, einv,
                                           pW, pNS, pNV, out, E);
}

// Round 13
// 257.864 us; speedup vs baseline: 4.8648x; 1.5274x over previous
//
#include <hip/hip_runtime.h>
#include <hip/hip_fp16.h>
#include <math.h>

// Problem constants
constexpr int S_IN = 32, V_IN = 16, INVD = 16;
constexpr int S_MSG = S_IN + V_IN;           // 48
constexpr int V_MSG = S_IN + V_IN;           // 48
constexpr int NFAC  = S_MSG + V_MSG;         // 96
constexpr int S_OUT = 32, V_OUT = 16;
constexpr int OUT_PER_NODE = S_OUT + V_OUT * 3;  // 80
constexpr float ISQRT3 = 0.57735026918962576f;
constexpr float ISQ48  = 0.14433756729740643f;

// prepped-weight layout (in shorts): W0T[64][40] | W1T[64][72] | W2T[96][72] | WLT[48][72]
constexpr int PW0 = 0, PW1 = 2560, PW2 = 7168, PWL = 14080, PWTOT = 17536;

typedef __attribute__((ext_vector_type(8))) short bf16x8;
typedef __attribute__((ext_vector_type(4))) float f32x4;

__device__ __forceinline__ float silu_f(float x) {
    return x / (1.0f + __expf(-x));
}
__device__ __forceinline__ unsigned short f2bf(float f) {
    unsigned int u = __float_as_uint(f);
    u += 0x7FFFu + ((u >> 16) & 1u);
    return (unsigned short)(u >> 16);
}
__device__ __forceinline__ float bf2f(unsigned short h) {
    return __uint_as_float(((unsigned int)h) << 16);
}
__device__ __forceinline__ unsigned int pack2(float a, float b) {
    return (unsigned int)f2bf(a) | ((unsigned int)f2bf(b) << 16);
}

// ---------------------------------------------------------------------------
// CSR construction: hist + 3-kernel parallel scan + fat scatter
// ---------------------------------------------------------------------------
__global__ __launch_bounds__(256) void hist_kernel(
    const int* __restrict__ edst, int* __restrict__ deg, int E)
{
    int e = blockIdx.x * 256 + threadIdx.x;
    if (e < E) atomicAdd(&deg[edst[e]], 1);
}

__global__ __launch_bounds__(256) void scanA(
    const int* __restrict__ deg, int* __restrict__ bsum, int Nn)
{
    __shared__ int sh[256];
    int i = blockIdx.x * 256 + threadIdx.x;
    sh[threadIdx.x] = (i < Nn) ? deg[i] : 0;
    __syncthreads();
    for (int o = 128; o > 0; o >>= 1) {
        if (threadIdx.x < o) sh[threadIdx.x] += sh[threadIdx.x + o];
        __syncthreads();
    }
    if (threadIdx.x == 0) bsum[blockIdx.x] = sh[0];
}

__global__ __launch_bounds__(1024) void scanB(int* __restrict__ bsum, int nb)
{
    __shared__ int sh[1024];
    int t = threadIdx.x;
    sh[t] = (t < nb) ? bsum[t] : 0;
    __syncthreads();
    for (int o = 1; o < 1024; o <<= 1) {
        int v = (t >= o) ? sh[t - o] : 0;
        __syncthreads();
        sh[t] += v;
        __syncthreads();
    }
    if (t < nb) bsum[t] = (t > 0) ? sh[t - 1] : 0;   // exclusive
}

__global__ __launch_bounds__(256) void scanC(
    const int* __restrict__ deg, const int* __restrict__ bsum,
    int* __restrict__ offs, int* __restrict__ cursor, int Nn, int E)
{
    __shared__ int sh[256];
    int i = blockIdx.x * 256 + threadIdx.x;
    int t = threadIdx.x;
    int v = (i < Nn) ? deg[i] : 0;
    sh[t] = v;
    __syncthreads();
    for (int o = 1; o < 256; o <<= 1) {
        int u = (t >= o) ? sh[t - o] : 0;
        __syncthreads();
        sh[t] += u;
        __syncthreads();
    }
    int excl = sh[t] - v + bsum[blockIdx.x];
    if (i < Nn) { offs[i] = excl; cursor[i] = excl; }
    if (i == Nn - 1) offs[Nn] = E;
}

// Fat scatter: build 64B per-edge record at permuted position.
// rec[p] = { einv bf16 x16 (32B) | cut,esh0,esh1,esh2 f32 (16B) | src,dst,0,0 }
__global__ __launch_bounds__(256) void scatter_permute(
    const int*   __restrict__ edst,
    const int*   __restrict__ esrc,
    const float* __restrict__ ecut,
    const float* __restrict__ esh,
    const float* __restrict__ einv,
    int* __restrict__ cursor,
    uint4* __restrict__ pedge,
    int E)
{
    int e = blockIdx.x * 256 + threadIdx.x;
    if (e >= E) return;
    int d = edst[e];
    int pos = atomicAdd(&cursor[d], 1);

    const float4* xr = reinterpret_cast<const float4*>(einv + (size_t)e * INVD);
    float4 a = xr[0], b = xr[1], c = xr[2], f = xr[3];
    uint4 r0 = make_uint4(pack2(a.x, a.y), pack2(a.z, a.w), pack2(b.x, b.y), pack2(b.z, b.w));
    uint4 r1 = make_uint4(pack2(c.x, c.y), pack2(c.z, c.w), pack2(f.x, f.y), pack2(f.z, f.w));
    uint4 r2 = make_uint4(__float_as_uint(ecut[e]),
                          __float_as_uint(esh[(size_t)e * 3 + 0]),
                          __float_as_uint(esh[(size_t)e * 3 + 1]),
                          __float_as_uint(esh[(size_t)e * 3 + 2]));
    uint4 r3 = make_uint4((unsigned int)esrc[e], (unsigned int)d, 0u, 0u);

    uint4* dst = pedge + (size_t)pos * 4;
    dst[0] = r0; dst[1] = r1; dst[2] = r2; dst[3] = r3;
}

// ---------------------------------------------------------------------------
// Fused pre-pass: weights (transposed/padded bf16) + ns/nv bf16 casts
// ---------------------------------------------------------------------------
__global__ __launch_bounds__(256) void prep_all(
    const float* __restrict__ W0, const float* __restrict__ W1,
    const float* __restrict__ W2, const float* __restrict__ WLs,
    const float* __restrict__ WLv,
    const float* __restrict__ ns, const float* __restrict__ nv,
    unsigned short* __restrict__ pW,
    unsigned short* __restrict__ pNS,
    unsigned short* __restrict__ pNV,
    int Nn)
{
    int i = blockIdx.x * 256 + threadIdx.x;
    int nNS = Nn * 4;   // uint4-groups of 8 floats
    int nNV = Nn * 6;
    if (i < PWTOT) {
        float v = 0.0f;
        if (i < PW1) {
            int j = i / 40, k = i - 40 * j;
            if (k < INVD) v = W0[k * 64 + j];
        } else if (i < PW2) {
            int t = i - PW1; int j = t / 72, k = t - 72 * j;
            if (k < 64) v = W1[k * 64 + j];
        } else if (i < PWL) {
            int t = i - PW2; int j = t / 72, k = t - 72 * j;
            if (k < 64) v = W2[k * 96 + j];
        } else {
            int t = i - PWL; int j = t / 72, k = t - 72 * j;
            if (k < 48) v = (j < 32) ? WLs[k * S_OUT + j] : WLv[k * V_OUT + (j - 32)];
        }
        pW[i] = f2bf(v);
    } else if (i < PWTOT + nNS) {
        int g = i - PWTOT;
        const float4* s4 = reinterpret_cast<const float4*>(ns + (size_t)g * 8);
        float4 a = s4[0], b = s4[1];
        *reinterpret_cast<uint4*>(pNS + (size_t)g * 8) =
            make_uint4(pack2(a.x, a.y), pack2(a.z, a.w), pack2(b.x, b.y), pack2(b.z, b.w));
    } else if (i < PWTOT + nNS + nNV) {
        int g = i - PWTOT - nNS;
        const float4* s4 = reinterpret_cast<const float4*>(nv + (size_t)g * 8);
        float4 a = s4[0], b = s4[1];
        *reinterpret_cast<uint4*>(pNV + (size_t)g * 8) =
            make_uint4(pack2(a.x, a.y), pack2(a.z, a.w), pack2(b.x, b.y), pack2(b.z, b.w));
    }
}

// ---------------------------------------------------------------------------
// MEGA kernel v5: sequential 64B edge records, fused MLP + WL + in-block
// segmented reduction -> atomicAdd into out. Block = 128 edges, 4 waves.
// ---------------------------------------------------------------------------
__global__ __launch_bounds__(256, 3) void edge_mega(
    const uint4* __restrict__ pedge,
    const unsigned short* __restrict__ pW,
    const unsigned short* __restrict__ pNS,
    const unsigned short* __restrict__ pNV,
    float* __restrict__ out,
    int E)
{
    __shared__ __align__(16) unsigned char smem[53760];

    unsigned short* sW0T = (unsigned short*)(smem + 0);      // [64][40]  (A)
    unsigned short* sW1T = (unsigned short*)(smem + 5120);   // [64][72]  (A)
    unsigned short* act0 = (unsigned short*)(smem + 14336);  // [128][72] (A)
    unsigned short* act1 = (unsigned short*)(smem + 32768);  // [128][72] (A)
    unsigned short* sWLT = (unsigned short*)(smem + 5120);   // [48][72]  (B)
    unsigned short* M    = (unsigned short*)(smem + 14336);  // [128][72] (B)
    unsigned short* Fns  = (unsigned short*)(smem + 32768);  // [128][33] (B)
    unsigned short* Fnv  = (unsigned short*)(smem + 41216);  // [128][49] (B)
    float*          redf = (float*)smem;                     // [128][84] (C)
    int*            sdst = (int*)(smem + 43008);             // [128]     (C)

    const int tid = threadIdx.x;
    const int pbase = blockIdx.x * 128;
    const int p1 = E;

    const int lane = tid & 63;
    const int w    = tid >> 6;
    const int lr   = lane & 15;
    const int lg   = lane >> 4;
    const int eb0  = w * 32 + lr;
    const int eb1  = eb0 + 16;
    const int pA   = pbase + eb0;
    const int pB   = pbase + eb1;

    // ============ PREFETCH (all coalesced record reads + L2-hot features) ===
    const uint4 rA2 = pedge[(size_t)(pA < p1 ? pA : p1 - 1) * 4 + 2];
    const uint4 rB2 = pedge[(size_t)(pB < p1 ? pB : p1 - 1) * 4 + 2];
    const float cutA = __uint_as_float(rA2.x);
    const float ev0a = __uint_as_float(rA2.y), ev1a = __uint_as_float(rA2.z), ev2a = __uint_as_float(rA2.w);
    const float cutB = __uint_as_float(rB2.x);
    const float ev0b = __uint_as_float(rB2.y), ev1b = __uint_as_float(rB2.z), ev2b = __uint_as_float(rB2.w);

    const int t2 = tid >> 1, half = tid & 1;
    int dS;
    uint4 pf0, pf1, pf2, pf3, pf4, pf5;
    {
        int pS = pbase + t2; if (pS >= p1) pS = p1 - 1;
        uint4 r3 = pedge[(size_t)pS * 4 + 3];
        int sS = (int)r3.x;
        dS = (int)r3.y;
        if (half == 0) {
            const uint4* nr = reinterpret_cast<const uint4*>(pNS + (size_t)sS * 32);
            pf0 = nr[0]; pf1 = nr[1]; pf2 = nr[2]; pf3 = nr[3];
        } else {
            const uint4* vr = reinterpret_cast<const uint4*>(pNV + (size_t)sS * 48);
            pf0 = vr[0]; pf1 = vr[1]; pf2 = vr[2]; pf3 = vr[3]; pf4 = vr[4]; pf5 = vr[5];
        }
    }

    const uint4* wsrc = reinterpret_cast<const uint4*>(pW);

    // ---- phase 1: copy W0T+W1T (896 uint4), stage X from record ----
    {
        uint4* s4 = reinterpret_cast<uint4*>(smem);
        #pragma unroll 2
        for (int i = tid; i < 896; i += 256) s4[i] = wsrc[i];
    }
    if (tid < 128) {
        int p = pbase + tid; if (p >= p1) p = p1 - 1;
        const uint4* rec = pedge + (size_t)p * 4;
        uint4 r0 = rec[0], r1 = rec[1];
        uint4* r4 = reinterpret_cast<uint4*>(&act0[tid * 72]);
        r4[0] = r0;
        r4[1] = r1;
        r4[2] = make_uint4(0u, 0u, 0u, 0u);
        r4[3] = make_uint4(0u, 0u, 0u, 0u);
    }
    __syncthreads();

    const f32x4 zero4 = {0.f, 0.f, 0.f, 0.f};

    // ---- Layer 1: h1 = silu((X@W0)/4) ----
    {
        bf16x8 b0 = *(const bf16x8*)&act0[eb0 * 72 + lg * 8];
        bf16x8 b1 = *(const bf16x8*)&act0[eb1 * 72 + lg * 8];
        #pragma unroll
        for (int jt = 0; jt < 4; jt++) {
            bf16x8 a = *(const bf16x8*)&sW0T[(jt * 16 + lr) * 40 + lg * 8];
            f32x4 d0 = __builtin_amdgcn_mfma_f32_16x16x32_bf16(a, b0, zero4, 0, 0, 0);
            f32x4 d1 = __builtin_amdgcn_mfma_f32_16x16x32_bf16(a, b1, zero4, 0, 0, 0);
            unsigned int u0, u1;
            u0 = pack2(silu_f(d0[0] * 0.25f), silu_f(d0[1] * 0.25f));
            u1 = pack2(silu_f(d0[2] * 0.25f), silu_f(d0[3] * 0.25f));
            *(uint2*)&act1[eb0 * 72 + jt * 16 + lg * 4] = make_uint2(u0, u1);
            u0 = pack2(silu_f(d1[0] * 0.25f), silu_f(d1[1] * 0.25f));
            u1 = pack2(silu_f(d1[2] * 0.25f), silu_f(d1[3] * 0.25f));
            *(uint2*)&act1[eb1 * 72 + jt * 16 + lg * 4] = make_uint2(u0, u1);
        }
    }

    // ---- Layer 2: h2 = silu((h1@W1)/8) ----
    {
        bf16x8 b00 = *(const bf16x8*)&act1[eb0 * 72 +      lg * 8];
        bf16x8 b01 = *(const bf16x8*)&act1[eb0 * 72 + 32 + lg * 8];
        bf16x8 b10 = *(const bf16x8*)&act1[eb1 * 72 +      lg * 8];
        bf16x8 b11 = *(const bf16x8*)&act1[eb1 * 72 + 32 + lg * 8];
        #pragma unroll
        for (int jt = 0; jt < 4; jt++) {
            bf16x8 a0 = *(const bf16x8*)&sW1T[(jt * 16 + lr) * 72 +      lg * 8];
            bf16x8 a1 = *(const bf16x8*)&sW1T[(jt * 16 + lr) * 72 + 32 + lg * 8];
            f32x4 d0 = __builtin_amdgcn_mfma_f32_16x16x32_bf16(a0, b00, zero4, 0, 0, 0);
            d0 = __builtin_amdgcn_mfma_f32_16x16x32_bf16(a1, b01, d0, 0, 0, 0);
            f32x4 d1 = __builtin_amdgcn_mfma_f32_16x16x32_bf16(a0, b10, zero4, 0, 0, 0);
            d1 = __builtin_amdgcn_mfma_f32_16x16x32_bf16(a1, b11, d1, 0, 0, 0);
            unsigned int u0, u1;
            u0 = pack2(silu_f(d0[0] * 0.125f), silu_f(d0[1] * 0.125f));
            u1 = pack2(silu_f(d0[2] * 0.125f), silu_f(d0[3] * 0.125f));
            *(uint2*)&act0[eb0 * 72 + jt * 16 + lg * 4] = make_uint2(u0, u1);
            u0 = pack2(silu_f(d1[0] * 0.125f), silu_f(d1[1] * 0.125f));
            u1 = pack2(silu_f(d1[2] * 0.125f), silu_f(d1[3] * 0.125f));
            *(uint2*)&act0[eb1 * 72 + jt * 16 + lg * 4] = make_uint2(u0, u1);
        }
    }

    // ---- stage W2T into act1 ----
    __syncthreads();
    {
        uint4* a14 = reinterpret_cast<uint4*>(act1);
        const uint4* w2s = wsrc + 896;
        #pragma unroll 2
        for (int i = tid; i < 864; i += 256) a14[i] = w2s[i];
    }
    __syncthreads();

    // ---- Layer 3: fac -> registers (scales folded) ----
    float fac0[6][4], fac1[6][4];
    {
        bf16x8 b00 = *(const bf16x8*)&act0[eb0 * 72 +      lg * 8];
        bf16x8 b01 = *(const bf16x8*)&act0[eb0 * 72 + 32 + lg * 8];
        bf16x8 b10 = *(const bf16x8*)&act0[eb1 * 72 +      lg * 8];
        bf16x8 b11 = *(const bf16x8*)&act0[eb1 * 72 + 32 + lg * 8];
        float K0 = cutA * 0.125f * ISQ48;
        float K1 = cutB * 0.125f * ISQ48;
        #pragma unroll
        for (int jt = 0; jt < 6; jt++) {
            bf16x8 a0 = *(const bf16x8*)&act1[(jt * 16 + lr) * 72 +      lg * 8];
            bf16x8 a1 = *(const bf16x8*)&act1[(jt * 16 + lr) * 72 + 32 + lg * 8];
            f32x4 d0 = __builtin_amdgcn_mfma_f32_16x16x32_bf16(a0, b00, zero4, 0, 0, 0);
            d0 = __builtin_amdgcn_mfma_f32_16x16x32_bf16(a1, b01, d0, 0, 0, 0);
            f32x4 d1 = __builtin_amdgcn_mfma_f32_16x16x32_bf16(a0, b10, zero4, 0, 0, 0);
            d1 = __builtin_amdgcn_mfma_f32_16x16x32_bf16(a1, b11, d1, 0, 0, 0);
            float s0 = (jt == 0) ? K0 * ISQRT3 : K0;
            float s1 = (jt == 0) ? K1 * ISQRT3 : K1;
            #pragma unroll
            for (int q = 0; q < 4; q++) {
                fac0[jt][q] = d0[q] * s0;
                fac1[jt][q] = d1[q] * s1;
            }
        }
    }
    __syncthreads();

    // ---- phase 6: write prefetched features to LDS + copy WLT ----
    {
        if (half == 0) {
            uint4 vv[4] = {pf0, pf1, pf2, pf3};
            #pragma unroll
            for (int q = 0; q < 4; q++) {
                uint4 v = vv[q];
                unsigned short* d = &Fns[t2 * 33 + 8 * q];
                d[0] = (unsigned short)v.x; d[1] = (unsigned short)(v.x >> 16);
                d[2] = (unsigned short)v.y; d[3] = (unsigned short)(v.y >> 16);
                d[4] = (unsigned short)v.z; d[5] = (unsigned short)(v.z >> 16);
                d[6] = (unsigned short)v.w; d[7] = (unsigned short)(v.w >> 16);
            }
        } else {
            uint4 vv[6] = {pf0, pf1, pf2, pf3, pf4, pf5};
            #pragma unroll
            for (int q = 0; q < 6; q++) {
                uint4 v = vv[q];
                unsigned short* d = &Fnv[t2 * 49 + 8 * q];
                d[0] = (unsigned short)v.x; d[1] = (unsigned short)(v.x >> 16);
                d[2] = (unsigned short)v.y; d[3] = (unsigned short)(v.y >> 16);
                d[4] = (unsigned short)v.z; d[5] = (unsigned short)(v.z >> 16);
                d[6] = (unsigned short)v.w; d[7] = (unsigned short)(v.w >> 16);
            }
        }
        uint4* wl4 = reinterpret_cast<uint4*>(sWLT);
        const uint4* wls = wsrc + 896 + 864;
        #pragma unroll 2
        for (int i = tid; i < 432; i += 256) wl4[i] = wls[i];
    }
    __syncthreads();

    // ---- M_s fill (48 gated scalar-message cols; 48..63 zero) ----
    #pragma unroll
    for (int jt = 0; jt < 3; jt++) {
        int c0 = jt * 16 + lg * 4;
        float vA[4], vB[4];
        #pragma unroll
        for (int q = 0; q < 4; q++) {
            int c = c0 + q;
            float fa, fb;
            if (jt == 0) {
                fa = bf2f(Fnv[eb0 * 49 + 3*c + 0]) * ev0a
                   + bf2f(Fnv[eb0 * 49 + 3*c + 1]) * ev1a
                   + bf2f(Fnv[eb0 * 49 + 3*c + 2]) * ev2a;
                fb = bf2f(Fnv[eb1 * 49 + 3*c + 0]) * ev0b
                   + bf2f(Fnv[eb1 * 49 + 3*c + 1]) * ev1b
                   + bf2f(Fnv[eb1 * 49 + 3*c + 2]) * ev2b;
            } else {
                fa = bf2f(Fns[eb0 * 33 + (c - 16)]);
                fb = bf2f(Fns[eb1 * 33 + (c - 16)]);
            }
            vA[q] = fa * fac0[jt][q];
            vB[q] = fb * fac1[jt][q];
        }
        *(uint2*)&M[eb0 * 72 + c0] = make_uint2(pack2(vA[0], vA[1]), pack2(vA[2], vA[3]));
        *(uint2*)&M[eb1 * 72 + c0] = make_uint2(pack2(vB[0], vB[1]), pack2(vB[2], vB[3]));
    }
    *(uint2*)&M[eb0 * 72 + 48 + lg * 4] = make_uint2(0u, 0u);
    *(uint2*)&M[eb1 * 72 + 48 + lg * 4] = make_uint2(0u, 0u);

    // ---- ys GEMM (keep in regs) ----
    f32x4 accS[2][2] = {{zero4, zero4}, {zero4, zero4}};
    #pragma unroll
    for (int kt = 0; kt < 2; kt++) {
        bf16x8 b0 = *(const bf16x8*)&M[eb0 * 72 + kt * 32 + lg * 8];
        bf16x8 b1 = *(const bf16x8*)&M[eb1 * 72 + kt * 32 + lg * 8];
        #pragma unroll
        for (int ot = 0; ot < 2; ot++) {
            bf16x8 a = *(const bf16x8*)&sWLT[(ot * 16 + lr) * 72 + kt * 32 + lg * 8];
            accS[0][ot] = __builtin_amdgcn_mfma_f32_16x16x32_bf16(a, b0, accS[0][ot], 0, 0, 0);
            accS[1][ot] = __builtin_amdgcn_mfma_f32_16x16x32_bf16(a, b1, accS[1][ot], 0, 0, 0);
        }
    }

    // ---- T1: (ns .* g2[0:32]) @ WLv[0:32], K=32, i-independent ----
    #pragma unroll
    for (int jt = 0; jt < 2; jt++) {
        int c0 = jt * 16 + lg * 4;
        float vA[4], vB[4];
        #pragma unroll
        for (int q = 0; q < 4; q++) {
            int c = c0 + q;
            vA[q] = bf2f(Fns[eb0 * 33 + c]) * fac0[3 + jt][q];
            vB[q] = bf2f(Fns[eb1 * 33 + c]) * fac1[3 + jt][q];
        }
        *(uint2*)&M[eb0 * 72 + c0] = make_uint2(pack2(vA[0], vA[1]), pack2(vA[2], vA[3]));
        *(uint2*)&M[eb1 * 72 + c0] = make_uint2(pack2(vB[0], vB[1]), pack2(vB[2], vB[3]));
    }
    f32x4 t1A = zero4, t1B = zero4;
    {
        bf16x8 b0 = *(const bf16x8*)&M[eb0 * 72 + lg * 8];
        bf16x8 b1 = *(const bf16x8*)&M[eb1 * 72 + lg * 8];
        bf16x8 a  = *(const bf16x8*)&sWLT[(32 + lr) * 72 + lg * 8];
        t1A = __builtin_amdgcn_mfma_f32_16x16x32_bf16(a, b0, t1A, 0, 0, 0);
        t1B = __builtin_amdgcn_mfma_f32_16x16x32_bf16(a, b1, t1B, 0, 0, 0);
    }

    // ---- T2_i: (nv_i .* g2[32:48]) @ WLv[32:48], K=16 (padded); combine ----
    float yvA[4][3], yvB[4][3];
    *(uint2*)&M[eb0 * 72 + 16 + lg * 4] = make_uint2(0u, 0u);
    *(uint2*)&M[eb1 * 72 + 16 + lg * 4] = make_uint2(0u, 0u);
    #pragma unroll
    for (int i = 0; i < 3; i++) {
        int k0 = lg * 4;
        float vA[4], vB[4];
        #pragma unroll
        for (int q = 0; q < 4; q++) {
            int r = k0 + q;
            vA[q] = bf2f(Fnv[eb0 * 49 + 3 * r + i]) * fac0[5][q];
            vB[q] = bf2f(Fnv[eb1 * 49 + 3 * r + i]) * fac1[5][q];
        }
        *(uint2*)&M[eb0 * 72 + k0] = make_uint2(pack2(vA[0], vA[1]), pack2(vA[2], vA[3]));
        *(uint2*)&M[eb1 * 72 + k0] = make_uint2(pack2(vB[0], vB[1]), pack2(vB[2], vB[3]));

        f32x4 t2A = zero4, t2B = zero4;
        bf16x8 b0 = *(const bf16x8*)&M[eb0 * 72 + lg * 8];
        bf16x8 b1 = *(const bf16x8*)&M[eb1 * 72 + lg * 8];
        bf16x8 a  = *(const bf16x8*)&sWLT[(32 + lr) * 72 + 32 + lg * 8];
        t2A = __builtin_amdgcn_mfma_f32_16x16x32_bf16(a, b0, t2A, 0, 0, 0);
        t2B = __builtin_amdgcn_mfma_f32_16x16x32_bf16(a, b1, t2B, 0, 0, 0);

        float evA = (i == 0) ? ev0a : ((i == 1) ? ev1a : ev2a);
        float evB = (i == 0) ? ev0b : ((i == 1) ? ev1b : ev2b);
        #pragma unroll
        for (int q = 0; q < 4; q++) {
            yvA[q][i] = fmaf(evA, t1A[q], t2A[q]);
            yvB[q][i] = fmaf(evB, t1B[q], t2B[q]);
        }
    }

    // ================= phase C: in-block segmented reduction ================
    __syncthreads();

    if (half == 0) sdst[t2] = dS;

    {
        bool okA = (pA < p1), okB = (pB < p1);
        #pragma unroll
        for (int ot = 0; ot < 2; ot++) {
            *(f32x4*)&redf[eb0 * 84 + ot * 16 + lg * 4] = okA ? accS[0][ot] : zero4;
            *(f32x4*)&redf[eb1 * 84 + ot * 16 + lg * 4] = okB ? accS[1][ot] : zero4;
        }
        #pragma unroll
        for (int q = 0; q < 4; q++) {
            int m = lg * 4 + q;
            #pragma unroll
            for (int i = 0; i < 3; i++) {
                redf[eb0 * 84 + 32 + 3 * m + i] = okA ? yvA[q][i] : 0.0f;
                redf[eb1 * 84 + 32 + 3 * m + i] = okB ? yvB[q][i] : 0.0f;
            }
        }
    }
    __syncthreads();

    {
        int base = w * 32;
        int cur = sdst[base];
        float s0 = 0.0f, s1 = 0.0f;
        for (int r = 0; r < 32; r++) {
            int d = sdst[base + r];
            if (d != cur) {
                atomicAdd(&out[(size_t)cur * OUT_PER_NODE + lane], s0);
                if (lane < 16) atomicAdd(&out[(size_t)cur * OUT_PER_NODE + 64 + lane], s1);
                s0 = 0.0f; s1 = 0.0f; cur = d;
            }
            s0 += redf[(base + r) * 84 + lane];
            if (lane < 16) s1 += redf[(base + r) * 84 + 64 + lane];
        }
        atomicAdd(&out[(size_t)cur * OUT_PER_NODE + lane], s0);
        if (lane < 16) atomicAdd(&out[(size_t)cur * OUT_PER_NODE + 64 + lane], s1);
    }
}

// ---------------------------------------------------------------------------
extern "C" void kernel_launch(void* const* d_in, const int* in_sizes, int n_in,
                              void* d_out, int out_size, void* d_ws, size_t ws_size,
                              hipStream_t stream) {
    const int*   esrc = (const int*)  d_in[0];
    const int*   edst = (const int*)  d_in[1];
    const float* ecut = (const float*)d_in[2];
    const float* einv = (const float*)d_in[3];
    const float* ns   = (const float*)d_in[4];
    const float* nv   = (const float*)d_in[5];
    const float* esh  = (const float*)d_in[6];
    const float* W0   = (const float*)d_in[7];
    const float* W1   = (const float*)d_in[8];
    const float* W2   = (const float*)d_in[9];
    const float* WLs  = (const float*)d_in[10];
    const float* WLv  = (const float*)d_in[11];
    float* out = (float*)d_out;

    const int E  = in_sizes[0];
    const int Nn = in_sizes[4] / S_IN;
    const int nb = (Nn + 255) / 256;

    size_t int_bytes = (((size_t)(3 * Nn + 1 + nb)) * sizeof(int) + 255) & ~(size_t)255;
    size_t pe_bytes  = ((size_t)E * 64 + 255) & ~(size_t)255;
    size_t pw_bytes  = ((size_t)PWTOT * 2 + 255) & ~(size_t)255;
    size_t ns_bytes  = ((size_t)Nn * 32 * 2 + 255) & ~(size_t)255;
    size_t nv_bytes  = ((size_t)Nn * 48 * 2 + 255) & ~(size_t)255;
    size_t fixed = int_bytes + pe_bytes + pw_bytes + ns_bytes + nv_bytes;

    int eblocks = (E + 255) / 256;

    hipMemsetAsync(out, 0, (size_t)Nn * OUT_PER_NODE * sizeof(float), stream);

    if (ws_size < fixed) return;   // ws known ample from prior rounds (~80+ MB)

    int*            deg    = (int*)d_ws;
    int*            offs   = deg + Nn;          // Nn+1
    int*            cursor = offs + Nn + 1;     // Nn
    int*            bsum   = cursor + Nn;       // nb
    uint4*          pedge  = (uint4*)((char*)d_ws + int_bytes);
    unsigned short* pW     = (unsigned short*)((char*)d_ws + int_bytes + pe_bytes);
    unsigned short* pNS    = (unsigned short*)((char*)d_ws + int_bytes + pe_bytes + pw_bytes);
    unsigned short* pNV    = (unsigned short*)((char*)d_ws + int_bytes + pe_bytes + pw_bytes + ns_bytes);

    hipMemsetAsync(deg, 0, (size_t)Nn * sizeof(int), stream);
    hist_kernel<<<eblocks, 256, 0, stream>>>(edst, deg, E);
    scanA<<<nb, 256, 0, stream>>>(deg, bsum, Nn);
    scanB<<<1, 1024, 0, stream>>>(bsum, nb);
    scanC<<<nb, 256, 0, stream>>>(deg, bsum, offs, cursor, Nn, E);
    scatter_permute<<<eblocks, 256, 0, stream>>>(edst, esrc, ecut, esh, einv,
                                                 cursor, pedge, E);

    int ptotal = PWTOT + Nn * 4 + Nn * 6;
    prep_all<<<(ptotal + 255) / 256, 256, 0, stream>>>(W0, W1, W2, WLs, WLv,
                                                       ns, nv, pW, pNS, pNV, Nn);

    int mblocks = (E + 127) / 128;
    edge_mega<<<mblocks, 256, 0, stream>>>(pedge, pW, pNS, pNV, out, E);
}

// Round 14
// 252.684 us; speedup vs baseline: 4.9646x; 1.0205x over previous
//
#include <hip/hip_runtime.h>
#include <hip/hip_fp16.h>
#include <math.h>

// Problem constants
constexpr int S_IN = 32, V_IN = 16, INVD = 16;
constexpr int S_MSG = S_IN + V_IN;           // 48
constexpr int V_MSG = S_IN + V_IN;           // 48
constexpr int NFAC  = S_MSG + V_MSG;         // 96
constexpr int S_OUT = 32, V_OUT = 16;
constexpr int OUT_PER_NODE = S_OUT + V_OUT * 3;  // 80
constexpr float ISQRT3 = 0.57735026918962576f;
constexpr float ISQ48  = 0.14433756729740643f;

// prepped-weight layout (in shorts): W0T[64][40] | W1T[64][72] | W2T[96][72] | WLT[48][72]
constexpr int PW0 = 0, PW1 = 2560, PW2 = 7168, PWL = 14080, PWTOT = 17536;

typedef _Float16 f16x8 __attribute__((ext_vector_type(8)));
typedef __attribute__((ext_vector_type(4))) float f32x4;

__device__ __forceinline__ float silu_f(float x) {
    return x / (1.0f + __expf(-x));
}
__device__ __forceinline__ unsigned int hpack2(float a, float b) {
    __half2 h = __floats2half2_rn(a, b);        // v_cvt_pkrtz_f16_f32 (1 instr)
    return *reinterpret_cast<unsigned int*>(&h);
}
__device__ __forceinline__ unsigned short f2h(float f) {
    __half h = __float2half_rn(f);
    return __half_as_ushort(h);
}
__device__ __forceinline__ float h2f(unsigned short u) {
    return __half2float(__ushort_as_half(u));
}

// ---------------------------------------------------------------------------
// hist + prep fused (independent jobs, one launch)
// ---------------------------------------------------------------------------
__global__ __launch_bounds__(256) void hist_prep(
    const int* __restrict__ edst, int* __restrict__ deg, int E,
    const float* __restrict__ W0, const float* __restrict__ W1,
    const float* __restrict__ W2, const float* __restrict__ WLs,
    const float* __restrict__ WLv,
    const float* __restrict__ ns, const float* __restrict__ nv,
    unsigned short* __restrict__ pW,
    unsigned short* __restrict__ pNS,
    unsigned short* __restrict__ pNV,
    int Nn)
{
    int i = blockIdx.x * 256 + threadIdx.x;
    if (i < E) atomicAdd(&deg[edst[i]], 1);

    int nNS = Nn * 4;   // uint4-groups of 8 floats
    int nNV = Nn * 6;
    if (i < PWTOT) {
        float v = 0.0f;
        if (i < PW1) {
            int j = i / 40, k = i - 40 * j;
            if (k < INVD) v = W0[k * 64 + j];
        } else if (i < PW2) {
            int t = i - PW1; int j = t / 72, k = t - 72 * j;
            if (k < 64) v = W1[k * 64 + j];
        } else if (i < PWL) {
            int t = i - PW2; int j = t / 72, k = t - 72 * j;
            if (k < 64) v = W2[k * 96 + j];
        } else {
            int t = i - PWL; int j = t / 72, k = t - 72 * j;
            if (k < 48) v = (j < 32) ? WLs[k * S_OUT + j] : WLv[k * V_OUT + (j - 32)];
        }
        pW[i] = f2h(v);
    } else if (i < PWTOT + nNS) {
        int g = i - PWTOT;
        const float4* s4 = reinterpret_cast<const float4*>(ns + (size_t)g * 8);
        float4 a = s4[0], b = s4[1];
        *reinterpret_cast<uint4*>(pNS + (size_t)g * 8) =
            make_uint4(hpack2(a.x, a.y), hpack2(a.z, a.w), hpack2(b.x, b.y), hpack2(b.z, b.w));
    } else if (i < PWTOT + nNS + nNV) {
        int g = i - PWTOT - nNS;
        const float4* s4 = reinterpret_cast<const float4*>(nv + (size_t)g * 8);
        float4 a = s4[0], b = s4[1];
        *reinterpret_cast<uint4*>(pNV + (size_t)g * 8) =
            make_uint4(hpack2(a.x, a.y), hpack2(a.z, a.w), hpack2(b.x, b.y), hpack2(b.z, b.w));
    }
}

// ---------------------------------------------------------------------------
// 3-kernel parallel scan
// ---------------------------------------------------------------------------
__global__ __launch_bounds__(256) void scanA(
    const int* __restrict__ deg, int* __restrict__ bsum, int Nn)
{
    __shared__ int sh[256];
    int i = blockIdx.x * 256 + threadIdx.x;
    sh[threadIdx.x] = (i < Nn) ? deg[i] : 0;
    __syncthreads();
    for (int o = 128; o > 0; o >>= 1) {
        if (threadIdx.x < o) sh[threadIdx.x] += sh[threadIdx.x + o];
        __syncthreads();
    }
    if (threadIdx.x == 0) bsum[blockIdx.x] = sh[0];
}

__global__ __launch_bounds__(1024) void scanB(int* __restrict__ bsum, int nb)
{
    __shared__ int sh[1024];
    int t = threadIdx.x;
    sh[t] = (t < nb) ? bsum[t] : 0;
    __syncthreads();
    for (int o = 1; o < 1024; o <<= 1) {
        int v = (t >= o) ? sh[t - o] : 0;
        __syncthreads();
        sh[t] += v;
        __syncthreads();
    }
    if (t < nb) bsum[t] = (t > 0) ? sh[t - 1] : 0;   // exclusive
}

__global__ __launch_bounds__(256) void scanC(
    const int* __restrict__ deg, const int* __restrict__ bsum,
    int* __restrict__ offs, int* __restrict__ cursor, int Nn, int E)
{
    __shared__ int sh[256];
    int i = blockIdx.x * 256 + threadIdx.x;
    int t = threadIdx.x;
    int v = (i < Nn) ? deg[i] : 0;
    sh[t] = v;
    __syncthreads();
    for (int o = 1; o < 256; o <<= 1) {
        int u = (t >= o) ? sh[t - o] : 0;
        __syncthreads();
        sh[t] += u;
        __syncthreads();
    }
    int excl = sh[t] - v + bsum[blockIdx.x];
    if (i < Nn) { offs[i] = excl; cursor[i] = excl; }
    if (i == Nn - 1) offs[Nn] = E;
}

// Fat scatter: build 64B per-edge record at permuted position.
// rec[p] = { einv f16 x16 (32B) | cut,esh0,esh1,esh2 f32 (16B) | src,dst,0,0 }
__global__ __launch_bounds__(256) void scatter_permute(
    const int*   __restrict__ edst,
    const int*   __restrict__ esrc,
    const float* __restrict__ ecut,
    const float* __restrict__ esh,
    const float* __restrict__ einv,
    int* __restrict__ cursor,
    uint4* __restrict__ pedge,
    int E)
{
    int e = blockIdx.x * 256 + threadIdx.x;
    if (e >= E) return;
    int d = edst[e];
    int pos = atomicAdd(&cursor[d], 1);

    const float4* xr = reinterpret_cast<const float4*>(einv + (size_t)e * INVD);
    float4 a = xr[0], b = xr[1], c = xr[2], f = xr[3];
    uint4 r0 = make_uint4(hpack2(a.x, a.y), hpack2(a.z, a.w), hpack2(b.x, b.y), hpack2(b.z, b.w));
    uint4 r1 = make_uint4(hpack2(c.x, c.y), hpack2(c.z, c.w), hpack2(f.x, f.y), hpack2(f.z, f.w));
    uint4 r2 = make_uint4(__float_as_uint(ecut[e]),
                          __float_as_uint(esh[(size_t)e * 3 + 0]),
                          __float_as_uint(esh[(size_t)e * 3 + 1]),
                          __float_as_uint(esh[(size_t)e * 3 + 2]));
    uint4 r3 = make_uint4((unsigned int)esrc[e], (unsigned int)d, 0u, 0u);

    uint4* dst = pedge + (size_t)pos * 4;
    dst[0] = r0; dst[1] = r1; dst[2] = r2; dst[3] = r3;
}

// ---------------------------------------------------------------------------
// MEGA kernel v6 (fp16): sequential 64B edge records, fused MLP + WL +
// in-block segmented reduction -> atomicAdd. Block = 128 edges, 4 waves.
// ---------------------------------------------------------------------------
__global__ __launch_bounds__(256, 3) void edge_mega(
    const uint4* __restrict__ pedge,
    const unsigned short* __restrict__ pW,
    const unsigned short* __restrict__ pNS,
    const unsigned short* __restrict__ pNV,
    float* __restrict__ out,
    int E)
{
    __shared__ __align__(16) unsigned char smem[53760];

    unsigned short* sW0T = (unsigned short*)(smem + 0);      // [64][40]  (A)
    unsigned short* sW1T = (unsigned short*)(smem + 5120);   // [64][72]  (A)
    unsigned short* act0 = (unsigned short*)(smem + 14336);  // [128][72] (A)
    unsigned short* act1 = (unsigned short*)(smem + 32768);  // [128][72] (A)
    unsigned short* sWLT = (unsigned short*)(smem + 5120);   // [48][72]  (B)
    unsigned short* M    = (unsigned short*)(smem + 14336);  // [128][72] (B)
    unsigned short* Fns  = (unsigned short*)(smem + 32768);  // [128][33] (B)
    unsigned short* Fnv  = (unsigned short*)(smem + 41216);  // [128][49] (B)
    float*          redf = (float*)smem;                     // [128][84] (C)
    int*            sdst = (int*)(smem + 43008);             // [128]     (C)

    const int tid = threadIdx.x;
    const int pbase = blockIdx.x * 128;
    const int p1 = E;

    const int lane = tid & 63;
    const int w    = tid >> 6;
    const int lr   = lane & 15;
    const int lg   = lane >> 4;
    const int eb0  = w * 32 + lr;
    const int eb1  = eb0 + 16;
    const int pA   = pbase + eb0;
    const int pB   = pbase + eb1;

    // ============ PREFETCH (coalesced record reads + feature gathers) =======
    const uint4 rA2 = pedge[(size_t)(pA < p1 ? pA : p1 - 1) * 4 + 2];
    const uint4 rB2 = pedge[(size_t)(pB < p1 ? pB : p1 - 1) * 4 + 2];
    const float cutA = __uint_as_float(rA2.x);
    const float ev0a = __uint_as_float(rA2.y), ev1a = __uint_as_float(rA2.z), ev2a = __uint_as_float(rA2.w);
    const float cutB = __uint_as_float(rB2.x);
    const float ev0b = __uint_as_float(rB2.y), ev1b = __uint_as_float(rB2.z), ev2b = __uint_as_float(rB2.w);

    const int t2 = tid >> 1, half = tid & 1;
    int dS;
    uint4 pf0, pf1, pf2, pf3, pf4, pf5;
    {
        int pS = pbase + t2; if (pS >= p1) pS = p1 - 1;
        uint4 r3 = pedge[(size_t)pS * 4 + 3];
        int sS = (int)r3.x;
        dS = (int)r3.y;
        if (half == 0) {
            const uint4* nr = reinterpret_cast<const uint4*>(pNS + (size_t)sS * 32);
            pf0 = nr[0]; pf1 = nr[1]; pf2 = nr[2]; pf3 = nr[3];
        } else {
            const uint4* vr = reinterpret_cast<const uint4*>(pNV + (size_t)sS * 48);
            pf0 = vr[0]; pf1 = vr[1]; pf2 = vr[2]; pf3 = vr[3]; pf4 = vr[4]; pf5 = vr[5];
        }
    }

    const uint4* wsrc = reinterpret_cast<const uint4*>(pW);

    // ---- phase 1: copy W0T+W1T (896 uint4), stage X from record ----
    {
        uint4* s4 = reinterpret_cast<uint4*>(smem);
        #pragma unroll 2
        for (int i = tid; i < 896; i += 256) s4[i] = wsrc[i];
    }
    if (tid < 128) {
        int p = pbase + tid; if (p >= p1) p = p1 - 1;
        const uint4* rec = pedge + (size_t)p * 4;
        uint4 r0 = rec[0], r1 = rec[1];
        uint4* r4 = reinterpret_cast<uint4*>(&act0[tid * 72]);
        r4[0] = r0;
        r4[1] = r1;
        r4[2] = make_uint4(0u, 0u, 0u, 0u);
        r4[3] = make_uint4(0u, 0u, 0u, 0u);
    }
    __syncthreads();

    const f32x4 zero4 = {0.f, 0.f, 0.f, 0.f};

    // ---- Layer 1: h1 = silu((X@W0)/4) ----
    {
        f16x8 b0 = *(const f16x8*)&act0[eb0 * 72 + lg * 8];
        f16x8 b1 = *(const f16x8*)&act0[eb1 * 72 + lg * 8];
        #pragma unroll
        for (int jt = 0; jt < 4; jt++) {
            f16x8 a = *(const f16x8*)&sW0T[(jt * 16 + lr) * 40 + lg * 8];
            f32x4 d0 = __builtin_amdgcn_mfma_f32_16x16x32_f16(a, b0, zero4, 0, 0, 0);
            f32x4 d1 = __builtin_amdgcn_mfma_f32_16x16x32_f16(a, b1, zero4, 0, 0, 0);
            unsigned int u0 = hpack2(silu_f(d0[0] * 0.25f), silu_f(d0[1] * 0.25f));
            unsigned int u1 = hpack2(silu_f(d0[2] * 0.25f), silu_f(d0[3] * 0.25f));
            *(uint2*)&act1[eb0 * 72 + jt * 16 + lg * 4] = make_uint2(u0, u1);
            u0 = hpack2(silu_f(d1[0] * 0.25f), silu_f(d1[1] * 0.25f));
            u1 = hpack2(silu_f(d1[2] * 0.25f), silu_f(d1[3] * 0.25f));
            *(uint2*)&act1[eb1 * 72 + jt * 16 + lg * 4] = make_uint2(u0, u1);
        }
    }

    // ---- Layer 2: h2 = silu((h1@W1)/8) ----
    {
        f16x8 b00 = *(const f16x8*)&act1[eb0 * 72 +      lg * 8];
        f16x8 b01 = *(const f16x8*)&act1[eb0 * 72 + 32 + lg * 8];
        f16x8 b10 = *(const f16x8*)&act1[eb1 * 72 +      lg * 8];
        f16x8 b11 = *(const f16x8*)&act1[eb1 * 72 + 32 + lg * 8];
        #pragma unroll
        for (int jt = 0; jt < 4; jt++) {
            f16x8 a0 = *(const f16x8*)&sW1T[(jt * 16 + lr) * 72 +      lg * 8];
            f16x8 a1 = *(const f16x8*)&sW1T[(jt * 16 + lr) * 72 + 32 + lg * 8];
            f32x4 d0 = __builtin_amdgcn_mfma_f32_16x16x32_f16(a0, b00, zero4, 0, 0, 0);
            d0 = __builtin_amdgcn_mfma_f32_16x16x32_f16(a1, b01, d0, 0, 0, 0);
            f32x4 d1 = __builtin_amdgcn_mfma_f32_16x16x32_f16(a0, b10, zero4, 0, 0, 0);
            d1 = __builtin_amdgcn_mfma_f32_16x16x32_f16(a1, b11, d1, 0, 0, 0);
            unsigned int u0 = hpack2(silu_f(d0[0] * 0.125f), silu_f(d0[1] * 0.125f));
            unsigned int u1 = hpack2(silu_f(d0[2] * 0.125f), silu_f(d0[3] * 0.125f));
            *(uint2*)&act0[eb0 * 72 + jt * 16 + lg * 4] = make_uint2(u0, u1);
            u0 = hpack2(silu_f(d1[0] * 0.125f), silu_f(d1[1] * 0.125f));
            u1 = hpack2(silu_f(d1[2] * 0.125f), silu_f(d1[3] * 0.125f));
            *(uint2*)&act0[eb1 * 72 + jt * 16 + lg * 4] = make_uint2(u0, u1);
        }
    }

    // ---- stage W2T into act1 ----
    __syncthreads();
    {
        uint4* a14 = reinterpret_cast<uint4*>(act1);
        const uint4* w2s = wsrc + 896;
        #pragma unroll 2
        for (int i = tid; i < 864; i += 256) a14[i] = w2s[i];
    }
    __syncthreads();

    // ---- Layer 3: fac -> registers (scales folded) ----
    float fac0[6][4], fac1[6][4];
    {
        f16x8 b00 = *(const f16x8*)&act0[eb0 * 72 +      lg * 8];
        f16x8 b01 = *(const f16x8*)&act0[eb0 * 72 + 32 + lg * 8];
        f16x8 b10 = *(const f16x8*)&act0[eb1 * 72 +      lg * 8];
        f16x8 b11 = *(const f16x8*)&act0[eb1 * 72 + 32 + lg * 8];
        float K0 = cutA * 0.125f * ISQ48;
        float K1 = cutB * 0.125f * ISQ48;
        #pragma unroll
        for (int jt = 0; jt < 6; jt++) {
            f16x8 a0 = *(const f16x8*)&act1[(jt * 16 + lr) * 72 +      lg * 8];
            f16x8 a1 = *(const f16x8*)&act1[(jt * 16 + lr) * 72 + 32 + lg * 8];
            f32x4 d0 = __builtin_amdgcn_mfma_f32_16x16x32_f16(a0, b00, zero4, 0, 0, 0);
            d0 = __builtin_amdgcn_mfma_f32_16x16x32_f16(a1, b01, d0, 0, 0, 0);
            f32x4 d1 = __builtin_amdgcn_mfma_f32_16x16x32_f16(a0, b10, zero4, 0, 0, 0);
            d1 = __builtin_amdgcn_mfma_f32_16x16x32_f16(a1, b11, d1, 0, 0, 0);
            float s0 = (jt == 0) ? K0 * ISQRT3 : K0;
            float s1 = (jt == 0) ? K1 * ISQRT3 : K1;
            #pragma unroll
            for (int q = 0; q < 4; q++) {
                fac0[jt][q] = d0[q] * s0;
                fac1[jt][q] = d1[q] * s1;
            }
        }
    }
    __syncthreads();

    // ---- phase 6: write prefetched features to LDS + copy WLT ----
    {
        if (half == 0) {
            uint4 vv[4] = {pf0, pf1, pf2, pf3};
            #pragma unroll
            for (int q = 0; q < 4; q++) {
                uint4 v = vv[q];
                unsigned short* d = &Fns[t2 * 33 + 8 * q];
                d[0] = (unsigned short)v.x; d[1] = (unsigned short)(v.x >> 16);
                d[2] = (unsigned short)v.y; d[3] = (unsigned short)(v.y >> 16);
                d[4] = (unsigned short)v.z; d[5] = (unsigned short)(v.z >> 16);
                d[6] = (unsigned short)v.w; d[7] = (unsigned short)(v.w >> 16);
            }
        } else {
            uint4 vv[6] = {pf0, pf1, pf2, pf3, pf4, pf5};
            #pragma unroll
            for (int q = 0; q < 6; q++) {
                uint4 v = vv[q];
                unsigned short* d = &Fnv[t2 * 49 + 8 * q];
                d[0] = (unsigned short)v.x; d[1] = (unsigned short)(v.x >> 16);
                d[2] = (unsigned short)v.y; d[3] = (unsigned short)(v.y >> 16);
                d[4] = (unsigned short)v.z; d[5] = (unsigned short)(v.z >> 16);
                d[6] = (unsigned short)v.w; d[7] = (unsigned short)(v.w >> 16);
            }
        }
        uint4* wl4 = reinterpret_cast<uint4*>(sWLT);
        const uint4* wls = wsrc + 896 + 864;
        #pragma unroll 2
        for (int i = tid; i < 432; i += 256) wl4[i] = wls[i];
    }
    __syncthreads();

    // ---- M_s fill (48 gated scalar-message cols; 48..63 zero) ----
    #pragma unroll
    for (int jt = 0; jt < 3; jt++) {
        int c0 = jt * 16 + lg * 4;
        float vA[4], vB[4];
        #pragma unroll
        for (int q = 0; q < 4; q++) {
            int c = c0 + q;
            float fa, fb;
            if (jt == 0) {
                fa = h2f(Fnv[eb0 * 49 + 3*c + 0]) * ev0a
                   + h2f(Fnv[eb0 * 49 + 3*c + 1]) * ev1a
                   + h2f(Fnv[eb0 * 49 + 3*c + 2]) * ev2a;
                fb = h2f(Fnv[eb1 * 49 + 3*c + 0]) * ev0b
                   + h2f(Fnv[eb1 * 49 + 3*c + 1]) * ev1b
                   + h2f(Fnv[eb1 * 49 + 3*c + 2]) * ev2b;
            } else {
                fa = h2f(Fns[eb0 * 33 + (c - 16)]);
                fb = h2f(Fns[eb1 * 33 + (c - 16)]);
            }
            vA[q] = fa * fac0[jt][q];
            vB[q] = fb * fac1[jt][q];
        }
        *(uint2*)&M[eb0 * 72 + c0] = make_uint2(hpack2(vA[0], vA[1]), hpack2(vA[2], vA[3]));
        *(uint2*)&M[eb1 * 72 + c0] = make_uint2(hpack2(vB[0], vB[1]), hpack2(vB[2], vB[3]));
    }
    *(uint2*)&M[eb0 * 72 + 48 + lg * 4] = make_uint2(0u, 0u);
    *(uint2*)&M[eb1 * 72 + 48 + lg * 4] = make_uint2(0u, 0u);

    // ---- ys GEMM (keep in regs) ----
    f32x4 accS[2][2] = {{zero4, zero4}, {zero4, zero4}};
    #pragma unroll
    for (int kt = 0; kt < 2; kt++) {
        f16x8 b0 = *(const f16x8*)&M[eb0 * 72 + kt * 32 + lg * 8];
        f16x8 b1 = *(const f16x8*)&M[eb1 * 72 + kt * 32 + lg * 8];
        #pragma unroll
        for (int ot = 0; ot < 2; ot++) {
            f16x8 a = *(const f16x8*)&sWLT[(ot * 16 + lr) * 72 + kt * 32 + lg * 8];
            accS[0][ot] = __builtin_amdgcn_mfma_f32_16x16x32_f16(a, b0, accS[0][ot], 0, 0, 0);
            accS[1][ot] = __builtin_amdgcn_mfma_f32_16x16x32_f16(a, b1, accS[1][ot], 0, 0, 0);
        }
    }

    // ---- T1: (ns .* g2[0:32]) @ WLv[0:32], K=32, i-independent ----
    #pragma unroll
    for (int jt = 0; jt < 2; jt++) {
        int c0 = jt * 16 + lg * 4;
        float vA[4], vB[4];
        #pragma unroll
        for (int q = 0; q < 4; q++) {
            int c = c0 + q;
            vA[q] = h2f(Fns[eb0 * 33 + c]) * fac0[3 + jt][q];
            vB[q] = h2f(Fns[eb1 * 33 + c]) * fac1[3 + jt][q];
        }
        *(uint2*)&M[eb0 * 72 + c0] = make_uint2(hpack2(vA[0], vA[1]), hpack2(vA[2], vA[3]));
        *(uint2*)&M[eb1 * 72 + c0] = make_uint2(hpack2(vB[0], vB[1]), hpack2(vB[2], vB[3]));
    }
    f32x4 t1A = zero4, t1B = zero4;
    {
        f16x8 b0 = *(const f16x8*)&M[eb0 * 72 + lg * 8];
        f16x8 b1 = *(const f16x8*)&M[eb1 * 72 + lg * 8];
        f16x8 a  = *(const f16x8*)&sWLT[(32 + lr) * 72 + lg * 8];
        t1A = __builtin_amdgcn_mfma_f32_16x16x32_f16(a, b0, t1A, 0, 0, 0);
        t1B = __builtin_amdgcn_mfma_f32_16x16x32_f16(a, b1, t1B, 0, 0, 0);
    }

    // ---- T2_i: (nv_i .* g2[32:48]) @ WLv[32:48], K=16 (padded); combine ----
    float yvA[4][3], yvB[4][3];
    *(uint2*)&M[eb0 * 72 + 16 + lg * 4] = make_uint2(0u, 0u);
    *(uint2*)&M[eb1 * 72 + 16 + lg * 4] = make_uint2(0u, 0u);
    #pragma unroll
    for (int i = 0; i < 3; i++) {
        int k0 = lg * 4;
        float vA[4], vB[4];
        #pragma unroll
        for (int q = 0; q < 4; q++) {
            int r = k0 + q;
            vA[q] = h2f(Fnv[eb0 * 49 + 3 * r + i]) * fac0[5][q];
            vB[q] = h2f(Fnv[eb1 * 49 + 3 * r + i]) * fac1[5][q];
        }
        *(uint2*)&M[eb0 * 72 + k0] = make_uint2(hpack2(vA[0], vA[1]), hpack2(vA[2], vA[3]));
        *(uint2*)&M[eb1 * 72 + k0] = make_uint2(hpack2(vB[0], vB[1]), hpack2(vB[2], vB[3]));

        f32x4 t2A = zero4, t2B = zero4;
        f16x8 b0 = *(const f16x8*)&M[eb0 * 72 + lg * 8];
        f16x8 b1 = *(const f16x8*)&M[eb1 * 72 + lg * 8];
        f16x8 a  = *(const f16x8*)&sWLT[(32 + lr) * 72 + 32 + lg * 8];
        t2A = __builtin_amdgcn_mfma_f32_16x16x32_f16(a, b0, t2A, 0, 0, 0);
        t2B = __builtin_amdgcn_mfma_f32_16x16x32_f16(a, b1, t2B, 0, 0, 0);

        float evA = (i == 0) ? ev0a : ((i == 1) ? ev1a : ev2a);
        float evB = (i == 0) ? ev0b : ((i == 1) ? ev1b : ev2b);
        #pragma unroll
        for (int q = 0; q < 4; q++) {
            yvA[q][i] = fmaf(evA, t1A[q], t2A[q]);
            yvB[q][i] = fmaf(evB, t1B[q], t2B[q]);
        }
    }

    // ================= phase C: in-block segmented reduction ================
    __syncthreads();

    if (half == 0) sdst[t2] = dS;

    {
        bool okA = (pA < p1), okB = (pB < p1);
        #pragma unroll
        for (int ot = 0; ot < 2; ot++) {
            *(f32x4*)&redf[eb0 * 84 + ot * 16 + lg * 4] = okA ? accS[0][ot] : zero4;
            *(f32x4*)&redf[eb1 * 84 + ot * 16 + lg * 4] = okB ? accS[1][ot] : zero4;
        }
        #pragma unroll
        for (int q = 0; q < 4; q++) {
            int m = lg * 4 + q;
            #pragma unroll
            for (int i = 0; i < 3; i++) {
                redf[eb0 * 84 + 32 + 3 * m + i] = okA ? yvA[q][i] : 0.0f;
                redf[eb1 * 84 + 32 + 3 * m + i] = okB ? yvB[q][i] : 0.0f;
            }
        }
    }
    __syncthreads();

    {
        int base = w * 32;
        int cur = sdst[base];
        float s0 = 0.0f, s1 = 0.0f;
        for (int r = 0; r < 32; r++) {
            int d = sdst[base + r];
            if (d != cur) {
                atomicAdd(&out[(size_t)cur * OUT_PER_NODE + lane], s0);
                if (lane < 16) atomicAdd(&out[(size_t)cur * OUT_PER_NODE + 64 + lane], s1);
                s0 = 0.0f; s1 = 0.0f; cur = d;
            }
            s0 += redf[(base + r) * 84 + lane];
            if (lane < 16) s1 += redf[(base + r) * 84 + 64 + lane];
        }
        atomicAdd(&out[(size_t)cur * OUT_PER_NODE + lane], s0);
        if (lane < 16) atomicAdd(&out[(size_t)cur * OUT_PER_NODE + 64 + lane], s1);
    }
}

// ---------------------------------------------------------------------------
extern "C" void kernel_launch(void* const* d_in, const int* in_sizes, int n_in,
                              void* d_out, int out_size, void* d_ws, size_t ws_size,
                              hipStream_t stream) {
    const int*   esrc = (const int*)  d_in[0];
    const int*   edst = (const int*)  d_in[1];
    const float* ecut = (const float*)d_in[2];
    const float* einv = (const float*)d_in[3];
    const float* ns   = (const float*)d_in[4];
    const float* nv   = (const float*)d_in[5];
    const float* esh  = (const float*)d_in[6];
    const float* W0   = (const float*)d_in[7];
    const float* W1   = (const float*)d_in[8];
    const float* W2   = (const float*)d_in[9];
    const float* WLs  = (const float*)d_in[10];
    const float* WLv  = (const float*)d_in[11];
    float* out = (float*)d_out;

    const int E  = in_sizes[0];
    const int Nn = in_sizes[4] / S_IN;
    const int nb = (Nn + 255) / 256;

    size_t int_bytes = (((size_t)(3 * Nn + 1 + nb)) * sizeof(int) + 255) & ~(size_t)255;
    size_t pe_bytes  = ((size_t)E * 64 + 255) & ~(size_t)255;
    size_t pw_bytes  = ((size_t)PWTOT * 2 + 255) & ~(size_t)255;
    size_t ns_bytes  = ((size_t)Nn * 32 * 2 + 255) & ~(size_t)255;
    size_t nv_bytes  = ((size_t)Nn * 48 * 2 + 255) & ~(size_t)255;
    size_t fixed = int_bytes + pe_bytes + pw_bytes + ns_bytes + nv_bytes;

    int eblocks = (E + 255) / 256;

    hipMemsetAsync(out, 0, (size_t)Nn * OUT_PER_NODE * sizeof(float), stream);

    if (ws_size < fixed) return;   // ws known ample from prior rounds

    int*            deg    = (int*)d_ws;
    int*            offs   = deg + Nn;          // Nn+1
    int*            cursor = offs + Nn + 1;     // Nn
    int*            bsum   = cursor + Nn;       // nb
    uint4*          pedge  = (uint4*)((char*)d_ws + int_bytes);
    unsigned short* pW     = (unsigned short*)((char*)d_ws + int_bytes + pe_bytes);
    unsigned short* pNS    = (unsigned short*)((char*)d_ws + int_bytes + pe_bytes + pw_bytes);
    unsigned short* pNV    = (unsigned short*)((char*)d_ws + int_bytes + pe_bytes + pw_bytes + ns_bytes);

    hipMemsetAsync(deg, 0, (size_t)Nn * sizeof(int), stream);

    int ptotal = PWTOT + Nn * 4 + Nn * 6;
    int hp_blocks = max(eblocks, (ptotal + 255) / 256);
    hist_prep<<<hp_blocks, 256, 0, stream>>>(edst, deg, E, W0, W1, W2, WLs, WLv,
                                             ns, nv, pW, pNS, pNV, Nn);
    scanA<<<nb, 256, 0, stream>>>(deg, bsum, Nn);
    scanB<<<1, 1024, 0, stream>>>(bsum, nb);
    scanC<<<nb, 256, 0, stream>>>(deg, bsum, offs, cursor, Nn, E);
    scatter_permute<<<eblocks, 256, 0, stream>>>(edst, esrc, ecut, esh, einv,
                                                 cursor, pedge, E);

    int mblocks = (E + 127) / 128;
    edge_mega<<<mblocks, 256, 0, stream>>>(pedge, pW, pNS, pNV, out, E);
}

// Round 15
// 214.343 us; speedup vs baseline: 5.8526x; 1.1789x over previous
//
#include <hip/hip_runtime.h>
#include <hip/hip_fp16.h>
#include <math.h>

// Problem constants
constexpr int S_IN = 32, V_IN = 16, INVD = 16;
constexpr int S_MSG = S_IN + V_IN;           // 48
constexpr int V_MSG = S_IN + V_IN;           // 48
constexpr int NFAC  = S_MSG + V_MSG;         // 96
constexpr int S_OUT = 32, V_OUT = 16;
constexpr int OUT_PER_NODE = S_OUT + V_OUT * 3;  // 80
constexpr float ISQRT3 = 0.57735026918962576f;
constexpr float ISQ48  = 0.14433756729740643f;

// prepped-weight layout (in shorts): W0T[64][40] | W1T[64][72] | W2T[96][72] | WLT[48][72]
constexpr int PW0 = 0, PW1 = 2560, PW2 = 7168, PWL = 14080, PWTOT = 17536;

typedef _Float16 f16x8 __attribute__((ext_vector_type(8)));
typedef __attribute__((ext_vector_type(4))) float f32x4;

__device__ __forceinline__ float silu_f(float x) {
    return x / (1.0f + __expf(-x));
}
__device__ __forceinline__ unsigned int hpack2(float a, float b) {
    __half2 h = __floats2half2_rn(a, b);        // v_cvt_pkrtz_f16_f32
    return *reinterpret_cast<unsigned int*>(&h);
}
__device__ __forceinline__ unsigned short f2h(float f) {
    __half h = __float2half_rn(f);
    return __half_as_ushort(h);
}
__device__ __forceinline__ float h2f(unsigned short u) {
    return __half2float(__ushort_as_half(u));
}
// load 4 fp16 from LDS (8B-aligned) -> 4 floats
__device__ __forceinline__ void ld4h(const unsigned short* p, float f[4]) {
    uint2 v = *reinterpret_cast<const uint2*>(p);
    f[0] = h2f((unsigned short)(v.x & 0xffffu));
    f[1] = h2f((unsigned short)(v.x >> 16));
    f[2] = h2f((unsigned short)(v.y & 0xffffu));
    f[3] = h2f((unsigned short)(v.y >> 16));
}

// ---------------------------------------------------------------------------
// hist + prep fused (independent jobs, one launch)
// ---------------------------------------------------------------------------
__global__ __launch_bounds__(256) void hist_prep(
    const int* __restrict__ edst, int* __restrict__ deg, int E,
    const float* __restrict__ W0, const float* __restrict__ W1,
    const float* __restrict__ W2, const float* __restrict__ WLs,
    const float* __restrict__ WLv,
    const float* __restrict__ ns, const float* __restrict__ nv,
    unsigned short* __restrict__ pW,
    unsigned short* __restrict__ pNS,
    unsigned short* __restrict__ pNV,
    int Nn)
{
    int i = blockIdx.x * 256 + threadIdx.x;
    if (i < E) atomicAdd(&deg[edst[i]], 1);

    int nNS = Nn * 4;   // uint4-groups of 8 floats
    int nNV = Nn * 6;
    if (i < PWTOT) {
        float v = 0.0f;
        if (i < PW1) {
            int j = i / 40, k = i - 40 * j;
            if (k < INVD) v = W0[k * 64 + j];
        } else if (i < PW2) {
            int t = i - PW1; int j = t / 72, k = t - 72 * j;
            if (k < 64) v = W1[k * 64 + j];
        } else if (i < PWL) {
            int t = i - PW2; int j = t / 72, k = t - 72 * j;
            if (k < 64) v = W2[k * 96 + j];
        } else {
            int t = i - PWL; int j = t / 72, k = t - 72 * j;
            if (k < 48) v = (j < 32) ? WLs[k * S_OUT + j] : WLv[k * V_OUT + (j - 32)];
        }
        pW[i] = f2h(v);
    } else if (i < PWTOT + nNS) {
        int g = i - PWTOT;
        const float4* s4 = reinterpret_cast<const float4*>(ns + (size_t)g * 8);
        float4 a = s4[0], b = s4[1];
        *reinterpret_cast<uint4*>(pNS + (size_t)g * 8) =
            make_uint4(hpack2(a.x, a.y), hpack2(a.z, a.w), hpack2(b.x, b.y), hpack2(b.z, b.w));
    } else if (i < PWTOT + nNS + nNV) {
        int g = i - PWTOT - nNS;
        const float4* s4 = reinterpret_cast<const float4*>(nv + (size_t)g * 8);
        float4 a = s4[0], b = s4[1];
        *reinterpret_cast<uint4*>(pNV + (size_t)g * 8) =
            make_uint4(hpack2(a.x, a.y), hpack2(a.z, a.w), hpack2(b.x, b.y), hpack2(b.z, b.w));
    }
}

// ---------------------------------------------------------------------------
// 3-kernel parallel scan
// ---------------------------------------------------------------------------
__global__ __launch_bounds__(256) void scanA(
    const int* __restrict__ deg, int* __restrict__ bsum, int Nn)
{
    __shared__ int sh[256];
    int i = blockIdx.x * 256 + threadIdx.x;
    sh[threadIdx.x] = (i < Nn) ? deg[i] : 0;
    __syncthreads();
    for (int o = 128; o > 0; o >>= 1) {
        if (threadIdx.x < o) sh[threadIdx.x] += sh[threadIdx.x + o];
        __syncthreads();
    }
    if (threadIdx.x == 0) bsum[blockIdx.x] = sh[0];
}

__global__ __launch_bounds__(1024) void scanB(int* __restrict__ bsum, int nb)
{
    __shared__ int sh[1024];
    int t = threadIdx.x;
    sh[t] = (t < nb) ? bsum[t] : 0;
    __syncthreads();
    for (int o = 1; o < 1024; o <<= 1) {
        int v = (t >= o) ? sh[t - o] : 0;
        __syncthreads();
        sh[t] += v;
        __syncthreads();
    }
    if (t < nb) bsum[t] = (t > 0) ? sh[t - 1] : 0;   // exclusive
}

__global__ __launch_bounds__(256) void scanC(
    const int* __restrict__ deg, const int* __restrict__ bsum,
    int* __restrict__ offs, int* __restrict__ cursor, int Nn, int E)
{
    __shared__ int sh[256];
    int i = blockIdx.x * 256 + threadIdx.x;
    int t = threadIdx.x;
    int v = (i < Nn) ? deg[i] : 0;
    sh[t] = v;
    __syncthreads();
    for (int o = 1; o < 256; o <<= 1) {
        int u = (t >= o) ? sh[t - o] : 0;
        __syncthreads();
        sh[t] += u;
        __syncthreads();
    }
    int excl = sh[t] - v + bsum[blockIdx.x];
    if (i < Nn) { offs[i] = excl; cursor[i] = excl; }
    if (i == Nn - 1) offs[Nn] = E;
}

// Fat scatter: build 64B per-edge record at permuted position.
// rec[p] = { einv f16 x16 (32B) | cut,esh0,esh1,esh2 f32 (16B) | src,dst,0,0 }
__global__ __launch_bounds__(256) void scatter_permute(
    const int*   __restrict__ edst,
    const int*   __restrict__ esrc,
    const float* __restrict__ ecut,
    const float* __restrict__ esh,
    const float* __restrict__ einv,
    int* __restrict__ cursor,
    uint4* __restrict__ pedge,
    int E)
{
    int e = blockIdx.x * 256 + threadIdx.x;
    if (e >= E) return;
    int d = edst[e];
    int pos = atomicAdd(&cursor[d], 1);

    const float4* xr = reinterpret_cast<const float4*>(einv + (size_t)e * INVD);
    float4 a = xr[0], b = xr[1], c = xr[2], f = xr[3];
    uint4 r0 = make_uint4(hpack2(a.x, a.y), hpack2(a.z, a.w), hpack2(b.x, b.y), hpack2(b.z, b.w));
    uint4 r1 = make_uint4(hpack2(c.x, c.y), hpack2(c.z, c.w), hpack2(f.x, f.y), hpack2(f.z, f.w));
    uint4 r2 = make_uint4(__float_as_uint(ecut[e]),
                          __float_as_uint(esh[(size_t)e * 3 + 0]),
                          __float_as_uint(esh[(size_t)e * 3 + 1]),
                          __float_as_uint(esh[(size_t)e * 3 + 2]));
    uint4 r3 = make_uint4((unsigned int)esrc[e], (unsigned int)d, 0u, 0u);

    uint4* dst = pedge + (size_t)pos * 4;
    dst[0] = r0; dst[1] = r1; dst[2] = r2; dst[3] = r3;
}

// ---------------------------------------------------------------------------
// MEGA kernel v7: fp16, component-major Fnv, vectorized LDS datapath.
// Block = 128 edges, 4 waves. LDS 53760 B -> 3 blocks/CU.
// Phase-B layout (bytes):
//   sWLT [5120,12032) | M [14336,32768) | Fns[128][40] [32768,43008)
//   sdst [43008,43520) | Fnv0 [43520,48640) | Fnv1 [48640,53760)
//   Fnv2 [0,5120)  (old W0T region, dead after layer 1)
// Phase-C: redf[128][84] f32 [0,43008); sdst preserved.
// ---------------------------------------------------------------------------
__global__ __launch_bounds__(256, 3) void edge_mega(
    const uint4* __restrict__ pedge,
    const unsigned short* __restrict__ pW,
    const unsigned short* __restrict__ pNS,
    const unsigned short* __restrict__ pNV,
    float* __restrict__ out,
    int E)
{
    __shared__ __align__(16) unsigned char smem[53760];

    unsigned short* sW0T = (unsigned short*)(smem + 0);      // [64][40]  (A)
    unsigned short* sW1T = (unsigned short*)(smem + 5120);   // [64][72]  (A)
    unsigned short* act0 = (unsigned short*)(smem + 14336);  // [128][72] (A)
    unsigned short* act1 = (unsigned short*)(smem + 32768);  // [128][72] (A)
    unsigned short* sWLT = (unsigned short*)(smem + 5120);   // [48][72]  (B)
    unsigned short* M    = (unsigned short*)(smem + 14336);  // [128][72] (B)
    unsigned short* Fns  = (unsigned short*)(smem + 32768);  // [128][40] (B)
    int*            sdst = (int*)(smem + 43008);             // [128]
    unsigned short* Fnv0 = (unsigned short*)(smem + 43520);  // [128][20] (B)
    unsigned short* Fnv1 = (unsigned short*)(smem + 48640);  // [128][20] (B)
    unsigned short* Fnv2 = (unsigned short*)(smem + 0);      // [128][20] (B)
    float*          redf = (float*)smem;                     // [128][84] (C)

    const int tid = threadIdx.x;
    const int pbase = blockIdx.x * 128;
    const int p1 = E;

    const int lane = tid & 63;
    const int w    = tid >> 6;
    const int lr   = lane & 15;
    const int lg   = lane >> 4;
    const int eb0  = w * 32 + lr;
    const int eb1  = eb0 + 16;
    const int pA   = pbase + eb0;
    const int pB   = pbase + eb1;

    // ============ PREFETCH ============
    const uint4 rA2 = pedge[(size_t)(pA < p1 ? pA : p1 - 1) * 4 + 2];
    const uint4 rB2 = pedge[(size_t)(pB < p1 ? pB : p1 - 1) * 4 + 2];
    const float cutA = __uint_as_float(rA2.x);
    const float ev0a = __uint_as_float(rA2.y), ev1a = __uint_as_float(rA2.z), ev2a = __uint_as_float(rA2.w);
    const float cutB = __uint_as_float(rB2.x);
    const float ev0b = __uint_as_float(rB2.y), ev1b = __uint_as_float(rB2.z), ev2b = __uint_as_float(rB2.w);

    const int t2 = tid >> 1, half = tid & 1;
    int dS;
    uint4 pf0, pf1, pf2, pf3, pf4, pf5;
    {
        int pS = pbase + t2; if (pS >= p1) pS = p1 - 1;
        uint4 r3 = pedge[(size_t)pS * 4 + 3];
        int sS = (int)r3.x;
        dS = (int)r3.y;
        if (half == 0) {
            const uint4* nr = reinterpret_cast<const uint4*>(pNS + (size_t)sS * 32);
            pf0 = nr[0]; pf1 = nr[1]; pf2 = nr[2]; pf3 = nr[3];
        } else {
            const uint4* vr = reinterpret_cast<const uint4*>(pNV + (size_t)sS * 48);
            pf0 = vr[0]; pf1 = vr[1]; pf2 = vr[2]; pf3 = vr[3]; pf4 = vr[4]; pf5 = vr[5];
        }
    }

    const uint4* wsrc = reinterpret_cast<const uint4*>(pW);

    // ---- phase 1: copy W0T+W1T (896 uint4), stage X from record ----
    {
        uint4* s4 = reinterpret_cast<uint4*>(smem);
        #pragma unroll 2
        for (int i = tid; i < 896; i += 256) s4[i] = wsrc[i];
    }
    if (tid < 128) {
        int p = pbase + tid; if (p >= p1) p = p1 - 1;
        const uint4* rec = pedge + (size_t)p * 4;
        uint4 r0 = rec[0], r1 = rec[1];
        uint4* r4 = reinterpret_cast<uint4*>(&act0[tid * 72]);
        r4[0] = r0;
        r4[1] = r1;
        r4[2] = make_uint4(0u, 0u, 0u, 0u);
        r4[3] = make_uint4(0u, 0u, 0u, 0u);
    }
    __syncthreads();

    const f32x4 zero4 = {0.f, 0.f, 0.f, 0.f};

    // ---- Layer 1: h1 = silu((X@W0)/4) ----
    {
        f16x8 b0 = *(const f16x8*)&act0[eb0 * 72 + lg * 8];
        f16x8 b1 = *(const f16x8*)&act0[eb1 * 72 + lg * 8];
        #pragma unroll
        for (int jt = 0; jt < 4; jt++) {
            f16x8 a = *(const f16x8*)&sW0T[(jt * 16 + lr) * 40 + lg * 8];
            f32x4 d0 = __builtin_amdgcn_mfma_f32_16x16x32_f16(a, b0, zero4, 0, 0, 0);
            f32x4 d1 = __builtin_amdgcn_mfma_f32_16x16x32_f16(a, b1, zero4, 0, 0, 0);
            unsigned int u0 = hpack2(silu_f(d0[0] * 0.25f), silu_f(d0[1] * 0.25f));
            unsigned int u1 = hpack2(silu_f(d0[2] * 0.25f), silu_f(d0[3] * 0.25f));
            *(uint2*)&act1[eb0 * 72 + jt * 16 + lg * 4] = make_uint2(u0, u1);
            u0 = hpack2(silu_f(d1[0] * 0.25f), silu_f(d1[1] * 0.25f));
            u1 = hpack2(silu_f(d1[2] * 0.25f), silu_f(d1[3] * 0.25f));
            *(uint2*)&act1[eb1 * 72 + jt * 16 + lg * 4] = make_uint2(u0, u1);
        }
    }

    // ---- Layer 2: h2 = silu((h1@W1)/8) ----
    {
        f16x8 b00 = *(const f16x8*)&act1[eb0 * 72 +      lg * 8];
        f16x8 b01 = *(const f16x8*)&act1[eb0 * 72 + 32 + lg * 8];
        f16x8 b10 = *(const f16x8*)&act1[eb1 * 72 +      lg * 8];
        f16x8 b11 = *(const f16x8*)&act1[eb1 * 72 + 32 + lg * 8];
        #pragma unroll
        for (int jt = 0; jt < 4; jt++) {
            f16x8 a0 = *(const f16x8*)&sW1T[(jt * 16 + lr) * 72 +      lg * 8];
            f16x8 a1 = *(const f16x8*)&sW1T[(jt * 16 + lr) * 72 + 32 + lg * 8];
            f32x4 d0 = __builtin_amdgcn_mfma_f32_16x16x32_f16(a0, b00, zero4, 0, 0, 0);
            d0 = __builtin_amdgcn_mfma_f32_16x16x32_f16(a1, b01, d0, 0, 0, 0);
            f32x4 d1 = __builtin_amdgcn_mfma_f32_16x16x32_f16(a0, b10, zero4, 0, 0, 0);
            d1 = __builtin_amdgcn_mfma_f32_16x16x32_f16(a1, b11, d1, 0, 0, 0);
            unsigned int u0 = hpack2(silu_f(d0[0] * 0.125f), silu_f(d0[1] * 0.125f));
            unsigned int u1 = hpack2(silu_f(d0[2] * 0.125f), silu_f(d0[3] * 0.125f));
            *(uint2*)&act0[eb0 * 72 + jt * 16 + lg * 4] = make_uint2(u0, u1);
            u0 = hpack2(silu_f(d1[0] * 0.125f), silu_f(d1[1] * 0.125f));
            u1 = hpack2(silu_f(d1[2] * 0.125f), silu_f(d1[3] * 0.125f));
            *(uint2*)&act0[eb1 * 72 + jt * 16 + lg * 4] = make_uint2(u0, u1);
        }
    }

    // ---- stage W2T into act1 ----
    __syncthreads();
    {
        uint4* a14 = reinterpret_cast<uint4*>(act1);
        const uint4* w2s = wsrc + 896;
        #pragma unroll 2
        for (int i = tid; i < 864; i += 256) a14[i] = w2s[i];
    }
    __syncthreads();

    // ---- Layer 3: fac -> registers (scales folded) ----
    float fac0[6][4], fac1[6][4];
    {
        f16x8 b00 = *(const f16x8*)&act0[eb0 * 72 +      lg * 8];
        f16x8 b01 = *(const f16x8*)&act0[eb0 * 72 + 32 + lg * 8];
        f16x8 b10 = *(const f16x8*)&act0[eb1 * 72 +      lg * 8];
        f16x8 b11 = *(const f16x8*)&act0[eb1 * 72 + 32 + lg * 8];
        float K0 = cutA * 0.125f * ISQ48;
        float K1 = cutB * 0.125f * ISQ48;
        #pragma unroll
        for (int jt = 0; jt < 6; jt++) {
            f16x8 a0 = *(const f16x8*)&act1[(jt * 16 + lr) * 72 +      lg * 8];
            f16x8 a1 = *(const f16x8*)&act1[(jt * 16 + lr) * 72 + 32 + lg * 8];
            f32x4 d0 = __builtin_amdgcn_mfma_f32_16x16x32_f16(a0, b00, zero4, 0, 0, 0);
            d0 = __builtin_amdgcn_mfma_f32_16x16x32_f16(a1, b01, d0, 0, 0, 0);
            f32x4 d1 = __builtin_amdgcn_mfma_f32_16x16x32_f16(a0, b10, zero4, 0, 0, 0);
            d1 = __builtin_amdgcn_mfma_f32_16x16x32_f16(a1, b11, d1, 0, 0, 0);
            float s0 = (jt == 0) ? K0 * ISQRT3 : K0;
            float s1 = (jt == 0) ? K1 * ISQRT3 : K1;
            #pragma unroll
            for (int q = 0; q < 4; q++) {
                fac0[jt][q] = d0[q] * s0;
                fac1[jt][q] = d1[q] * s1;
            }
        }
    }
    __syncthreads();

    // ---- phase 6: write prefetched features to LDS (vectorized) + WLT ----
    {
        if (half == 0) {
            // Fns row: 32 contiguous fp16, stride 40 -> base 16B-aligned
            uint4* d4 = reinterpret_cast<uint4*>(&Fns[t2 * 40]);
            d4[0] = pf0; d4[1] = pf1;
            uint4* d4b = reinterpret_cast<uint4*>(&Fns[t2 * 40 + 16]);
            d4b[0] = pf2; d4b[1] = pf3;
        } else {
            // register transpose: v[3r+i] -> Fnv_i[t2][r], written as 4 uint2 per comp
            unsigned int wb[24];
            wb[0]=pf0.x; wb[1]=pf0.y; wb[2]=pf0.z; wb[3]=pf0.w;
            wb[4]=pf1.x; wb[5]=pf1.y; wb[6]=pf1.z; wb[7]=pf1.w;
            wb[8]=pf2.x; wb[9]=pf2.y; wb[10]=pf2.z; wb[11]=pf2.w;
            wb[12]=pf3.x; wb[13]=pf3.y; wb[14]=pf3.z; wb[15]=pf3.w;
            wb[16]=pf4.x; wb[17]=pf4.y; wb[18]=pf4.z; wb[19]=pf4.w;
            wb[20]=pf5.x; wb[21]=pf5.y; wb[22]=pf5.z; wb[23]=pf5.w;
            #pragma unroll
            for (int i = 0; i < 3; i++) {
                unsigned short* FnvI = (i == 0) ? Fnv0 : ((i == 1) ? Fnv1 : Fnv2);
                unsigned int ow[8];
                #pragma unroll
                for (int wd = 0; wd < 8; wd++) {
                    int kLo = 6 * wd + i;        // v[3*(2wd)+i]
                    int kHi = 6 * wd + 3 + i;    // v[3*(2wd+1)+i]
                    unsigned int lo = (kLo & 1) ? (wb[kLo >> 1] >> 16) : (wb[kLo >> 1] & 0xffffu);
                    unsigned int hi = (kHi & 1) ? (wb[kHi >> 1] >> 16) : (wb[kHi >> 1] & 0xffffu);
                    ow[wd] = lo | (hi << 16);
                }
                uint2* d2 = reinterpret_cast<uint2*>(&FnvI[t2 * 20]);
                d2[0] = make_uint2(ow[0], ow[1]);
                d2[1] = make_uint2(ow[2], ow[3]);
                d2[2] = make_uint2(ow[4], ow[5]);
                d2[3] = make_uint2(ow[6], ow[7]);
            }
        }
        uint4* wl4 = reinterpret_cast<uint4*>(sWLT);
        const uint4* wls = wsrc + 896 + 864;
        #pragma unroll 2
        for (int i = tid; i < 432; i += 256) wl4[i] = wls[i];
    }
    __syncthreads();

    // ---- load per-thread feature fragments ONCE (vectorized uint2 reads) ----
    float fvA[3][4], fvB[3][4];   // Fnv_i[eb][lg*4 + q]
    float fsA[2][4], fsB[2][4];   // Fns[eb][jt*16 + lg*4 + q]
    #pragma unroll
    for (int i = 0; i < 3; i++) {
        const unsigned short* FnvI = (i == 0) ? Fnv0 : ((i == 1) ? Fnv1 : Fnv2);
        ld4h(&FnvI[eb0 * 20 + lg * 4], fvA[i]);
        ld4h(&FnvI[eb1 * 20 + lg * 4], fvB[i]);
    }
    #pragma unroll
    for (int jt = 0; jt < 2; jt++) {
        ld4h(&Fns[eb0 * 40 + jt * 16 + lg * 4], fsA[jt]);
        ld4h(&Fns[eb1 * 40 + jt * 16 + lg * 4], fsB[jt]);
    }

    // ---- M_s fill (48 gated scalar-message cols; 48..63 zero) ----
    {
        // jt0: tp_s = dot(nv_c, ev)  (cols 0..15)
        float vA[4], vB[4];
        #pragma unroll
        for (int q = 0; q < 4; q++) {
            float fa = fvA[0][q] * ev0a + fvA[1][q] * ev1a + fvA[2][q] * ev2a;
            float fb = fvB[0][q] * ev0b + fvB[1][q] * ev1b + fvB[2][q] * ev2b;
            vA[q] = fa * fac0[0][q];
            vB[q] = fb * fac1[0][q];
        }
        *(uint2*)&M[eb0 * 72 + lg * 4] = make_uint2(hpack2(vA[0], vA[1]), hpack2(vA[2], vA[3]));
        *(uint2*)&M[eb1 * 72 + lg * 4] = make_uint2(hpack2(vB[0], vB[1]), hpack2(vB[2], vB[3]));
    }
    #pragma unroll
    for (int jt = 1; jt < 3; jt++) {   // src_s cols 16..47
        int c0 = jt * 16 + lg * 4;
        float vA[4], vB[4];
        #pragma unroll
        for (int q = 0; q < 4; q++) {
            vA[q] = fsA[jt - 1][q] * fac0[jt][q];
            vB[q] = fsB[jt - 1][q] * fac1[jt][q];
        }
        *(uint2*)&M[eb0 * 72 + c0] = make_uint2(hpack2(vA[0], vA[1]), hpack2(vA[2], vA[3]));
        *(uint2*)&M[eb1 * 72 + c0] = make_uint2(hpack2(vB[0], vB[1]), hpack2(vB[2], vB[3]));
    }
    *(uint2*)&M[eb0 * 72 + 48 + lg * 4] = make_uint2(0u, 0u);
    *(uint2*)&M[eb1 * 72 + 48 + lg * 4] = make_uint2(0u, 0u);

    // ---- ys GEMM (keep in regs) ----
    f32x4 accS[2][2] = {{zero4, zero4}, {zero4, zero4}};
    #pragma unroll
    for (int kt = 0; kt < 2; kt++) {
        f16x8 b0 = *(const f16x8*)&M[eb0 * 72 + kt * 32 + lg * 8];
        f16x8 b1 = *(const f16x8*)&M[eb1 * 72 + kt * 32 + lg * 8];
        #pragma unroll
        for (int ot = 0; ot < 2; ot++) {
            f16x8 a = *(const f16x8*)&sWLT[(ot * 16 + lr) * 72 + kt * 32 + lg * 8];
            accS[0][ot] = __builtin_amdgcn_mfma_f32_16x16x32_f16(a, b0, accS[0][ot], 0, 0, 0);
            accS[1][ot] = __builtin_amdgcn_mfma_f32_16x16x32_f16(a, b1, accS[1][ot], 0, 0, 0);
        }
    }

    // ---- T1: (ns .* g2[0:32]) @ WLv[0:32], K=32, i-independent ----
    #pragma unroll
    for (int jt = 0; jt < 2; jt++) {
        int c0 = jt * 16 + lg * 4;
        float vA[4], vB[4];
        #pragma unroll
        for (int q = 0; q < 4; q++) {
            vA[q] = fsA[jt][q] * fac0[3 + jt][q];
            vB[q] = fsB[jt][q] * fac1[3 + jt][q];
        }
        *(uint2*)&M[eb0 * 72 + c0] = make_uint2(hpack2(vA[0], vA[1]), hpack2(vA[2], vA[3]));
        *(uint2*)&M[eb1 * 72 + c0] = make_uint2(hpack2(vB[0], vB[1]), hpack2(vB[2], vB[3]));
    }
    f32x4 t1A = zero4, t1B = zero4;
    {
        f16x8 b0 = *(const f16x8*)&M[eb0 * 72 + lg * 8];
        f16x8 b1 = *(const f16x8*)&M[eb1 * 72 + lg * 8];
        f16x8 a  = *(const f16x8*)&sWLT[(32 + lr) * 72 + lg * 8];
        t1A = __builtin_amdgcn_mfma_f32_16x16x32_f16(a, b0, t1A, 0, 0, 0);
        t1B = __builtin_amdgcn_mfma_f32_16x16x32_f16(a, b1, t1B, 0, 0, 0);
    }

    // ---- T2_i: (nv_i .* g2[32:48]) @ WLv[32:48], K=16 (padded); combine ----
    float yvA[4][3], yvB[4][3];
    *(uint2*)&M[eb0 * 72 + 16 + lg * 4] = make_uint2(0u, 0u);
    *(uint2*)&M[eb1 * 72 + 16 + lg * 4] = make_uint2(0u, 0u);
    #pragma unroll
    for (int i = 0; i < 3; i++) {
        float vA[4], vB[4];
        #pragma unroll
        for (int q = 0; q < 4; q++) {
            vA[q] = fvA[i][q] * fac0[5][q];
            vB[q] = fvB[i][q] * fac1[5][q];
        }
        *(uint2*)&M[eb0 * 72 + lg * 4] = make_uint2(hpack2(vA[0], vA[1]), hpack2(vA[2], vA[3]));
        *(uint2*)&M[eb1 * 72 + lg * 4] = make_uint2(hpack2(vB[0], vB[1]), hpack2(vB[2], vB[3]));

        f32x4 t2A = zero4, t2B = zero4;
        f16x8 b0 = *(const f16x8*)&M[eb0 * 72 + lg * 8];
        f16x8 b1 = *(const f16x8*)&M[eb1 * 72 + lg * 8];
        f16x8 a  = *(const f16x8*)&sWLT[(32 + lr) * 72 + 32 + lg * 8];
        t2A = __builtin_amdgcn_mfma_f32_16x16x32_f16(a, b0, t2A, 0, 0, 0);
        t2B = __builtin_amdgcn_mfma_f32_16x16x32_f16(a, b1, t2B, 0, 0, 0);

        float evA = (i == 0) ? ev0a : ((i == 1) ? ev1a : ev2a);
        float evB = (i == 0) ? ev0b : ((i == 1) ? ev1b : ev2b);
        #pragma unroll
        for (int q = 0; q < 4; q++) {
            yvA[q][i] = fmaf(evA, t1A[q], t2A[q]);
            yvB[q][i] = fmaf(evB, t1B[q], t2B[q]);
        }
    }

    // ================= phase C: in-block segmented reduction ================
    __syncthreads();

    if (half == 0) sdst[t2] = dS;

    {
        bool okA = (pA < p1), okB = (pB < p1);
        #pragma unroll
        for (int ot = 0; ot < 2; ot++) {
            *(f32x4*)&redf[eb0 * 84 + ot * 16 + lg * 4] = okA ? accS[0][ot] : zero4;
            *(f32x4*)&redf[eb1 * 84 + ot * 16 + lg * 4] = okB ? accS[1][ot] : zero4;
        }
        #pragma unroll
        for (int q = 0; q < 4; q++) {
            int m = lg * 4 + q;
            #pragma unroll
            for (int i = 0; i < 3; i++) {
                redf[eb0 * 84 + 32 + 3 * m + i] = okA ? yvA[q][i] : 0.0f;
                redf[eb1 * 84 + 32 + 3 * m + i] = okB ? yvB[q][i] : 0.0f;
            }
        }
    }
    __syncthreads();

    {
        int base = w * 32;
        int cur = sdst[base];
        float s0 = 0.0f, s1 = 0.0f;
        for (int r = 0; r < 32; r++) {
            int d = sdst[base + r];
            if (d != cur) {
                atomicAdd(&out[(size_t)cur * OUT_PER_NODE + lane], s0);
                if (lane < 16) atomicAdd(&out[(size_t)cur * OUT_PER_NODE + 64 + lane], s1);
                s0 = 0.0f; s1 = 0.0f; cur = d;
            }
            s0 += redf[(base + r) * 84 + lane];
            if (lane < 16) s1 += redf[(base + r) * 84 + 64 + lane];
        }
        atomicAdd(&out[(size_t)cur * OUT_PER_NODE + lane], s0);
        if (lane < 16) atomicAdd(&out[(size_t)cur * OUT_PER_NODE + 64 + lane], s1);
    }
}

// ---------------------------------------------------------------------------
extern "C" void kernel_launch(void* const* d_in, const int* in_sizes, int n_in,
                              void* d_out, int out_size, void* d_ws, size_t ws_size,
                              hipStream_t stream) {
    const int*   esrc = (const int*)  d_in[0];
    const int*   edst = (const int*)  d_in[1];
    const float* ecut = (const float*)d_in[2];
    const float* einv = (const float*)d_in[3];
    const float* ns   = (const float*)d_in[4];
    const float* nv   = (const float*)d_in[5];
    const float* esh  = (const float*)d_in[6];
    const float* W0   = (const float*)d_in[7];
    const float* W1   = (const float*)d_in[8];
    const float* W2   = (const float*)d_in[9];
    const float* WLs  = (const float*)d_in[10];
    const float* WLv  = (const float*)d_in[11];
    float* out = (float*)d_out;

    const int E  = in_sizes[0];
    const int Nn = in_sizes[4] / S_IN;
    const int nb = (Nn + 255) / 256;

    size_t int_bytes = (((size_t)(3 * Nn + 1 + nb)) * sizeof(int) + 255) & ~(size_t)255;
    size_t pe_bytes  = ((size_t)E * 64 + 255) & ~(size_t)255;
    size_t pw_bytes  = ((size_t)PWTOT * 2 + 255) & ~(size_t)255;
    size_t ns_bytes  = ((size_t)Nn * 32 * 2 + 255) & ~(size_t)255;
    size_t nv_bytes  = ((size_t)Nn * 48 * 2 + 255) & ~(size_t)255;
    size_t fixed = int_bytes + pe_bytes + pw_bytes + ns_bytes + nv_bytes;

    int eblocks = (E + 255) / 256;

    hipMemsetAsync(out, 0, (size_t)Nn * OUT_PER_NODE * sizeof(float), stream);

    if (ws_size < fixed) return;   // ws known ample from prior rounds

    int*            deg    = (int*)d_ws;
    int*            offs   = deg + Nn;          // Nn+1
    int*            cursor = offs + Nn + 1;     // Nn
    int*            bsum   = cursor + Nn;       // nb
    uint4*          pedge  = (uint4*)((char*)d_ws + int_bytes);
    unsigned short* pW     = (unsigned short*)((char*)d_ws + int_bytes + pe_bytes);
    unsigned short* pNS    = (unsigned short*)((char*)d_ws + int_bytes + pe_bytes + pw_bytes);
    unsigned short* pNV    = (unsigned short*)((char*)d_ws + int_bytes + pe_bytes + pw_bytes + ns_bytes);

    hipMemsetAsync(deg, 0, (size_t)Nn * sizeof(int), stream);

    int ptotal = PWTOT + Nn * 4 + Nn * 6;
    int hp_blocks = max(eblocks, (ptotal + 255) / 256);
    hist_prep<<<hp_blocks, 256, 0, stream>>>(edst, deg, E, W0, W1, W2, WLs, WLv,
                                             ns, nv, pW, pNS, pNV, Nn);
    scanA<<<nb, 256, 0, stream>>>(deg, bsum, Nn);
    scanB<<<1, 1024, 0, stream>>>(bsum, nb);
    scanC<<<nb, 256, 0, stream>>>(deg, bsum, offs, cursor, Nn, E);
    scatter_permute<<<eblocks, 256, 0, stream>>>(edst, esrc, ecut, esh, einv,
                                                 cursor, pedge, E);

    int mblocks = (E + 127) / 128;
    edge_mega<<<mblocks, 256, 0, stream>>>(pedge, pW, pNS, pNV, out, E);
}

// Round 16
// 209.635 us; speedup vs baseline: 5.9841x; 1.0225x over previous
//
#include <hip/hip_runtime.h>
#include <hip/hip_fp16.h>
#include <math.h>

// Problem constants
constexpr int S_IN = 32, V_IN = 16, INVD = 16;
constexpr int S_MSG = S_IN + V_IN;           // 48
constexpr int V_MSG = S_IN + V_IN;           // 48
constexpr int NFAC  = S_MSG + V_MSG;         // 96
constexpr int S_OUT = 32, V_OUT = 16;
constexpr int OUT_PER_NODE = S_OUT + V_OUT * 3;  // 80
constexpr float ISQRT3 = 0.57735026918962576f;
constexpr float ISQ48  = 0.14433756729740643f;

// prepped-weight layout (in shorts): W0T[64][40] | W1T[64][72] | W2T[96][72] | WLT[48][72]
constexpr int PW0 = 0, PW1 = 2560, PW2 = 7168, PWL = 14080, PWTOT = 17536;

typedef _Float16 f16x8 __attribute__((ext_vector_type(8)));
typedef __attribute__((ext_vector_type(4))) float f32x4;

__device__ __forceinline__ float silu_f(float x) {
    // fast: x * rcp(1+e^-x); v_rcp_f32 (~1ulp) instead of precise-div sequence
    return x * __builtin_amdgcn_rcpf(1.0f + __expf(-x));
}
__device__ __forceinline__ unsigned int hpack2(float a, float b) {
    __half2 h = __floats2half2_rn(a, b);        // v_cvt_pkrtz_f16_f32
    return *reinterpret_cast<unsigned int*>(&h);
}
__device__ __forceinline__ unsigned short f2h(float f) {
    __half h = __float2half_rn(f);
    return __half_as_ushort(h);
}
__device__ __forceinline__ float h2f(unsigned short u) {
    return __half2float(__ushort_as_half(u));
}
__device__ __forceinline__ float lo16f(unsigned int u) { return h2f((unsigned short)(u & 0xffffu)); }
__device__ __forceinline__ float hi16f(unsigned int u) { return h2f((unsigned short)(u >> 16)); }
__device__ __forceinline__ unsigned int pkmul(unsigned int a, unsigned int b) {
    __half2 ha = *reinterpret_cast<__half2*>(&a);
    __half2 hb = *reinterpret_cast<__half2*>(&b);
    __half2 hc = __hmul2(ha, hb);               // v_pk_mul_f16
    return *reinterpret_cast<unsigned int*>(&hc);
}
__device__ __forceinline__ float2 up2(unsigned int u) {
    __half2 h = *reinterpret_cast<__half2*>(&u);
    return __half22float2(h);
}

// ---------------------------------------------------------------------------
// hist + prep fused (independent jobs, one launch)
// ---------------------------------------------------------------------------
__global__ __launch_bounds__(256) void hist_prep(
    const int* __restrict__ edst, int* __restrict__ deg, int E,
    const float* __restrict__ W0, const float* __restrict__ W1,
    const float* __restrict__ W2, const float* __restrict__ WLs,
    const float* __restrict__ WLv,
    const float* __restrict__ ns, const float* __restrict__ nv,
    unsigned short* __restrict__ pW,
    unsigned short* __restrict__ pNS,
    unsigned short* __restrict__ pNV,
    int Nn)
{
    int i = blockIdx.x * 256 + threadIdx.x;
    if (i < E) atomicAdd(&deg[edst[i]], 1);

    int nNS = Nn * 4;   // uint4-groups of 8 floats
    int nNV = Nn * 6;
    if (i < PWTOT) {
        float v = 0.0f;
        if (i < PW1) {
            int j = i / 40, k = i - 40 * j;
            if (k < INVD) v = W0[k * 64 + j];
        } else if (i < PW2) {
            int t = i - PW1; int j = t / 72, k = t - 72 * j;
            if (k < 64) v = W1[k * 64 + j];
        } else if (i < PWL) {
            int t = i - PW2; int j = t / 72, k = t - 72 * j;
            if (k < 64) v = W2[k * 96 + j];
        } else {
            int t = i - PWL; int j = t / 72, k = t - 72 * j;
            if (k < 48) v = (j < 32) ? WLs[k * S_OUT + j] : WLv[k * V_OUT + (j - 32)];
        }
        pW[i] = f2h(v);
    } else if (i < PWTOT + nNS) {
        int g = i - PWTOT;
        const float4* s4 = reinterpret_cast<const float4*>(ns + (size_t)g * 8);
        float4 a = s4[0], b = s4[1];
        *reinterpret_cast<uint4*>(pNS + (size_t)g * 8) =
            make_uint4(hpack2(a.x, a.y), hpack2(a.z, a.w), hpack2(b.x, b.y), hpack2(b.z, b.w));
    } else if (i < PWTOT + nNS + nNV) {
        int g = i - PWTOT - nNS;
        const float4* s4 = reinterpret_cast<const float4*>(nv + (size_t)g * 8);
        float4 a = s4[0], b = s4[1];
        *reinterpret_cast<uint4*>(pNV + (size_t)g * 8) =
            make_uint4(hpack2(a.x, a.y), hpack2(a.z, a.w), hpack2(b.x, b.y), hpack2(b.z, b.w));
    }
}

// ---------------------------------------------------------------------------
// 3-kernel parallel scan
// ---------------------------------------------------------------------------
__global__ __launch_bounds__(256) void scanA(
    const int* __restrict__ deg, int* __restrict__ bsum, int Nn)
{
    __shared__ int sh[256];
    int i = blockIdx.x * 256 + threadIdx.x;
    sh[threadIdx.x] = (i < Nn) ? deg[i] : 0;
    __syncthreads();
    for (int o = 128; o > 0; o >>= 1) {
        if (threadIdx.x < o) sh[threadIdx.x] += sh[threadIdx.x + o];
        __syncthreads();
    }
    if (threadIdx.x == 0) bsum[blockIdx.x] = sh[0];
}

__global__ __launch_bounds__(1024) void scanB(int* __restrict__ bsum, int nb)
{
    __shared__ int sh[1024];
    int t = threadIdx.x;
    sh[t] = (t < nb) ? bsum[t] : 0;
    __syncthreads();
    for (int o = 1; o < 1024; o <<= 1) {
        int v = (t >= o) ? sh[t - o] : 0;
        __syncthreads();
        sh[t] += v;
        __syncthreads();
    }
    if (t < nb) bsum[t] = (t > 0) ? sh[t - 1] : 0;   // exclusive
}

__global__ __launch_bounds__(256) void scanC(
    const int* __restrict__ deg, const int* __restrict__ bsum,
    int* __restrict__ offs, int* __restrict__ cursor, int Nn, int E)
{
    __shared__ int sh[256];
    int i = blockIdx.x * 256 + threadIdx.x;
    int t = threadIdx.x;
    int v = (i < Nn) ? deg[i] : 0;
    sh[t] = v;
    __syncthreads();
    for (int o = 1; o < 256; o <<= 1) {
        int u = (t >= o) ? sh[t - o] : 0;
        __syncthreads();
        sh[t] += u;
        __syncthreads();
    }
    int excl = sh[t] - v + bsum[blockIdx.x];
    if (i < Nn) { offs[i] = excl; cursor[i] = excl; }
    if (i == Nn - 1) offs[Nn] = E;
}

// Fat scatter: 48B per-edge record at permuted position (3 x uint4).
// r0,r1 = einv f16 x16 (32B)
// r2 = { cut_h|esh0_h, esh1_h|esh2_h, src, dst } (16B)
__global__ __launch_bounds__(256) void scatter_permute(
    const int*   __restrict__ edst,
    const int*   __restrict__ esrc,
    const float* __restrict__ ecut,
    const float* __restrict__ esh,
    const float* __restrict__ einv,
    int* __restrict__ cursor,
    uint4* __restrict__ pedge,
    int E)
{
    int e = blockIdx.x * 256 + threadIdx.x;
    if (e >= E) return;
    int d = edst[e];
    int pos = atomicAdd(&cursor[d], 1);

    const float4* xr = reinterpret_cast<const float4*>(einv + (size_t)e * INVD);
    float4 a = xr[0], b = xr[1], c = xr[2], f = xr[3];
    uint4 r0 = make_uint4(hpack2(a.x, a.y), hpack2(a.z, a.w), hpack2(b.x, b.y), hpack2(b.z, b.w));
    uint4 r1 = make_uint4(hpack2(c.x, c.y), hpack2(c.z, c.w), hpack2(f.x, f.y), hpack2(f.z, f.w));
    uint4 r2 = make_uint4(hpack2(ecut[e], esh[(size_t)e * 3 + 0]),
                          hpack2(esh[(size_t)e * 3 + 1], esh[(size_t)e * 3 + 2]),
                          (unsigned int)esrc[e], (unsigned int)d);

    uint4* dst = pedge + (size_t)pos * 3;
    dst[0] = r0; dst[1] = r1; dst[2] = r2;
}

// ---------------------------------------------------------------------------
// MEGA kernel v8: fp16 datapath, packed-fp16 gated products, fast silu,
// 48B records. Block = 128 edges, 4 waves. LDS 53760 B -> 3 blocks/CU.
// ---------------------------------------------------------------------------
__global__ __launch_bounds__(256, 3) void edge_mega(
    const uint4* __restrict__ pedge,
    const unsigned short* __restrict__ pW,
    const unsigned short* __restrict__ pNS,
    const unsigned short* __restrict__ pNV,
    float* __restrict__ out,
    int E)
{
    __shared__ __align__(16) unsigned char smem[53760];

    unsigned short* sW0T = (unsigned short*)(smem + 0);      // [64][40]  (A)
    unsigned short* sW1T = (unsigned short*)(smem + 5120);   // [64][72]  (A)
    unsigned short* act0 = (unsigned short*)(smem + 14336);  // [128][72] (A)
    unsigned short* act1 = (unsigned short*)(smem + 32768);  // [128][72] (A)
    unsigned short* sWLT = (unsigned short*)(smem + 5120);   // [48][72]  (B)
    unsigned short* M    = (unsigned short*)(smem + 14336);  // [128][72] (B)
    unsigned short* Fns  = (unsigned short*)(smem + 32768);  // [128][40] (B)
    int*            sdst = (int*)(smem + 43008);             // [128]
    unsigned short* Fnv0 = (unsigned short*)(smem + 43520);  // [128][20] (B)
    unsigned short* Fnv1 = (unsigned short*)(smem + 48640);  // [128][20] (B)
    unsigned short* Fnv2 = (unsigned short*)(smem + 0);      // [128][20] (B)
    float*          redf = (float*)smem;                     // [128][84] (C)

    const int tid = threadIdx.x;
    const int pbase = blockIdx.x * 128;
    const int p1 = E;

    const int lane = tid & 63;
    const int w    = tid >> 6;
    const int lr   = lane & 15;
    const int lg   = lane >> 4;
    const int eb0  = w * 32 + lr;
    const int eb1  = eb0 + 16;
    const int pA   = pbase + eb0;
    const int pB   = pbase + eb1;

    // ============ PREFETCH ============
    const uint4 rA2 = pedge[(size_t)(pA < p1 ? pA : p1 - 1) * 3 + 2];
    const uint4 rB2 = pedge[(size_t)(pB < p1 ? pB : p1 - 1) * 3 + 2];
    const float cutA = lo16f(rA2.x);
    const float ev0a = hi16f(rA2.x), ev1a = lo16f(rA2.y), ev2a = hi16f(rA2.y);
    const float cutB = lo16f(rB2.x);
    const float ev0b = hi16f(rB2.x), ev1b = lo16f(rB2.y), ev2b = hi16f(rB2.y);

    const int t2 = tid >> 1, half = tid & 1;
    int dS;
    uint4 pf0, pf1, pf2, pf3, pf4, pf5;
    {
        int pS = pbase + t2; if (pS >= p1) pS = p1 - 1;
        uint4 r2 = pedge[(size_t)pS * 3 + 2];
        int sS = (int)r2.z;
        dS = (int)r2.w;
        if (half == 0) {
            const uint4* nr = reinterpret_cast<const uint4*>(pNS + (size_t)sS * 32);
            pf0 = nr[0]; pf1 = nr[1]; pf2 = nr[2]; pf3 = nr[3];
        } else {
            const uint4* vr = reinterpret_cast<const uint4*>(pNV + (size_t)sS * 48);
            pf0 = vr[0]; pf1 = vr[1]; pf2 = vr[2]; pf3 = vr[3]; pf4 = vr[4]; pf5 = vr[5];
        }
    }

    const uint4* wsrc = reinterpret_cast<const uint4*>(pW);

    // ---- phase 1: copy W0T+W1T (896 uint4), stage X from record ----
    {
        uint4* s4 = reinterpret_cast<uint4*>(smem);
        #pragma unroll 2
        for (int i = tid; i < 896; i += 256) s4[i] = wsrc[i];
    }
    if (tid < 128) {
        int p = pbase + tid; if (p >= p1) p = p1 - 1;
        const uint4* rec = pedge + (size_t)p * 3;
        uint4 r0 = rec[0], r1 = rec[1];
        uint4* r4 = reinterpret_cast<uint4*>(&act0[tid * 72]);
        r4[0] = r0;
        r4[1] = r1;
        r4[2] = make_uint4(0u, 0u, 0u, 0u);
        r4[3] = make_uint4(0u, 0u, 0u, 0u);
    }
    __syncthreads();

    const f32x4 zero4 = {0.f, 0.f, 0.f, 0.f};

    // ---- Layer 1: h1 = silu((X@W0)/4) ----
    {
        f16x8 b0 = *(const f16x8*)&act0[eb0 * 72 + lg * 8];
        f16x8 b1 = *(const f16x8*)&act0[eb1 * 72 + lg * 8];
        #pragma unroll
        for (int jt = 0; jt < 4; jt++) {
            f16x8 a = *(const f16x8*)&sW0T[(jt * 16 + lr) * 40 + lg * 8];
            f32x4 d0 = __builtin_amdgcn_mfma_f32_16x16x32_f16(a, b0, zero4, 0, 0, 0);
            f32x4 d1 = __builtin_amdgcn_mfma_f32_16x16x32_f16(a, b1, zero4, 0, 0, 0);
            unsigned int u0 = hpack2(silu_f(d0[0] * 0.25f), silu_f(d0[1] * 0.25f));
            unsigned int u1 = hpack2(silu_f(d0[2] * 0.25f), silu_f(d0[3] * 0.25f));
            *(uint2*)&act1[eb0 * 72 + jt * 16 + lg * 4] = make_uint2(u0, u1);
            u0 = hpack2(silu_f(d1[0] * 0.25f), silu_f(d1[1] * 0.25f));
            u1 = hpack2(silu_f(d1[2] * 0.25f), silu_f(d1[3] * 0.25f));
            *(uint2*)&act1[eb1 * 72 + jt * 16 + lg * 4] = make_uint2(u0, u1);
        }
    }

    // ---- Layer 2: h2 = silu((h1@W1)/8) ----
    {
        f16x8 b00 = *(const f16x8*)&act1[eb0 * 72 +      lg * 8];
        f16x8 b01 = *(const f16x8*)&act1[eb0 * 72 + 32 + lg * 8];
        f16x8 b10 = *(const f16x8*)&act1[eb1 * 72 +      lg * 8];
        f16x8 b11 = *(const f16x8*)&act1[eb1 * 72 + 32 + lg * 8];
        #pragma unroll
        for (int jt = 0; jt < 4; jt++) {
            f16x8 a0 = *(const f16x8*)&sW1T[(jt * 16 + lr) * 72 +      lg * 8];
            f16x8 a1 = *(const f16x8*)&sW1T[(jt * 16 + lr) * 72 + 32 + lg * 8];
            f32x4 d0 = __builtin_amdgcn_mfma_f32_16x16x32_f16(a0, b00, zero4, 0, 0, 0);
            d0 = __builtin_amdgcn_mfma_f32_16x16x32_f16(a1, b01, d0, 0, 0, 0);
            f32x4 d1 = __builtin_amdgcn_mfma_f32_16x16x32_f16(a0, b10, zero4, 0, 0, 0);
            d1 = __builtin_amdgcn_mfma_f32_16x16x32_f16(a1, b11, d1, 0, 0, 0);
            unsigned int u0 = hpack2(silu_f(d0[0] * 0.125f), silu_f(d0[1] * 0.125f));
            unsigned int u1 = hpack2(silu_f(d0[2] * 0.125f), silu_f(d0[3] * 0.125f));
            *(uint2*)&act0[eb0 * 72 + jt * 16 + lg * 4] = make_uint2(u0, u1);
            u0 = hpack2(silu_f(d1[0] * 0.125f), silu_f(d1[1] * 0.125f));
            u1 = hpack2(silu_f(d1[2] * 0.125f), silu_f(d1[3] * 0.125f));
            *(uint2*)&act0[eb1 * 72 + jt * 16 + lg * 4] = make_uint2(u0, u1);
        }
    }

    // ---- stage W2T into act1 ----
    __syncthreads();
    {
        uint4* a14 = reinterpret_cast<uint4*>(act1);
        const uint4* w2s = wsrc + 896;
        #pragma unroll 2
        for (int i = tid; i < 864; i += 256) a14[i] = w2s[i];
    }
    __syncthreads();

    // ---- Layer 3: fac -> registers (scales folded) ----
    float fac0[6][4], fac1[6][4];
    {
        f16x8 b00 = *(const f16x8*)&act0[eb0 * 72 +      lg * 8];
        f16x8 b01 = *(const f16x8*)&act0[eb0 * 72 + 32 + lg * 8];
        f16x8 b10 = *(const f16x8*)&act0[eb1 * 72 +      lg * 8];
        f16x8 b11 = *(const f16x8*)&act0[eb1 * 72 + 32 + lg * 8];
        float K0 = cutA * 0.125f * ISQ48;
        float K1 = cutB * 0.125f * ISQ48;
        #pragma unroll
        for (int jt = 0; jt < 6; jt++) {
            f16x8 a0 = *(const f16x8*)&act1[(jt * 16 + lr) * 72 +      lg * 8];
            f16x8 a1 = *(const f16x8*)&act1[(jt * 16 + lr) * 72 + 32 + lg * 8];
            f32x4 d0 = __builtin_amdgcn_mfma_f32_16x16x32_f16(a0, b00, zero4, 0, 0, 0);
            d0 = __builtin_amdgcn_mfma_f32_16x16x32_f16(a1, b01, d0, 0, 0, 0);
            f32x4 d1 = __builtin_amdgcn_mfma_f32_16x16x32_f16(a0, b10, zero4, 0, 0, 0);
            d1 = __builtin_amdgcn_mfma_f32_16x16x32_f16(a1, b11, d1, 0, 0, 0);
            float s0 = (jt == 0) ? K0 * ISQRT3 : K0;
            float s1 = (jt == 0) ? K1 * ISQRT3 : K1;
            #pragma unroll
            for (int q = 0; q < 4; q++) {
                fac0[jt][q] = d0[q] * s0;
                fac1[jt][q] = d1[q] * s1;
            }
        }
    }
    __syncthreads();

    // ---- phase 6: write prefetched features to LDS (vectorized) + WLT ----
    {
        if (half == 0) {
            uint4* d4 = reinterpret_cast<uint4*>(&Fns[t2 * 40]);
            d4[0] = pf0; d4[1] = pf1;
            uint4* d4b = reinterpret_cast<uint4*>(&Fns[t2 * 40 + 16]);
            d4b[0] = pf2; d4b[1] = pf3;
        } else {
            unsigned int wb[24];
            wb[0]=pf0.x; wb[1]=pf0.y; wb[2]=pf0.z; wb[3]=pf0.w;
            wb[4]=pf1.x; wb[5]=pf1.y; wb[6]=pf1.z; wb[7]=pf1.w;
            wb[8]=pf2.x; wb[9]=pf2.y; wb[10]=pf2.z; wb[11]=pf2.w;
            wb[12]=pf3.x; wb[13]=pf3.y; wb[14]=pf3.z; wb[15]=pf3.w;
            wb[16]=pf4.x; wb[17]=pf4.y; wb[18]=pf4.z; wb[19]=pf4.w;
            wb[20]=pf5.x; wb[21]=pf5.y; wb[22]=pf5.z; wb[23]=pf5.w;
            #pragma unroll
            for (int i = 0; i < 3; i++) {
                unsigned short* FnvI = (i == 0) ? Fnv0 : ((i == 1) ? Fnv1 : Fnv2);
                unsigned int ow[8];
                #pragma unroll
                for (int wd = 0; wd < 8; wd++) {
                    int kLo = 6 * wd + i;
                    int kHi = 6 * wd + 3 + i;
                    unsigned int lo = (kLo & 1) ? (wb[kLo >> 1] >> 16) : (wb[kLo >> 1] & 0xffffu);
                    unsigned int hi = (kHi & 1) ? (wb[kHi >> 1] >> 16) : (wb[kHi >> 1] & 0xffffu);
                    ow[wd] = lo | (hi << 16);
                }
                uint2* d2 = reinterpret_cast<uint2*>(&FnvI[t2 * 20]);
                d2[0] = make_uint2(ow[0], ow[1]);
                d2[1] = make_uint2(ow[2], ow[3]);
                d2[2] = make_uint2(ow[4], ow[5]);
                d2[3] = make_uint2(ow[6], ow[7]);
            }
        }
        uint4* wl4 = reinterpret_cast<uint4*>(sWLT);
        const uint4* wls = wsrc + 896 + 864;
        #pragma unroll 2
        for (int i = tid; i < 432; i += 256) wl4[i] = wls[i];
    }
    __syncthreads();

    // ---- load raw packed feature fragments ONCE ----
    uint2 fsrA[2], fsrB[2];   // Fns[eb][jt*16 + lg*4 .. +3]
    uint2 fvrA[3], fvrB[3];   // Fnv_i[eb][lg*4 .. +3]
    #pragma unroll
    for (int i = 0; i < 3; i++) {
        const unsigned short* FnvI = (i == 0) ? Fnv0 : ((i == 1) ? Fnv1 : Fnv2);
        fvrA[i] = *reinterpret_cast<const uint2*>(&FnvI[eb0 * 20 + lg * 4]);
        fvrB[i] = *reinterpret_cast<const uint2*>(&FnvI[eb1 * 20 + lg * 4]);
    }
    #pragma unroll
    for (int jt = 0; jt < 2; jt++) {
        fsrA[jt] = *reinterpret_cast<const uint2*>(&Fns[eb0 * 40 + jt * 16 + lg * 4]);
        fsrB[jt] = *reinterpret_cast<const uint2*>(&Fns[eb1 * 40 + jt * 16 + lg * 4]);
    }

    // ---- pack fac (jt 1..5) to fp16 for v_pk_mul_f16 path ----
    uint2 fpA[5], fpB[5];
    #pragma unroll
    for (int jt = 1; jt < 6; jt++) {
        fpA[jt - 1] = make_uint2(hpack2(fac0[jt][0], fac0[jt][1]), hpack2(fac0[jt][2], fac0[jt][3]));
        fpB[jt - 1] = make_uint2(hpack2(fac1[jt][0], fac1[jt][1]), hpack2(fac1[jt][2], fac1[jt][3]));
    }

    // ---- M_s fill: jt0 (tp_s dot, f32) + jt1,2 (packed mul) ----
    {
        float2 a0 = up2(fvrA[0].x), a1 = up2(fvrA[0].y);
        float2 b0 = up2(fvrA[1].x), b1 = up2(fvrA[1].y);
        float2 c0 = up2(fvrA[2].x), c1 = up2(fvrA[2].y);
        float2 d0 = up2(fvrB[0].x), d1 = up2(fvrB[0].y);
        float2 e0 = up2(fvrB[1].x), e1 = up2(fvrB[1].y);
        float2 g0 = up2(fvrB[2].x), g1 = up2(fvrB[2].y);
        float vA[4], vB[4];
        vA[0] = (a0.x*ev0a + b0.x*ev1a + c0.x*ev2a) * fac0[0][0];
        vA[1] = (a0.y*ev0a + b0.y*ev1a + c0.y*ev2a) * fac0[0][1];
        vA[2] = (a1.x*ev0a + b1.x*ev1a + c1.x*ev2a) * fac0[0][2];
        vA[3] = (a1.y*ev0a + b1.y*ev1a + c1.y*ev2a) * fac0[0][3];
        vB[0] = (d0.x*ev0b + e0.x*ev1b + g0.x*ev2b) * fac1[0][0];
        vB[1] = (d0.y*ev0b + e0.y*ev1b + g0.y*ev2b) * fac1[0][1];
        vB[2] = (d1.x*ev0b + e1.x*ev1b + g1.x*ev2b) * fac1[0][2];
        vB[3] = (d1.y*ev0b + e1.y*ev1b + g1.y*ev2b) * fac1[0][3];
        *(uint2*)&M[eb0 * 72 + lg * 4] = make_uint2(hpack2(vA[0], vA[1]), hpack2(vA[2], vA[3]));
        *(uint2*)&M[eb1 * 72 + lg * 4] = make_uint2(hpack2(vB[0], vB[1]), hpack2(vB[2], vB[3]));
    }
    #pragma unroll
    for (int jt = 1; jt < 3; jt++) {   // src_s cols 16..47 (packed)
        int c0 = jt * 16 + lg * 4;
        *(uint2*)&M[eb0 * 72 + c0] =
            make_uint2(pkmul(fsrA[jt-1].x, fpA[jt-1].x), pkmul(fsrA[jt-1].y, fpA[jt-1].y));
        *(uint2*)&M[eb1 * 72 + c0] =
            make_uint2(pkmul(fsrB[jt-1].x, fpB[jt-1].x), pkmul(fsrB[jt-1].y, fpB[jt-1].y));
    }
    *(uint2*)&M[eb0 * 72 + 48 + lg * 4] = make_uint2(0u, 0u);
    *(uint2*)&M[eb1 * 72 + 48 + lg * 4] = make_uint2(0u, 0u);

    // ---- ys GEMM (keep in regs) ----
    f32x4 accS[2][2] = {{zero4, zero4}, {zero4, zero4}};
    #pragma unroll
    for (int kt = 0; kt < 2; kt++) {
        f16x8 b0 = *(const f16x8*)&M[eb0 * 72 + kt * 32 + lg * 8];
        f16x8 b1 = *(const f16x8*)&M[eb1 * 72 + kt * 32 + lg * 8];
        #pragma unroll
        for (int ot = 0; ot < 2; ot++) {
            f16x8 a = *(const f16x8*)&sWLT[(ot * 16 + lr) * 72 + kt * 32 + lg * 8];
            accS[0][ot] = __builtin_amdgcn_mfma_f32_16x16x32_f16(a, b0, accS[0][ot], 0, 0, 0);
            accS[1][ot] = __builtin_amdgcn_mfma_f32_16x16x32_f16(a, b1, accS[1][ot], 0, 0, 0);
        }
    }

    // ---- T1: (ns .* g2[0:32]) @ WLv[0:32], K=32 (packed mul) ----
    #pragma unroll
    for (int jt = 0; jt < 2; jt++) {
        int c0 = jt * 16 + lg * 4;
        *(uint2*)&M[eb0 * 72 + c0] =
            make_uint2(pkmul(fsrA[jt].x, fpA[jt+2].x), pkmul(fsrA[jt].y, fpA[jt+2].y));
        *(uint2*)&M[eb1 * 72 + c0] =
            make_uint2(pkmul(fsrB[jt].x, fpB[jt+2].x), pkmul(fsrB[jt].y, fpB[jt+2].y));
    }
    f32x4 t1A = zero4, t1B = zero4;
    {
        f16x8 b0 = *(const f16x8*)&M[eb0 * 72 + lg * 8];
        f16x8 b1 = *(const f16x8*)&M[eb1 * 72 + lg * 8];
        f16x8 a  = *(const f16x8*)&sWLT[(32 + lr) * 72 + lg * 8];
        t1A = __builtin_amdgcn_mfma_f32_16x16x32_f16(a, b0, t1A, 0, 0, 0);
        t1B = __builtin_amdgcn_mfma_f32_16x16x32_f16(a, b1, t1B, 0, 0, 0);
    }

    // ---- T2_i: (nv_i .* g2[32:48]) @ WLv[32:48], K=16 (packed mul); combine ----
    float yvA[4][3], yvB[4][3];
    *(uint2*)&M[eb0 * 72 + 16 + lg * 4] = make_uint2(0u, 0u);
    *(uint2*)&M[eb1 * 72 + 16 + lg * 4] = make_uint2(0u, 0u);
    #pragma unroll
    for (int i = 0; i < 3; i++) {
        *(uint2*)&M[eb0 * 72 + lg * 4] =
            make_uint2(pkmul(fvrA[i].x, fpA[4].x), pkmul(fvrA[i].y, fpA[4].y));
        *(uint2*)&M[eb1 * 72 + lg * 4] =
            make_uint2(pkmul(fvrB[i].x, fpB[4].x), pkmul(fvrB[i].y, fpB[4].y));

        f32x4 t2A = zero4, t2B = zero4;
        f16x8 b0 = *(const f16x8*)&M[eb0 * 72 + lg * 8];
        f16x8 b1 = *(const f16x8*)&M[eb1 * 72 + lg * 8];
        f16x8 a  = *(const f16x8*)&sWLT[(32 + lr) * 72 + 32 + lg * 8];
        t2A = __builtin_amdgcn_mfma_f32_16x16x32_f16(a, b0, t2A, 0, 0, 0);
        t2B = __builtin_amdgcn_mfma_f32_16x16x32_f16(a, b1, t2B, 0, 0, 0);

        float evA = (i == 0) ? ev0a : ((i == 1) ? ev1a : ev2a);
        float evB = (i == 0) ? ev0b : ((i == 1) ? ev1b : ev2b);
        #pragma unroll
        for (int q = 0; q < 4; q++) {
            yvA[q][i] = fmaf(evA, t1A[q], t2A[q]);
            yvB[q][i] = fmaf(evB, t1B[q], t2B[q]);
        }
    }

    // ================= phase C: in-block segmented reduction ================
    __syncthreads();

    if (half == 0) sdst[t2] = dS;

    {
        bool okA = (pA < p1), okB = (pB < p1);
        #pragma unroll
        for (int ot = 0; ot < 2; ot++) {
            *(f32x4*)&redf[eb0 * 84 + ot * 16 + lg * 4] = okA ? accS[0][ot] : zero4;
            *(f32x4*)&redf[eb1 * 84 + ot * 16 + lg * 4] = okB ? accS[1][ot] : zero4;
        }
        #pragma unroll
        for (int q = 0; q < 4; q++) {
            int m = lg * 4 + q;
            #pragma unroll
            for (int i = 0; i < 3; i++) {
                redf[eb0 * 84 + 32 + 3 * m + i] = okA ? yvA[q][i] : 0.0f;
                redf[eb1 * 84 + 32 + 3 * m + i] = okB ? yvB[q][i] : 0.0f;
            }
        }
    }
    __syncthreads();

    {
        int base = w * 32;
        int cur = sdst[base];
        float s0 = 0.0f, s1 = 0.0f;
        for (int r = 0; r < 32; r++) {
            int d = sdst[base + r];
            if (d != cur) {
                atomicAdd(&out[(size_t)cur * OUT_PER_NODE + lane], s0);
                if (lane < 16) atomicAdd(&out[(size_t)cur * OUT_PER_NODE + 64 + lane], s1);
                s0 = 0.0f; s1 = 0.0f; cur = d;
            }
            s0 += redf[(base + r) * 84 + lane];
            if (lane < 16) s1 += redf[(base + r) * 84 + 64 + lane];
        }
        atomicAdd(&out[(size_t)cur * OUT_PER_NODE + lane], s0);
        if (lane < 16) atomicAdd(&out[(size_t)cur * OUT_PER_NODE + 64 + lane], s1);
    }
}

// ---------------------------------------------------------------------------
extern "C" void kernel_launch(void* const* d_in, const int* in_sizes, int n_in,
                              void* d_out, int out_size, void* d_ws, size_t ws_size,
                              hipStream_t stream) {
    const int*   esrc = (const int*)  d_in[0];
    const int*   edst = (const int*)  d_in[1];
    const float* ecut = (const float*)d_in[2];
    const float* einv = (const float*)d_in[3];
    const float* ns   = (const float*)d_in[4];
    const float* nv   = (const float*)d_in[5];
    const float* esh  = (const float*)d_in[6];
    const float* W0   = (const float*)d_in[7];
    const float* W1   = (const float*)d_in[8];
    const float* W2   = (const float*)d_in[9];
    const float* WLs  = (const float*)d_in[10];
    const float* WLv  = (const float*)d_in[11];
    float* out = (float*)d_out;

    const int E  = in_sizes[0];
    const int Nn = in_sizes[4] / S_IN;
    const int nb = (Nn + 255) / 256;

    size_t int_bytes = (((size_t)(3 * Nn + 1 + nb)) * sizeof(int) + 255) & ~(size_t)255;
    size_t pe_bytes  = ((size_t)E * 48 + 255) & ~(size_t)255;
    size_t pw_bytes  = ((size_t)PWTOT * 2 + 255) & ~(size_t)255;
    size_t ns_bytes  = ((size_t)Nn * 32 * 2 + 255) & ~(size_t)255;
    size_t nv_bytes  = ((size_t)Nn * 48 * 2 + 255) & ~(size_t)255;
    size_t fixed = int_bytes + pe_bytes + pw_bytes + ns_bytes + nv_bytes;

    int eblocks = (E + 255) / 256;

    hipMemsetAsync(out, 0, (size_t)Nn * OUT_PER_NODE * sizeof(float), stream);

    if (ws_size < fixed) return;   // ws known ample from prior rounds

    int*            deg    = (int*)d_ws;
    int*            offs   = deg + Nn;          // Nn+1
    int*            cursor = offs + Nn + 1;     // Nn
    int*            bsum   = cursor + Nn;       // nb
    uint4*          pedge  = (uint4*)((char*)d_ws + int_bytes);
    unsigned short* pW     = (unsigned short*)((char*)d_ws + int_bytes + pe_bytes);
    unsigned short* pNS    = (unsigned short*)((char*)d_ws + int_bytes + pe_bytes + pw_bytes);
    unsigned short* pNV    = (unsigned short*)((char*)d_ws + int_bytes + pe_bytes + pw_bytes + ns_bytes);

    hipMemsetAsync(deg, 0, (size_t)Nn * sizeof(int), stream);

    int ptotal = PWTOT + Nn * 4 + Nn * 6;
    int hp_blocks = max(eblocks, (ptotal + 255) / 256);
    hist_prep<<<hp_blocks, 256, 0, stream>>>(edst, deg, E, W0, W1, W2, WLs, WLv,
                                             ns, nv, pW, pNS, pNV, Nn);
    scanA<<<nb, 256, 0, stream>>>(deg, bsum, Nn);
    scanB<<<1, 1024, 0, stream>>>(bsum, nb);
    scanC<<<nb, 256, 0, stream>>>(deg, bsum, offs, cursor, Nn, E);
    scatter_permute<<<eblocks, 256, 0, stream>>>(edst, esrc, ecut, esh, einv,
                                                 cursor, pedge, E);

    int mblocks = (E + 127) / 128;
    edge_mega<<<mblocks, 256, 0, stream>>>(pedge, pW, pNS, pNV, out, E);
}